// Round 2
// 451.338 us; speedup vs baseline: 1.0725x; 1.0725x over previous
//
#include <hip/hip_runtime.h>
#include <math.h>

#define BB 2
#define SS 2048
#define DD 2048
#define HH 16
#define DN 128
#define DR 64
#define DV 128
#define QL 1536
#define KVL 512
#define DQ 192           // DN + DR
#define CKVS 640         // ckv row stride (576 padded to 640)
#define KVD 256          // DN + DV
#define NCAT 2176        // QL + CKVS (fused first GEMM)
#define NCATP 2304       // NCAT padded to 9*256 for the 256-wide GEMM tile
#define EPSF 1e-6f

typedef short bfrag __attribute__((ext_vector_type(8)));   // 8 bf16 (4 VGPRs)
typedef float facc  __attribute__((ext_vector_type(4)));   // 4 fp32 acc

// ---------------- helpers ----------------
__device__ __forceinline__ ushort f2bf(float f) {
    union { float f; unsigned u; } v; v.f = f;
    unsigned r = v.u + 0x7fffu + ((v.u >> 16) & 1u);  // RNE
    return (ushort)(r >> 16);
}
__device__ __forceinline__ float bf2f(ushort u) {
    union { unsigned u; float f; } v; v.u = ((unsigned)u) << 16;
    return v.f;
}
__device__ __forceinline__ float wave_red_sum(float v) {
    #pragma unroll
    for (int o = 32; o > 0; o >>= 1) v += __shfl_down(v, o);
    return v;
}
__device__ __forceinline__ void gl2lds16(const ushort* g, ushort* l) {
    __builtin_amdgcn_global_load_lds(
        (const __attribute__((address_space(1))) void*)g,
        (__attribute__((address_space(3))) void*)l, 16, 0, 0);
}
__device__ __forceinline__ void storeC(float* c, float v)  { *c = v; }
__device__ __forceinline__ void storeC(ushort* c, float v) { *c = f2bf(v); }

// ---------------- fp32 -> bf16 cast (vectorized) ----------------
__global__ __launch_bounds__(256) void castf2bf(const float* __restrict__ x,
                                                ushort* __restrict__ y) {
    const int i = blockIdx.x * 256 + threadIdx.x;
    const float4 v = ((const float4*)x)[i];
    ushort4 o;
    o.x = f2bf(v.x); o.y = f2bf(v.y); o.z = f2bf(v.z); o.w = f2bf(v.w);
    ((ushort4*)y)[i] = o;
}

// ------- batched weight cast+transpose: 5 segments in one launch ----------
struct WtBatch {
    const float* src[5];
    ushort* dst[5];
    int K[5];
    int N[5];
    int nx[5];
    int base[6];
};
__global__ __launch_bounds__(256) void wtrans_b(WtBatch d) {
    __shared__ float tile[32][33];
    int bid = blockIdx.x;
    int seg = 0;
    while (bid >= d.base[seg + 1]) ++seg;
    const int l = bid - d.base[seg];
    const int nx = d.nx[seg];
    const int bx = l % nx, by = l / nx;
    const float* W = d.src[seg];
    ushort* Wt = d.dst[seg];
    const int K = d.K[seg], N = d.N[seg];
    const int k0 = by * 32, n0 = bx * 32;
    const int t = threadIdx.x;
    const int tx = t & 31, ty = t >> 5;
    #pragma unroll
    for (int r = 0; r < 4; ++r) {
        const int n = n0 + tx;
        tile[ty + r * 8][tx] =
            (n < N) ? W[(size_t)(k0 + ty + r * 8) * N + n] : 0.f;
    }
    __syncthreads();
    #pragma unroll
    for (int r = 0; r < 4; ++r) {
        const int n = n0 + ty + r * 8;
        Wt[(size_t)n * K + k0 + tx] = f2bf(tile[tx][ty + r * 8]);
    }
}

// ================== 256x256 8-phase MFMA GEMM (m201 template) ==============
// 512 threads = 8 waves (2M x 4N), per-wave C = 128x64, BK=64, dbuf LDS 128KB
// (STATIC __shared__ -- dynamic >64KB needs a runtime opt-in that can abort
//  graph capture; static 128KB is within gfx950's 160KB target limit).
// LDS regions (ushort offsets): REGOFF(buf,ab,half) = buf*32768 + ab*16384 +
// half*8192, half = 128 rows x 64 cols bf16 (16KB).
// T2 swizzle: logical 16B slot s of row r lives at physical slot s^(r&7);
// gl2lds writes linearly, so the GLOBAL source is pre-swizzled and ds_read
// applies the same XOR (involution).  Per-phase: {ds_read frags | stage 1-2
// half-tiles | (vmcnt at q4) | barrier | lgkmcnt(0) | 16 MFMA | barrier}.
// Stage schedule (K-tile kt, buf p=kt&1): q1: A-h0(kt+1)->p^1, q2: A-h1(kt+1),
// q4: B-h0+B-h1(kt+2)->p with vmcnt(4).  Every overwrite is >=1 barrier-pair
// after the last read of that region; reads of kt+1 are behind q4's vmcnt.

__device__ __forceinline__ void stage_half(const ushort* __restrict__ G,
                                           int ldg, int grow0, int kcol0,
                                           ushort* Lr, int wave, int lane) {
    const int r0   = lane >> 3;
    const int slot = (lane & 7) ^ r0;          // inverse-swizzled global slot
    const ushort* s0 = G + (size_t)(grow0 + wave * 16 + r0) * ldg + kcol0 + slot * 8;
    gl2lds16(s0,                    Lr + wave * 1024);        // rows w*16..+8
    gl2lds16(s0 + (size_t)8 * ldg,  Lr + wave * 1024 + 512);  // rows +8..+16
}

#define PH_PRE  do { __builtin_amdgcn_sched_barrier(0);                      \
                     __builtin_amdgcn_s_barrier();                           \
                     asm volatile("s_waitcnt lgkmcnt(0)" ::: "memory");      \
                     __builtin_amdgcn_sched_barrier(0);                      \
                     __builtin_amdgcn_s_setprio(1); } while (0)
#define PH_POST do { __builtin_amdgcn_s_setprio(0);                          \
                     __builtin_amdgcn_sched_barrier(0);                      \
                     __builtin_amdgcn_s_barrier(); } while (0)

#define MFMA16(RB)                                                           \
    _Pragma("unroll")                                                        \
    for (int i = 0; i < 4; ++i)                                              \
        _Pragma("unroll")                                                    \
        for (int j = 0; j < 4; ++j)                                          \
            acc[(RB) + i][j] = __builtin_amdgcn_mfma_f32_16x16x32_bf16(      \
                a[i], b[j], acc[(RB) + i][j], 0, 0, 0);

#define GEMM256_CORE(A_, Bt_, K_, NBX_)                                       \
    __shared__ ushort L[65536]; /* 128 KiB static */                          \
    const int t    = threadIdx.x;                                             \
    const int lane = t & 63;                                                  \
    const int wave = t >> 6;                                                  \
    const int wm   = wave >> 2;                                               \
    const int wn   = wave & 3;                                                \
    const int quad = lane >> 4;                                               \
    const int lrow = lane & 15;                                               \
    int wg = (int)blockIdx.x;                                                 \
    { const int cpx = (int)gridDim.x >> 3; wg = (wg & 7) * cpx + (wg >> 3); } \
    const int bx = wg % (NBX_), by = wg / (NBX_);                             \
    const int m0 = by * 256, n0 = bx * 256;                                   \
    const int s0x8  = (quad ^ (lrow & 7)) * 8;   /* swizzled slot, kh=0 */    \
    const int s1x8  = s0x8 ^ 32;                 /* kh=1: slot^4          */  \
    const int abase = lrow * 64;                                              \
    const int bbase = (wn & 1) * 4096 + lrow * 64;                            \
    facc acc[8][4];                                                           \
    _Pragma("unroll")                                                         \
    for (int i = 0; i < 8; ++i)                                               \
        _Pragma("unroll")                                                     \
        for (int j = 0; j < 4; ++j) acc[i][j] = (facc)(0.f);                  \
    const int nk = (K_) >> 6;                                                 \
    /* prologue: K0 all 4 halves -> buf0; K1 B halves -> buf1 */              \
    stage_half((A_),  (K_), m0,        0, L,         wave, lane);             \
    stage_half((A_),  (K_), m0 + 128,  0, L + 8192,  wave, lane);             \
    stage_half((Bt_), (K_), n0,        0, L + 16384, wave, lane);             \
    stage_half((Bt_), (K_), n0 + 128,  0, L + 24576, wave, lane);             \
    stage_half((Bt_), (K_), n0,       64, L + 49152, wave, lane);             \
    stage_half((Bt_), (K_), n0 + 128, 64, L + 57344, wave, lane);             \
    asm volatile("s_waitcnt vmcnt(4)" ::: "memory");                          \
    __builtin_amdgcn_s_barrier();                                             \
    for (int kt = 0; kt < nk; ++kt) {                                         \
        const int p = kt & 1;                                                 \
        ushort* LA = L + p * 32768 + wm * 8192;                               \
        ushort* LB = L + p * 32768 + 16384 + (wn >> 1) * 8192;                \
        ushort* Lq = L + (p ^ 1) * 32768;                                     \
        const int kn = (kt + 1) * 64;                                         \
        bfrag a[4], b[4];                                                     \
        /* ---- q1: frags m0-3, kh0 ---- */                                   \
        _Pragma("unroll")                                                     \
        for (int i = 0; i < 4; ++i)                                           \
            a[i] = *(const bfrag*)(LA + i * 1024 + abase + s0x8);             \
        _Pragma("unroll")                                                     \
        for (int j = 0; j < 4; ++j)                                           \
            b[j] = *(const bfrag*)(LB + bbase + j * 1024 + s0x8);             \
        if (kt + 1 < nk) stage_half((A_), (K_), m0, kn, Lq, wave, lane);      \
        PH_PRE;                                                               \
        MFMA16(0)                                                             \
        PH_POST;                                                              \
        /* ---- q2: frags m4-7, kh0 (b reused) ---- */                        \
        _Pragma("unroll")                                                     \
        for (int i = 0; i < 4; ++i)                                           \
            a[i] = *(const bfrag*)(LA + (4 + i) * 1024 + abase + s0x8);       \
        if (kt + 1 < nk)                                                      \
            stage_half((A_), (K_), m0 + 128, kn, Lq + 8192, wave, lane);      \
        PH_PRE;                                                               \
        MFMA16(4)                                                             \
        PH_POST;                                                              \
        /* ---- q3: frags m0-3, kh1 ---- */                                   \
        _Pragma("unroll")                                                     \
        for (int i = 0; i < 4; ++i)                                           \
            a[i] = *(const bfrag*)(LA + i * 1024 + abase + s1x8);             \
        _Pragma("unroll")                                                     \
        for (int j = 0; j < 4; ++j)                                           \
            b[j] = *(const bfrag*)(LB + bbase + j * 1024 + s1x8);             \
        PH_PRE;                                                               \
        MFMA16(0)                                                             \
        PH_POST;                                                              \
        /* ---- q4: frags m4-7, kh1; stage B(kt+2); counted vmcnt ---- */     \
        _Pragma("unroll")                                                     \
        for (int i = 0; i < 4; ++i)                                           \
            a[i] = *(const bfrag*)(LA + (4 + i) * 1024 + abase + s1x8);       \
        if (kt + 2 < nk) {                                                    \
            stage_half((Bt_), (K_), n0,       kn + 64,                        \
                       L + p * 32768 + 16384, wave, lane);                    \
            stage_half((Bt_), (K_), n0 + 128, kn + 64,                        \
                       L + p * 32768 + 24576, wave, lane);                    \
            asm volatile("s_waitcnt vmcnt(4)" ::: "memory");                  \
        } else {                                                              \
            asm volatile("s_waitcnt vmcnt(0)" ::: "memory");                  \
        }                                                                     \
        PH_PRE;                                                               \
        MFMA16(4)                                                             \
        PH_POST;                                                              \
    }

// ---------------- generic 256-tile GEMM, row-major C ----------------
template <typename OUT, int K, int NBX, int NOUT>
__global__ __launch_bounds__(512, 2) void gemm256(const ushort* __restrict__ A,
                                                  const ushort* __restrict__ Bt,
                                                  OUT* __restrict__ C) {
    GEMM256_CORE(A, Bt, K, NBX)
    #pragma unroll
    for (int m = 0; m < 8; ++m) {
        const int row = m0 + wm * 128 + m * 16 + quad * 4;
        #pragma unroll
        for (int nf = 0; nf < 4; ++nf) {
            const int col = n0 + wn * 64 + nf * 16 + lrow;
            #pragma unroll
            for (int r = 0; r < 4; ++r)
                storeC(&C[(size_t)(row + r) * NOUT + col], acc[m][nf][r]);
        }
    }
}

// -------- fused GEMM A: hs @ [Wqa | Wkva] -> qa_bf, ckv_bf (N pad 2304) -----
__global__ __launch_bounds__(512, 2) void gemmA256(const ushort* __restrict__ A,
                                                   const ushort* __restrict__ Bt,
                                                   ushort* __restrict__ qa,
                                                   ushort* __restrict__ ckv) {
    GEMM256_CORE(A, Bt, DD, 9)
    #pragma unroll
    for (int m = 0; m < 8; ++m) {
        const int row = m0 + wm * 128 + m * 16 + quad * 4;
        #pragma unroll
        for (int nf = 0; nf < 4; ++nf) {
            const int col = n0 + wn * 64 + nf * 16 + lrow;
            #pragma unroll
            for (int r = 0; r < 4; ++r) {
                if (col < QL)
                    qa[(size_t)(row + r) * QL + col] = f2bf(acc[m][nf][r]);
                else if (col < NCAT)
                    ckv[(size_t)(row + r) * CKVS + col - QL] = f2bf(acc[m][nf][r]);
            }
        }
    }
}

// -------- GEMM Q: qa @ Wqb -> Qbuf[(b*HH+h)*SS+s][192], scale folded -------
__global__ __launch_bounds__(512, 2) void gemmQ256(const ushort* __restrict__ A,
                                                   const ushort* __restrict__ Bt,
                                                   ushort* __restrict__ Qbuf) {
    GEMM256_CORE(A, Bt, QL, 12)
    const float scaling = 0.07216878364870323f; // 192^-0.5
    #pragma unroll
    for (int m = 0; m < 8; ++m) {
        const int row = m0 + wm * 128 + m * 16 + quad * 4;
        #pragma unroll
        for (int nf = 0; nf < 4; ++nf) {
            const int col = n0 + wn * 64 + nf * 16 + lrow;
            const int h = col / DQ, d = col - h * DQ;
            #pragma unroll
            for (int r = 0; r < 4; ++r) {
                const int tok = row + r;
                const int b = tok >> 11, s = tok & (SS - 1);
                Qbuf[((size_t)(b * HH + h) * SS + s) * DQ + d] =
                    f2bf(acc[m][nf][r] * scaling);
            }
        }
    }
}

// ---------------- RMSNorm bf16 in-place ----------------
__global__ __launch_bounds__(256) void rmsnorm_bf_ip(ushort* __restrict__ x,
                                                     const float* __restrict__ w,
                                                     int n) {
    ushort* xr = x + (size_t)blockIdx.x * n;
    const int t = threadIdx.x;
    float ss = 0.f;
    for (int i = t; i < n; i += 256) { float v = bf2f(xr[i]); ss += v * v; }
    ss = wave_red_sum(ss);
    __shared__ float red[4];
    const int lane = t & 63, wid = t >> 6;
    if (lane == 0) red[wid] = ss;
    __syncthreads();
    const float tot = red[0] + red[1] + red[2] + red[3];
    const float scale = rsqrtf(tot / (float)n + EPSF);
    for (int i = t; i < n; i += 256) xr[i] = f2bf(w[i] * bf2f(xr[i]) * scale);
}

// ------- kv RMSNorm (ckv[:, :512] -> kvn) fused with roped k_rot -> krb -----
__global__ __launch_bounds__(256) void rmsnorm_kv(const ushort* __restrict__ x,
                                                  const float* __restrict__ w,
                                                  ushort* __restrict__ y,
                                                  ushort* __restrict__ krb,
                                                  const float* __restrict__ cosb,
                                                  const float* __restrict__ sinb) {
    const int row = blockIdx.x;
    const ushort* xr = x + (size_t)row * CKVS;
    ushort* yr = y + (size_t)row * KVL;
    const int t = threadIdx.x;
    if (t < 64) {   // k_rot rope (independent of the norm)
        const int p = t;
        const ushort* kin = xr + KVL;
        const float c  = cosb[(size_t)row * DR + p];
        const float sn = sinb[(size_t)row * DR + p];
        const float self = bf2f(kin[p]);
        const float partner = bf2f(kin[p < 32 ? p + 32 : p - 32]);
        const float v = (p < 32) ? (self * c - partner * sn)
                                 : (self * c + partner * sn);
        krb[(size_t)row * DR + p] = f2bf(v);
    }
    float ss = 0.f;
    for (int i = t; i < KVL; i += 256) { float v = bf2f(xr[i]); ss += v * v; }
    ss = wave_red_sum(ss);
    __shared__ float red[4];
    const int lane = t & 63, wid = t >> 6;
    if (lane == 0) red[wid] = ss;
    __syncthreads();
    const float tot = red[0] + red[1] + red[2] + red[3];
    const float scale = rsqrtf(tot / (float)KVL + EPSF);
    for (int i = t; i < KVL; i += 256) yr[i] = f2bf(w[i] * bf2f(xr[i]) * scale);
}

// ---------------- qrope: in-place rope on Qbuf rope lanes ----------------
__global__ __launch_bounds__(256) void qrope(ushort* __restrict__ Qbuf,
                                             const float* __restrict__ cosb,
                                             const float* __restrict__ sinb) {
    const int tok = blockIdx.x;
    const int b = tok >> 11, s = tok & (SS - 1);
    const int t = threadIdx.x;
    const int p = t & 31, hh = t >> 5;
    const float c0 = cosb[(size_t)tok * DR + p];
    const float s0 = sinb[(size_t)tok * DR + p];
    const float c1 = cosb[(size_t)tok * DR + p + 32];
    const float s1 = sinb[(size_t)tok * DR + p + 32];
    #pragma unroll
    for (int it = 0; it < 2; ++it) {
        const int h = hh + it * 8;
        ushort* base = Qbuf + ((size_t)(b * HH + h) * SS + s) * DQ + DN;
        const float x0 = bf2f(base[p]), x1 = bf2f(base[p + 32]);
        base[p]      = f2bf(x0 * c0 - x1 * s0);
        base[p + 32] = f2bf(x1 * c1 + x0 * s1);
    }
}

// ---------------- vprep: transpose V -> Vt[bh][dv][SS] bf16 ----------------
__global__ __launch_bounds__(256) void vprep(const ushort* __restrict__ kv_bf,
                                             ushort* __restrict__ Vtb) {
    __shared__ ushort tile[32][33];
    const int kp0 = blockIdx.x * 32, dv0 = blockIdx.y * 32, bh = blockIdx.z;
    const int b = bh / HH, h = bh - b * HH;
    const int t = threadIdx.x, tx = t & 31, ty = t >> 5;
    #pragma unroll
    for (int r = 0; r < 4; ++r)
        tile[ty + r * 8][tx] =
            kv_bf[(size_t)(b * SS + kp0 + ty + r * 8) * (HH * KVD) + h * KVD + DN + dv0 + tx];
    __syncthreads();
    #pragma unroll
    for (int r = 0; r < 4; ++r)
        Vtb[((size_t)bh * DV + dv0 + ty + r * 8) * SS + kp0 + tx] = tile[tx][ty + r * 8];
}

// ---------------- MFMA flash attention, q-tile 128, uniform pairing -------
__global__ __launch_bounds__(256, 2) void fattn_mfma(
    const ushort* __restrict__ Qb,   // [(b*HH+h)*SS+s][192] pre-scaled+roped
    const ushort* __restrict__ kvb,  // [tok][HH*KVD]
    const ushort* __restrict__ krb,  // [tok][64]
    const ushort* __restrict__ Vt,   // [(b*HH+h)*DV+dv][SS]
    ushort* __restrict__ o)          // [tok][HH*DV]
{
    const int h  = blockIdx.y;
    const int b  = blockIdx.z;
    const int qt = b ? (15 - (int)blockIdx.x) : (int)blockIdx.x;
    const int bh = b * HH + h;
    const int q0 = qt * 128;
    const int t    = threadIdx.x;
    const int lane = t & 63;
    const int wave = t >> 6;
    const int quad = lane >> 4;
    const int n    = lane & 15;
    const int wstrip = wave * 16;

    __shared__ ushort Ksu[6 * 64 * 32];   // 24 KB
    __shared__ ushort Vtu[2 * 128 * 32];  // 16 KB
    __shared__ ushort Psu[2 * 128 * 40];  // 20 KB (padded rows)

    const ushort* vbase = Vt + (size_t)bh * DV * SS;

    // preload Q A-frags for both strips
    bfrag aQ[2][6];
    #pragma unroll
    for (int sp = 0; sp < 2; ++sp) {
        const ushort* qrow = Qb + ((size_t)bh * SS + q0 + sp * 64 + wstrip + n) * DQ;
        #pragma unroll
        for (int kb = 0; kb < 6; ++kb)
            aQ[sp][kb] = *(const bfrag*)(qrow + kb * 32 + quad * 8);
    }

    facc oacc[2][8];
    float lp[2][4];
    #pragma unroll
    for (int sp = 0; sp < 2; ++sp) {
        #pragma unroll
        for (int jd = 0; jd < 8; ++jd) oacc[sp][jd] = (facc)(0.f);
        #pragma unroll
        for (int r = 0; r < 4; ++r) lp[sp][r] = 0.f;
    }

    const int nkt = 2 * qt + 2;
    for (int kt = 0; kt < nkt; ++kt) {
        const int k0 = kt * 64;

        // stage K tile: kb 0..3 from kv_bf, kb 4..5 from krb
        #pragma unroll
        for (int i = 0; i < 6; ++i) {
            const int g = wave + 4 * i;
            const int kb = g >> 2;                    // wave-uniform
            const int rem = (g & 3) * 64 + lane;
            const int row = rem >> 2, sub = rem & 3;
            const int tok = b * SS + k0 + row;
            const ushort* src = (kb < 4)
                ? kvb + (size_t)tok * (HH * KVD) + h * KVD + kb * 32 + sub * 8
                : krb + (size_t)tok * DR + (kb - 4) * 32 + sub * 8;
            gl2lds16(src, Ksu + g * 512);
        }
        // stage Vt tile
        #pragma unroll
        for (int i = 0; i < 4; ++i) {
            const int g = wave + 4 * i;
            const int kb2 = g >> 3;                   // wave-uniform
            const int rem = (g & 7) * 64 + lane;
            const int dv = rem >> 2, sub = rem & 3;
            gl2lds16(vbase + (size_t)dv * SS + k0 + kb2 * 32 + sub * 8,
                     Vtu + g * 512);
        }
        __syncthreads();

        // S = Q K^T, both strips share each K frag
        facc s[2][4];
        #pragma unroll
        for (int sp = 0; sp < 2; ++sp)
            #pragma unroll
            for (int j = 0; j < 4; ++j) s[sp][j] = (facc)(0.f);
        #pragma unroll
        for (int kb = 0; kb < 6; ++kb) {
            #pragma unroll
            for (int j = 0; j < 4; ++j) {
                const bfrag bk =
                    *(const bfrag*)&Ksu[kb * 2048 + (j * 16 + n) * 32 + quad * 8];
                s[0][j] = __builtin_amdgcn_mfma_f32_16x16x32_bf16(aQ[0][kb], bk, s[0][j], 0, 0, 0);
                s[1][j] = __builtin_amdgcn_mfma_f32_16x16x32_bf16(aQ[1][kb], bk, s[1][j], 0, 0, 0);
            }
        }

        // exp (m=0) + causal select; P -> LDS (wave-private rows)
        #pragma unroll
        for (int sp = 0; sp < 2; ++sp) {
            const int rowg0 = q0 + sp * 64 + wstrip + quad * 4;
            #pragma unroll
            for (int j = 0; j < 4; ++j) {
                const int kpos = k0 + j * 16 + n;
                #pragma unroll
                for (int r = 0; r < 4; ++r) {
                    float p = (kpos <= rowg0 + r) ? __expf(s[sp][j][r]) : 0.f;
                    lp[sp][r] += p;
                    Psu[(j >> 1) * 5120 + (sp * 64 + wstrip + quad * 4 + r) * 40
                        + (j & 1) * 16 + n] = f2bf(p);
                }
            }
        }

        // O += P @ V; V frags shared across strips
        #pragma unroll
        for (int kb2 = 0; kb2 < 2; ++kb2) {
            const bfrag aP0 = *(const bfrag*)&Psu[kb2 * 5120 + (wstrip + n) * 40 + quad * 8];
            const bfrag aP1 = *(const bfrag*)&Psu[kb2 * 5120 + (64 + wstrip + n) * 40 + quad * 8];
            #pragma unroll
            for (int jd = 0; jd < 8; ++jd) {
                const bfrag bV = *(const bfrag*)&Vtu[kb2 * 4096 + (jd * 16 + n) * 32 + quad * 8];
                oacc[0][jd] = __builtin_amdgcn_mfma_f32_16x16x32_bf16(aP0, bV, oacc[0][jd], 0, 0, 0);
                oacc[1][jd] = __builtin_amdgcn_mfma_f32_16x16x32_bf16(aP1, bV, oacc[1][jd], 0, 0, 0);
            }
        }
        __syncthreads();   // LDS reads drained before next stage overwrites
    }

    // reduce l partials, epilogue
    #pragma unroll
    for (int sp = 0; sp < 2; ++sp) {
        #pragma unroll
        for (int r = 0; r < 4; ++r) {
            float v = lp[sp][r];
            #pragma unroll
            for (int msk = 1; msk < 16; msk <<= 1) v += __shfl_xor(v, msk);
            const float inv = 1.f / v;
            ushort* op = o + (size_t)(b * SS + q0 + sp * 64 + wstrip + quad * 4 + r)
                             * (HH * DV) + h * DV;
            #pragma unroll
            for (int jd = 0; jd < 8; ++jd)
                op[jd * 16 + n] = f2bf(oacc[sp][jd][r] * inv);
        }
    }
}

// ---------------- launch ----------------
extern "C" void kernel_launch(void* const* d_in, const int* in_sizes, int n_in,
                              void* d_out, int out_size, void* d_ws, size_t ws_size,
                              hipStream_t stream) {
    const float* hs    = (const float*)d_in[0];
    const float* cosb  = (const float*)d_in[1];
    const float* sinb  = (const float*)d_in[2];
    const float* Wqa   = (const float*)d_in[3];
    const float* qa_w  = (const float*)d_in[4];
    const float* Wqb   = (const float*)d_in[5];
    const float* Wkva  = (const float*)d_in[6];
    const float* kva_w = (const float*)d_in[7];
    const float* Wkvb  = (const float*)d_in[8];
    const float* Wo    = (const float*)d_in[9];
    float* out = (float*)d_out;

    const int T = BB * SS; // 4096 tokens

    char* w = (char*)d_ws;
    auto alloc = [&](size_t bytes) {
        void* r = (void*)w;
        w += (bytes + 255) & ~(size_t)255;
        return r;
    };
    ushort* hs_bf  = (ushort*)alloc((size_t)T * DD * 2);            // 16.8 MB
    ushort* Wcat   = (ushort*)alloc((size_t)NCATP * DD * 2);        //  9.4 (pad rows 2176..2303 read-but-discarded)
    ushort* Wqbt   = (ushort*)alloc((size_t)(HH * DQ) * QL * 2);    //  9.4
    ushort* Wkvbt  = (ushort*)alloc((size_t)(HH * KVD) * KVL * 2);  //  4.2
    ushort* Wot    = (ushort*)alloc((size_t)DD * DD * 2);           //  8.4
    ushort* qa_bf  = (ushort*)alloc((size_t)T * QL * 2);            // 12.6
    ushort* Qbuf   = (ushort*)alloc((size_t)T * HH * DQ * 2);       // 25.2
    ushort* ckv_bf = (ushort*)alloc((size_t)T * CKVS * 2);          //  5.2
    ushort* kvn_bf = (ushort*)alloc((size_t)T * KVL * 2);           //  4.2
    ushort* kv_bf  = (ushort*)alloc((size_t)T * HH * KVD * 2);      // 33.6
    ushort* krb    = (ushort*)alloc((size_t)T * DR * 2);            //  0.5
    // aliases (lifetimes verified):
    ushort* Vtb    = Wcat;   // 16.8 MB over Wcat+Wqbt (dead after gemmA/gemmQ)
    ushort* ao_bf  = hs_bf;  // hs_bf dead after gemmA

    // 0. cast hs; all 5 weight transposes in ONE batched launch
    castf2bf<<<(T * DD / 4) / 256, 256, 0, stream>>>(hs, hs_bf);
    WtBatch wb;
    wb.src[0] = Wqa;  wb.dst[0] = Wcat;                      wb.K[0] = DD;  wb.N[0] = QL;       wb.nx[0] = 48;
    wb.src[1] = Wkva; wb.dst[1] = Wcat + (size_t)QL * DD;    wb.K[1] = DD;  wb.N[1] = KVL + DR; wb.nx[1] = 20;
    wb.src[2] = Wqb;  wb.dst[2] = Wqbt;                      wb.K[2] = QL;  wb.N[2] = HH * DQ;  wb.nx[2] = 96;
    wb.src[3] = Wkvb; wb.dst[3] = Wkvbt;                     wb.K[3] = KVL; wb.N[3] = HH * KVD; wb.nx[3] = 128;
    wb.src[4] = Wo;   wb.dst[4] = Wot;                       wb.K[4] = DD;  wb.N[4] = DD;       wb.nx[4] = 64;
    wb.base[0] = 0;
    wb.base[1] = wb.base[0] + wb.nx[0] * (DD / 32);   // 3072
    wb.base[2] = wb.base[1] + wb.nx[1] * (DD / 32);   // 4352
    wb.base[3] = wb.base[2] + wb.nx[2] * (QL / 32);   // 8960
    wb.base[4] = wb.base[3] + wb.nx[3] * (KVL / 32);  // 11008
    wb.base[5] = wb.base[4] + wb.nx[4] * (DD / 32);   // 15104
    wtrans_b<<<wb.base[5], 256, 0, stream>>>(wb);

    // 1. fused: qa | ckv = hs @ [Wqa | Wkva]  (256-tile, N padded to 2304)
    gemmA256<<<dim3(9 * 16), 512, 0, stream>>>(hs_bf, Wcat, qa_bf, ckv_bf);
    // 2. rmsnorm qa in place
    rmsnorm_bf_ip<<<T, 256, 0, stream>>>(qa_bf, qa_w, QL);
    // 3. Q = qa @ Wqb -> Qbuf layout, scale folded
    gemmQ256<<<dim3(12 * 16), 512, 0, stream>>>(qa_bf, Wqbt, Qbuf);
    // 4. rope Q in place (rope lanes only)
    qrope<<<T, 256, 0, stream>>>(Qbuf, cosb, sinb);
    // 5. kvn = rmsnorm(ckv[:, :512]) + roped k_rot -> krb (fused)
    rmsnorm_kv<<<T, 256, 0, stream>>>(ckv_bf, kva_w, kvn_bf, krb, cosb, sinb);
    // 6. kv = kvn @ Wkvb (bf16)
    gemm256<ushort, KVL, 16, HH * KVD><<<dim3(16 * 16), 512, 0, stream>>>(kvn_bf, Wkvbt, kv_bf);
    // 7. V transpose -> Vt
    vprep<<<dim3(SS / 32, DV / 32, BB * HH), 256, 0, stream>>>(kv_bf, Vtb);
    // 8. MFMA flash attention (q-tile 128, uniform pairing) -> ao (bf16)
    fattn_mfma<<<dim3(16, HH, BB), 256, 0, stream>>>(Qbuf, kv_bf, krb, Vtb, ao_bf);
    // 9. out = ao @ Wo (fp32)
    gemm256<float, DD, 8, DD><<<dim3(8 * 16), 512, 0, stream>>>(ao_bf, Wot, out);
}

// Round 3
// 448.980 us; speedup vs baseline: 1.0782x; 1.0053x over previous
//
#include <hip/hip_runtime.h>
#include <math.h>

#define BB 2
#define SS 2048
#define DD 2048
#define HH 16
#define DN 128
#define DR 64
#define DV 128
#define QL 1536
#define KVL 512
#define DQ 192           // DN + DR
#define CKVS 640         // ckv row stride (576 padded to 640)
#define KVD 256          // DN + DV
#define NCAT 2176        // QL + CKVS (fused first GEMM)
#define NCATP 2304       // NCAT padded to 9*256 for the 256-wide GEMM tile
#define EPSF 1e-6f

typedef short bfrag __attribute__((ext_vector_type(8)));   // 8 bf16 (4 VGPRs)
typedef float facc  __attribute__((ext_vector_type(4)));   // 4 fp32 acc

// ---------------- helpers ----------------
__device__ __forceinline__ ushort f2bf(float f) {
    union { float f; unsigned u; } v; v.f = f;
    unsigned r = v.u + 0x7fffu + ((v.u >> 16) & 1u);  // RNE
    return (ushort)(r >> 16);
}
__device__ __forceinline__ float bf2f(ushort u) {
    union { unsigned u; float f; } v; v.u = ((unsigned)u) << 16;
    return v.f;
}
__device__ __forceinline__ float wave_red_sum(float v) {
    #pragma unroll
    for (int o = 32; o > 0; o >>= 1) v += __shfl_down(v, o);
    return v;
}
__device__ __forceinline__ void gl2lds16(const ushort* g, ushort* l) {
    __builtin_amdgcn_global_load_lds(
        (const __attribute__((address_space(1))) void*)g,
        (__attribute__((address_space(3))) void*)l, 16, 0, 0);
}
__device__ __forceinline__ void storeC(float* c, float v)  { *c = v; }
__device__ __forceinline__ void storeC(ushort* c, float v) { *c = f2bf(v); }

// ---------------- fp32 -> bf16 cast (vectorized) ----------------
__global__ __launch_bounds__(256) void castf2bf(const float* __restrict__ x,
                                                ushort* __restrict__ y) {
    const int i = blockIdx.x * 256 + threadIdx.x;
    const float4 v = ((const float4*)x)[i];
    ushort4 o;
    o.x = f2bf(v.x); o.y = f2bf(v.y); o.z = f2bf(v.z); o.w = f2bf(v.w);
    ((ushort4*)y)[i] = o;
}

// ------- batched weight cast+transpose: 5 segments in one launch ----------
struct WtBatch {
    const float* src[5];
    ushort* dst[5];
    int K[5];
    int N[5];
    int nx[5];
    int base[6];
};
__global__ __launch_bounds__(256) void wtrans_b(WtBatch d) {
    __shared__ float tile[32][33];
    int bid = blockIdx.x;
    int seg = 0;
    while (bid >= d.base[seg + 1]) ++seg;
    const int l = bid - d.base[seg];
    const int nx = d.nx[seg];
    const int bx = l % nx, by = l / nx;
    const float* W = d.src[seg];
    ushort* Wt = d.dst[seg];
    const int K = d.K[seg], N = d.N[seg];
    const int k0 = by * 32, n0 = bx * 32;
    const int t = threadIdx.x;
    const int tx = t & 31, ty = t >> 5;
    #pragma unroll
    for (int r = 0; r < 4; ++r) {
        const int n = n0 + tx;
        tile[ty + r * 8][tx] =
            (n < N) ? W[(size_t)(k0 + ty + r * 8) * N + n] : 0.f;
    }
    __syncthreads();
    #pragma unroll
    for (int r = 0; r < 4; ++r) {
        const int n = n0 + ty + r * 8;
        Wt[(size_t)n * K + k0 + tx] = f2bf(tile[tx][ty + r * 8]);
    }
}

// ================== 256x256 8-phase MFMA GEMM (m201 template) ==============
// 512 threads = 8 waves (2M x 4N), per-wave C = 128x64, BK=64, dbuf LDS 128KB
// (static __shared__).
// LDS regions (ushort offsets): REGOFF(buf,ab,half) = buf*32768 + ab*16384 +
// half*8192, half = 128 rows x 64 cols bf16 (16KB).
// T2 swizzle: logical 16B slot s of row r lives at physical slot s^(r&7);
// gl2lds writes linearly, so the GLOBAL source is pre-swizzled and ds_read
// applies the same XOR (involution).  Per-phase: {ds_read frags | stage 1-2
// half-tiles | (vmcnt at q4) | barrier | lgkmcnt(0) | 16 MFMA | barrier}.
// Stage schedule (K-tile kt, buf p=kt&1): q1: A-h0(kt+1)->p^1, q2: A-h1(kt+1),
// q4: B-h0+B-h1(kt+2)->p with vmcnt(4).  Every overwrite is >=1 barrier-pair
// after the last read of that region; reads of kt+1 are behind q4's vmcnt.

__device__ __forceinline__ void stage_half(const ushort* __restrict__ G,
                                           int ldg, int grow0, int kcol0,
                                           ushort* Lr, int wave, int lane) {
    const int r0   = lane >> 3;
    const int slot = (lane & 7) ^ r0;          // inverse-swizzled global slot
    const ushort* s0 = G + (size_t)(grow0 + wave * 16 + r0) * ldg + kcol0 + slot * 8;
    gl2lds16(s0,                    Lr + wave * 1024);        // rows w*16..+8
    gl2lds16(s0 + (size_t)8 * ldg,  Lr + wave * 1024 + 512);  // rows +8..+16
}

#define PH_PRE  do { __builtin_amdgcn_sched_barrier(0);                      \
                     __builtin_amdgcn_s_barrier();                           \
                     asm volatile("s_waitcnt lgkmcnt(0)" ::: "memory");      \
                     __builtin_amdgcn_sched_barrier(0);                      \
                     __builtin_amdgcn_s_setprio(1); } while (0)
#define PH_POST do { __builtin_amdgcn_s_setprio(0);                          \
                     __builtin_amdgcn_sched_barrier(0);                      \
                     __builtin_amdgcn_s_barrier(); } while (0)

#define MFMA16(RB)                                                           \
    _Pragma("unroll")                                                        \
    for (int i = 0; i < 4; ++i)                                              \
        _Pragma("unroll")                                                    \
        for (int j = 0; j < 4; ++j)                                          \
            acc[(RB) + i][j] = __builtin_amdgcn_mfma_f32_16x16x32_bf16(      \
                a[i], b[j], acc[(RB) + i][j], 0, 0, 0);

#define GEMM256_CORE(A_, Bt_, K_, NBX_)                                       \
    __shared__ ushort L[65536]; /* 128 KiB static */                          \
    const int t    = threadIdx.x;                                             \
    const int lane = t & 63;                                                  \
    const int wave = t >> 6;                                                  \
    const int wm   = wave >> 2;                                               \
    const int wn   = wave & 3;                                                \
    const int quad = lane >> 4;                                               \
    const int lrow = lane & 15;                                               \
    int wg = (int)blockIdx.x;                                                 \
    { const int cpx = (int)gridDim.x >> 3; wg = (wg & 7) * cpx + (wg >> 3); } \
    const int bx = wg % (NBX_), by = wg / (NBX_);                             \
    const int m0 = by * 256, n0 = bx * 256;                                   \
    const int s0x8  = (quad ^ (lrow & 7)) * 8;   /* swizzled slot, kh=0 */    \
    const int s1x8  = s0x8 ^ 32;                 /* kh=1: slot^4          */  \
    const int abase = lrow * 64;                                              \
    const int bbase = (wn & 1) * 4096 + lrow * 64;                            \
    facc acc[8][4];                                                           \
    _Pragma("unroll")                                                         \
    for (int i = 0; i < 8; ++i)                                               \
        _Pragma("unroll")                                                     \
        for (int j = 0; j < 4; ++j) acc[i][j] = (facc)(0.f);                  \
    const int nk = (K_) >> 6;                                                 \
    /* prologue: K0 all 4 halves -> buf0; K1 B halves -> buf1 */              \
    stage_half((A_),  (K_), m0,        0, L,         wave, lane);             \
    stage_half((A_),  (K_), m0 + 128,  0, L + 8192,  wave, lane);             \
    stage_half((Bt_), (K_), n0,        0, L + 16384, wave, lane);             \
    stage_half((Bt_), (K_), n0 + 128,  0, L + 24576, wave, lane);             \
    stage_half((Bt_), (K_), n0,       64, L + 49152, wave, lane);             \
    stage_half((Bt_), (K_), n0 + 128, 64, L + 57344, wave, lane);             \
    asm volatile("s_waitcnt vmcnt(4)" ::: "memory");                          \
    __builtin_amdgcn_s_barrier();                                             \
    for (int kt = 0; kt < nk; ++kt) {                                         \
        const int p = kt & 1;                                                 \
        ushort* LA = L + p * 32768 + wm * 8192;                               \
        ushort* LB = L + p * 32768 + 16384 + (wn >> 1) * 8192;                \
        ushort* Lq = L + (p ^ 1) * 32768;                                     \
        const int kn = (kt + 1) * 64;                                         \
        bfrag a[4], b[4];                                                     \
        /* ---- q1: frags m0-3, kh0 ---- */                                   \
        _Pragma("unroll")                                                     \
        for (int i = 0; i < 4; ++i)                                           \
            a[i] = *(const bfrag*)(LA + i * 1024 + abase + s0x8);             \
        _Pragma("unroll")                                                     \
        for (int j = 0; j < 4; ++j)                                           \
            b[j] = *(const bfrag*)(LB + bbase + j * 1024 + s0x8);             \
        if (kt + 1 < nk) stage_half((A_), (K_), m0, kn, Lq, wave, lane);      \
        PH_PRE;                                                               \
        MFMA16(0)                                                             \
        PH_POST;                                                              \
        /* ---- q2: frags m4-7, kh0 (b reused) ---- */                        \
        _Pragma("unroll")                                                     \
        for (int i = 0; i < 4; ++i)                                           \
            a[i] = *(const bfrag*)(LA + (4 + i) * 1024 + abase + s0x8);       \
        if (kt + 1 < nk)                                                      \
            stage_half((A_), (K_), m0 + 128, kn, Lq + 8192, wave, lane);      \
        PH_PRE;                                                               \
        MFMA16(4)                                                             \
        PH_POST;                                                              \
        /* ---- q3: frags m0-3, kh1 ---- */                                   \
        _Pragma("unroll")                                                     \
        for (int i = 0; i < 4; ++i)                                           \
            a[i] = *(const bfrag*)(LA + i * 1024 + abase + s1x8);             \
        _Pragma("unroll")                                                     \
        for (int j = 0; j < 4; ++j)                                           \
            b[j] = *(const bfrag*)(LB + bbase + j * 1024 + s1x8);             \
        PH_PRE;                                                               \
        MFMA16(0)                                                             \
        PH_POST;                                                              \
        /* ---- q4: frags m4-7, kh1; stage B(kt+2); counted vmcnt ---- */     \
        _Pragma("unroll")                                                     \
        for (int i = 0; i < 4; ++i)                                           \
            a[i] = *(const bfrag*)(LA + (4 + i) * 1024 + abase + s1x8);       \
        if (kt + 2 < nk) {                                                    \
            stage_half((Bt_), (K_), n0,       kn + 64,                        \
                       L + p * 32768 + 16384, wave, lane);                    \
            stage_half((Bt_), (K_), n0 + 128, kn + 64,                        \
                       L + p * 32768 + 24576, wave, lane);                    \
            asm volatile("s_waitcnt vmcnt(4)" ::: "memory");                  \
        } else {                                                              \
            asm volatile("s_waitcnt vmcnt(0)" ::: "memory");                  \
        }                                                                     \
        PH_PRE;                                                               \
        MFMA16(4)                                                             \
        PH_POST;                                                              \
    }

// ---------------- generic 256-tile GEMM, row-major C ----------------
template <typename OUT, int K, int NBX, int NOUT>
__global__ __launch_bounds__(512, 2) void gemm256(const ushort* __restrict__ A,
                                                  const ushort* __restrict__ Bt,
                                                  OUT* __restrict__ C) {
    GEMM256_CORE(A, Bt, K, NBX)
    #pragma unroll
    for (int m = 0; m < 8; ++m) {
        const int row = m0 + wm * 128 + m * 16 + quad * 4;
        #pragma unroll
        for (int nf = 0; nf < 4; ++nf) {
            const int col = n0 + wn * 64 + nf * 16 + lrow;
            #pragma unroll
            for (int r = 0; r < 4; ++r)
                storeC(&C[(size_t)(row + r) * NOUT + col], acc[m][nf][r]);
        }
    }
}

// -------- fused GEMM A: hs @ [Wqa | Wkva] -> qa_bf, ckv_bf (N pad 2304) -----
__global__ __launch_bounds__(512, 2) void gemmA256(const ushort* __restrict__ A,
                                                   const ushort* __restrict__ Bt,
                                                   ushort* __restrict__ qa,
                                                   ushort* __restrict__ ckv) {
    GEMM256_CORE(A, Bt, DD, 9)
    #pragma unroll
    for (int m = 0; m < 8; ++m) {
        const int row = m0 + wm * 128 + m * 16 + quad * 4;
        #pragma unroll
        for (int nf = 0; nf < 4; ++nf) {
            const int col = n0 + wn * 64 + nf * 16 + lrow;
            #pragma unroll
            for (int r = 0; r < 4; ++r) {
                if (col < QL)
                    qa[(size_t)(row + r) * QL + col] = f2bf(acc[m][nf][r]);
                else if (col < NCAT)
                    ckv[(size_t)(row + r) * CKVS + col - QL] = f2bf(acc[m][nf][r]);
            }
        }
    }
}

// -------- GEMM Q: qa @ Wqb -> Qbuf[(b*HH+h)*SS+s][192], scale folded -------
__global__ __launch_bounds__(512, 2) void gemmQ256(const ushort* __restrict__ A,
                                                   const ushort* __restrict__ Bt,
                                                   ushort* __restrict__ Qbuf) {
    GEMM256_CORE(A, Bt, QL, 12)
    const float scaling = 0.07216878364870323f; // 192^-0.5
    #pragma unroll
    for (int m = 0; m < 8; ++m) {
        const int row = m0 + wm * 128 + m * 16 + quad * 4;
        #pragma unroll
        for (int nf = 0; nf < 4; ++nf) {
            const int col = n0 + wn * 64 + nf * 16 + lrow;
            const int h = col / DQ, d = col - h * DQ;
            #pragma unroll
            for (int r = 0; r < 4; ++r) {
                const int tok = row + r;
                const int b = tok >> 11, s = tok & (SS - 1);
                Qbuf[((size_t)(b * HH + h) * SS + s) * DQ + d] =
                    f2bf(acc[m][nf][r] * scaling);
            }
        }
    }
}

// ---------------- RMSNorm bf16 in-place ----------------
__global__ __launch_bounds__(256) void rmsnorm_bf_ip(ushort* __restrict__ x,
                                                     const float* __restrict__ w,
                                                     int n) {
    ushort* xr = x + (size_t)blockIdx.x * n;
    const int t = threadIdx.x;
    float ss = 0.f;
    for (int i = t; i < n; i += 256) { float v = bf2f(xr[i]); ss += v * v; }
    ss = wave_red_sum(ss);
    __shared__ float red[4];
    const int lane = t & 63, wid = t >> 6;
    if (lane == 0) red[wid] = ss;
    __syncthreads();
    const float tot = red[0] + red[1] + red[2] + red[3];
    const float scale = rsqrtf(tot / (float)n + EPSF);
    for (int i = t; i < n; i += 256) xr[i] = f2bf(w[i] * bf2f(xr[i]) * scale);
}

// ------- kv RMSNorm (ckv[:, :512] -> kvn) fused with roped k_rot -> krb -----
__global__ __launch_bounds__(256) void rmsnorm_kv(const ushort* __restrict__ x,
                                                  const float* __restrict__ w,
                                                  ushort* __restrict__ y,
                                                  ushort* __restrict__ krb,
                                                  const float* __restrict__ cosb,
                                                  const float* __restrict__ sinb) {
    const int row = blockIdx.x;
    const ushort* xr = x + (size_t)row * CKVS;
    ushort* yr = y + (size_t)row * KVL;
    const int t = threadIdx.x;
    if (t < 64) {   // k_rot rope (independent of the norm)
        const int p = t;
        const ushort* kin = xr + KVL;
        const float c  = cosb[(size_t)row * DR + p];
        const float sn = sinb[(size_t)row * DR + p];
        const float self = bf2f(kin[p]);
        const float partner = bf2f(kin[p < 32 ? p + 32 : p - 32]);
        const float v = (p < 32) ? (self * c - partner * sn)
                                 : (self * c + partner * sn);
        krb[(size_t)row * DR + p] = f2bf(v);
    }
    float ss = 0.f;
    for (int i = t; i < KVL; i += 256) { float v = bf2f(xr[i]); ss += v * v; }
    ss = wave_red_sum(ss);
    __shared__ float red[4];
    const int lane = t & 63, wid = t >> 6;
    if (lane == 0) red[wid] = ss;
    __syncthreads();
    const float tot = red[0] + red[1] + red[2] + red[3];
    const float scale = rsqrtf(tot / (float)KVL + EPSF);
    for (int i = t; i < KVL; i += 256) yr[i] = f2bf(w[i] * bf2f(xr[i]) * scale);
}

// ---------------- qrope: in-place rope on Qbuf rope lanes ----------------
__global__ __launch_bounds__(256) void qrope(ushort* __restrict__ Qbuf,
                                             const float* __restrict__ cosb,
                                             const float* __restrict__ sinb) {
    const int tok = blockIdx.x;
    const int b = tok >> 11, s = tok & (SS - 1);
    const int t = threadIdx.x;
    const int p = t & 31, hh = t >> 5;
    const float c0 = cosb[(size_t)tok * DR + p];
    const float s0 = sinb[(size_t)tok * DR + p];
    const float c1 = cosb[(size_t)tok * DR + p + 32];
    const float s1 = sinb[(size_t)tok * DR + p + 32];
    #pragma unroll
    for (int it = 0; it < 2; ++it) {
        const int h = hh + it * 8;
        ushort* base = Qbuf + ((size_t)(b * HH + h) * SS + s) * DQ + DN;
        const float x0 = bf2f(base[p]), x1 = bf2f(base[p + 32]);
        base[p]      = f2bf(x0 * c0 - x1 * s0);
        base[p + 32] = f2bf(x1 * c1 + x0 * s1);
    }
}

// ---------------- vprep: transpose V -> Vt[bh][dv][SS] bf16 ----------------
__global__ __launch_bounds__(256) void vprep(const ushort* __restrict__ kv_bf,
                                             ushort* __restrict__ Vtb) {
    __shared__ ushort tile[32][33];
    const int kp0 = blockIdx.x * 32, dv0 = blockIdx.y * 32, bh = blockIdx.z;
    const int b = bh / HH, h = bh - b * HH;
    const int t = threadIdx.x, tx = t & 31, ty = t >> 5;
    #pragma unroll
    for (int r = 0; r < 4; ++r)
        tile[ty + r * 8][tx] =
            kv_bf[(size_t)(b * SS + kp0 + ty + r * 8) * (HH * KVD) + h * KVD + DN + dv0 + tx];
    __syncthreads();
    #pragma unroll
    for (int r = 0; r < 4; ++r)
        Vtb[((size_t)bh * DV + dv0 + ty + r * 8) * SS + kp0 + tx] = tile[tx][ty + r * 8];
}

// ---------------- MFMA flash attention, q-tile 128, uniform pairing -------
// v2: T14 async-STAGE — next K/V tile is prefetched into REGISTERS at the
// top of iteration kt (global_load_dwordx4, no wait); the post-PV barrier's
// implicit vmcnt(0) lands after ~2000cy of compute, hiding HBM/L2 latency;
// ds_write_b128 (wave-linear, conflict-free) then refills Ksu/Vtu.
// Barrier count per kt unchanged (2).  Block-uniform `fullt` branch skips
// the causal compare on the 2*qt fully-visible tiles.
__global__ __launch_bounds__(256, 2) void fattn_mfma(
    const ushort* __restrict__ Qb,   // [(b*HH+h)*SS+s][192] pre-scaled+roped
    const ushort* __restrict__ kvb,  // [tok][HH*KVD]
    const ushort* __restrict__ krb,  // [tok][64]
    const ushort* __restrict__ Vt,   // [(b*HH+h)*DV+dv][SS]
    ushort* __restrict__ o)          // [tok][HH*DV]
{
    const int h  = blockIdx.y;
    const int b  = blockIdx.z;
    const int qt = b ? (15 - (int)blockIdx.x) : (int)blockIdx.x;
    const int bh = b * HH + h;
    const int q0 = qt * 128;
    const int t    = threadIdx.x;
    const int lane = t & 63;
    const int wave = t >> 6;
    const int quad = lane >> 4;
    const int n    = lane & 15;
    const int wstrip = wave * 16;

    __shared__ ushort Ksu[6 * 64 * 32];   // 24 KB
    __shared__ ushort Vtu[2 * 128 * 32];  // 16 KB
    __shared__ ushort Psu[2 * 128 * 40];  // 20 KB (padded rows)

    const ushort* vbase = Vt + (size_t)bh * DV * SS;

    // preload Q A-frags for both strips
    bfrag aQ[2][6];
    #pragma unroll
    for (int sp = 0; sp < 2; ++sp) {
        const ushort* qrow = Qb + ((size_t)bh * SS + q0 + sp * 64 + wstrip + n) * DQ;
        #pragma unroll
        for (int kb = 0; kb < 6; ++kb)
            aQ[sp][kb] = *(const bfrag*)(qrow + kb * 32 + quad * 8);
    }

    facc oacc[2][8];
    float lp[2][4];
    #pragma unroll
    for (int sp = 0; sp < 2; ++sp) {
        #pragma unroll
        for (int jd = 0; jd < 8; ++jd) oacc[sp][jd] = (facc)(0.f);
        #pragma unroll
        for (int r = 0; r < 4; ++r) lp[sp][r] = 0.f;
    }

    // prologue: stage tile kt=0 via global_load_lds (full drain is fine once)
    #pragma unroll
    for (int i = 0; i < 6; ++i) {
        const int g = wave + 4 * i;
        const int kb = g >> 2;                    // wave-uniform
        const int rem = (g & 3) * 64 + lane;
        const int row = rem >> 2, sub = rem & 3;
        const int tok = b * SS + row;
        const ushort* src = (kb < 4)
            ? kvb + (size_t)tok * (HH * KVD) + h * KVD + kb * 32 + sub * 8
            : krb + (size_t)tok * DR + (kb - 4) * 32 + sub * 8;
        gl2lds16(src, Ksu + g * 512);
    }
    #pragma unroll
    for (int i = 0; i < 4; ++i) {
        const int g = wave + 4 * i;
        const int kb2 = g >> 3;                   // wave-uniform
        const int rem = (g & 7) * 64 + lane;
        const int dv = rem >> 2, sub = rem & 3;
        gl2lds16(vbase + (size_t)dv * SS + kb2 * 32 + sub * 8, Vtu + g * 512);
    }
    __syncthreads();

    const int nkt = 2 * qt + 2;
    for (int kt = 0; kt < nkt; ++kt) {
        const int k0 = kt * 64;
        const int k1 = k0 + 64;
        const bool more = (kt + 1 < nkt);

        // ---- issue next-tile global loads into registers (no wait) ----
        bfrag kreg[6], vreg[4];
        if (more) {
            #pragma unroll
            for (int i = 0; i < 6; ++i) {
                const int g = wave + 4 * i;
                const int kb = g >> 2;
                const int rem = (g & 3) * 64 + lane;
                const int row = rem >> 2, sub = rem & 3;
                const int tok = b * SS + k1 + row;
                const ushort* src = (kb < 4)
                    ? kvb + (size_t)tok * (HH * KVD) + h * KVD + kb * 32 + sub * 8
                    : krb + (size_t)tok * DR + (kb - 4) * 32 + sub * 8;
                kreg[i] = *(const bfrag*)src;
            }
            #pragma unroll
            for (int i = 0; i < 4; ++i) {
                const int g = wave + 4 * i;
                const int kb2 = g >> 3;
                const int rem = (g & 7) * 64 + lane;
                const int dv = rem >> 2, sub = rem & 3;
                vreg[i] = *(const bfrag*)(vbase + (size_t)dv * SS + k1 + kb2 * 32 + sub * 8);
            }
        }

        // ---- S = Q K^T, both strips share each K frag ----
        facc s[2][4];
        #pragma unroll
        for (int sp = 0; sp < 2; ++sp)
            #pragma unroll
            for (int j = 0; j < 4; ++j) s[sp][j] = (facc)(0.f);
        #pragma unroll
        for (int kb = 0; kb < 6; ++kb) {
            #pragma unroll
            for (int j = 0; j < 4; ++j) {
                const bfrag bk =
                    *(const bfrag*)&Ksu[kb * 2048 + (j * 16 + n) * 32 + quad * 8];
                s[0][j] = __builtin_amdgcn_mfma_f32_16x16x32_bf16(aQ[0][kb], bk, s[0][j], 0, 0, 0);
                s[1][j] = __builtin_amdgcn_mfma_f32_16x16x32_bf16(aQ[1][kb], bk, s[1][j], 0, 0, 0);
            }
        }

        // ---- exp (m=0) + causal select; P -> LDS (wave-private rows) ----
        const bool fullt = (k1 <= q0);   // tile entirely below the diagonal
        if (fullt) {
            #pragma unroll
            for (int sp = 0; sp < 2; ++sp) {
                #pragma unroll
                for (int j = 0; j < 4; ++j) {
                    #pragma unroll
                    for (int r = 0; r < 4; ++r) {
                        const float p = __expf(s[sp][j][r]);
                        lp[sp][r] += p;
                        Psu[(j >> 1) * 5120 + (sp * 64 + wstrip + quad * 4 + r) * 40
                            + (j & 1) * 16 + n] = f2bf(p);
                    }
                }
            }
        } else {
            #pragma unroll
            for (int sp = 0; sp < 2; ++sp) {
                const int rowg0 = q0 + sp * 64 + wstrip + quad * 4;
                #pragma unroll
                for (int j = 0; j < 4; ++j) {
                    const int kpos = k0 + j * 16 + n;
                    #pragma unroll
                    for (int r = 0; r < 4; ++r) {
                        const float p = (kpos <= rowg0 + r) ? __expf(s[sp][j][r]) : 0.f;
                        lp[sp][r] += p;
                        Psu[(j >> 1) * 5120 + (sp * 64 + wstrip + quad * 4 + r) * 40
                            + (j & 1) * 16 + n] = f2bf(p);
                    }
                }
            }
        }

        // ---- O += P @ V; V frags shared across strips ----
        #pragma unroll
        for (int kb2 = 0; kb2 < 2; ++kb2) {
            const bfrag aP0 = *(const bfrag*)&Psu[kb2 * 5120 + (wstrip + n) * 40 + quad * 8];
            const bfrag aP1 = *(const bfrag*)&Psu[kb2 * 5120 + (64 + wstrip + n) * 40 + quad * 8];
            #pragma unroll
            for (int jd = 0; jd < 8; ++jd) {
                const bfrag bV = *(const bfrag*)&Vtu[kb2 * 4096 + (jd * 16 + n) * 32 + quad * 8];
                oacc[0][jd] = __builtin_amdgcn_mfma_f32_16x16x32_bf16(aP0, bV, oacc[0][jd], 0, 0, 0);
                oacc[1][jd] = __builtin_amdgcn_mfma_f32_16x16x32_bf16(aP1, bV, oacc[1][jd], 0, 0, 0);
            }
        }

        __syncthreads();   // all LDS readers drained (also drains vmcnt -> regs valid)
        if (more) {
            // refill Ksu/Vtu from registers (wave-linear b128, conflict-free)
            #pragma unroll
            for (int i = 0; i < 6; ++i)
                *(bfrag*)(Ksu + (wave + 4 * i) * 512 + lane * 8) = kreg[i];
            #pragma unroll
            for (int i = 0; i < 4; ++i)
                *(bfrag*)(Vtu + (wave + 4 * i) * 512 + lane * 8) = vreg[i];
        }
        __syncthreads();   // new tile visible before next QK^T
    }

    // reduce l partials, epilogue
    #pragma unroll
    for (int sp = 0; sp < 2; ++sp) {
        #pragma unroll
        for (int r = 0; r < 4; ++r) {
            float v = lp[sp][r];
            #pragma unroll
            for (int msk = 1; msk < 16; msk <<= 1) v += __shfl_xor(v, msk);
            const float inv = 1.f / v;
            ushort* op = o + (size_t)(b * SS + q0 + sp * 64 + wstrip + quad * 4 + r)
                             * (HH * DV) + h * DV;
            #pragma unroll
            for (int jd = 0; jd < 8; ++jd)
                op[jd * 16 + n] = f2bf(oacc[sp][jd][r] * inv);
        }
    }
}

// ---------------- launch ----------------
extern "C" void kernel_launch(void* const* d_in, const int* in_sizes, int n_in,
                              void* d_out, int out_size, void* d_ws, size_t ws_size,
                              hipStream_t stream) {
    const float* hs    = (const float*)d_in[0];
    const float* cosb  = (const float*)d_in[1];
    const float* sinb  = (const float*)d_in[2];
    const float* Wqa   = (const float*)d_in[3];
    const float* qa_w  = (const float*)d_in[4];
    const float* Wqb   = (const float*)d_in[5];
    const float* Wkva  = (const float*)d_in[6];
    const float* kva_w = (const float*)d_in[7];
    const float* Wkvb  = (const float*)d_in[8];
    const float* Wo    = (const float*)d_in[9];
    float* out = (float*)d_out;

    const int T = BB * SS; // 4096 tokens

    char* w = (char*)d_ws;
    auto alloc = [&](size_t bytes) {
        void* r = (void*)w;
        w += (bytes + 255) & ~(size_t)255;
        return r;
    };
    ushort* hs_bf  = (ushort*)alloc((size_t)T * DD * 2);            // 16.8 MB
    ushort* Wcat   = (ushort*)alloc((size_t)NCATP * DD * 2);        //  9.4 (pad rows 2176..2303 read-but-discarded)
    ushort* Wqbt   = (ushort*)alloc((size_t)(HH * DQ) * QL * 2);    //  9.4
    ushort* Wkvbt  = (ushort*)alloc((size_t)(HH * KVD) * KVL * 2);  //  4.2
    ushort* Wot    = (ushort*)alloc((size_t)DD * DD * 2);           //  8.4
    ushort* qa_bf  = (ushort*)alloc((size_t)T * QL * 2);            // 12.6
    ushort* Qbuf   = (ushort*)alloc((size_t)T * HH * DQ * 2);       // 25.2
    ushort* ckv_bf = (ushort*)alloc((size_t)T * CKVS * 2);          //  5.2
    ushort* kvn_bf = (ushort*)alloc((size_t)T * KVL * 2);           //  4.2
    ushort* kv_bf  = (ushort*)alloc((size_t)T * HH * KVD * 2);      // 33.6
    ushort* krb    = (ushort*)alloc((size_t)T * DR * 2);            //  0.5
    // aliases (lifetimes verified):
    ushort* Vtb    = Wcat;   // 16.8 MB over Wcat+Wqbt (dead after gemmA/gemmQ)
    ushort* ao_bf  = hs_bf;  // hs_bf dead after gemmA

    // 0. cast hs; all 5 weight transposes in ONE batched launch
    castf2bf<<<(T * DD / 4) / 256, 256, 0, stream>>>(hs, hs_bf);
    WtBatch wb;
    wb.src[0] = Wqa;  wb.dst[0] = Wcat;                      wb.K[0] = DD;  wb.N[0] = QL;       wb.nx[0] = 48;
    wb.src[1] = Wkva; wb.dst[1] = Wcat + (size_t)QL * DD;    wb.K[1] = DD;  wb.N[1] = KVL + DR; wb.nx[1] = 20;
    wb.src[2] = Wqb;  wb.dst[2] = Wqbt;                      wb.K[2] = QL;  wb.N[2] = HH * DQ;  wb.nx[2] = 96;
    wb.src[3] = Wkvb; wb.dst[3] = Wkvbt;                     wb.K[3] = KVL; wb.N[3] = HH * KVD; wb.nx[3] = 128;
    wb.src[4] = Wo;   wb.dst[4] = Wot;                       wb.K[4] = DD;  wb.N[4] = DD;       wb.nx[4] = 64;
    wb.base[0] = 0;
    wb.base[1] = wb.base[0] + wb.nx[0] * (DD / 32);   // 3072
    wb.base[2] = wb.base[1] + wb.nx[1] * (DD / 32);   // 4352
    wb.base[3] = wb.base[2] + wb.nx[2] * (QL / 32);   // 8960
    wb.base[4] = wb.base[3] + wb.nx[3] * (KVL / 32);  // 11008
    wb.base[5] = wb.base[4] + wb.nx[4] * (DD / 32);   // 15104
    wtrans_b<<<wb.base[5], 256, 0, stream>>>(wb);

    // 1. fused: qa | ckv = hs @ [Wqa | Wkva]  (256-tile, N padded to 2304)
    gemmA256<<<dim3(9 * 16), 512, 0, stream>>>(hs_bf, Wcat, qa_bf, ckv_bf);
    // 2. rmsnorm qa in place
    rmsnorm_bf_ip<<<T, 256, 0, stream>>>(qa_bf, qa_w, QL);
    // 3. Q = qa @ Wqb -> Qbuf layout, scale folded
    gemmQ256<<<dim3(12 * 16), 512, 0, stream>>>(qa_bf, Wqbt, Qbuf);
    // 4. rope Q in place (rope lanes only)
    qrope<<<T, 256, 0, stream>>>(Qbuf, cosb, sinb);
    // 5. kvn = rmsnorm(ckv[:, :512]) + roped k_rot -> krb (fused)
    rmsnorm_kv<<<T, 256, 0, stream>>>(ckv_bf, kva_w, kvn_bf, krb, cosb, sinb);
    // 6. kv = kvn @ Wkvb (bf16)
    gemm256<ushort, KVL, 16, HH * KVD><<<dim3(16 * 16), 512, 0, stream>>>(kvn_bf, Wkvbt, kv_bf);
    // 7. V transpose -> Vt
    vprep<<<dim3(SS / 32, DV / 32, BB * HH), 256, 0, stream>>>(kv_bf, Vtb);
    // 8. MFMA flash attention (q-tile 128, uniform pairing) -> ao (bf16)
    fattn_mfma<<<dim3(16, HH, BB), 256, 0, stream>>>(Qbuf, kv_bf, krb, Vtb, ao_bf);
    // 9. out = ao @ Wo (fp32)
    gemm256<float, DD, 8, DD><<<dim3(8 * 16), 512, 0, stream>>>(ao_bf, Wot, out);
}

// Round 4
// 430.089 us; speedup vs baseline: 1.1255x; 1.0439x over previous
//
#include <hip/hip_runtime.h>
#include <math.h>

#define BB 2
#define SS 2048
#define DD 2048
#define HH 16
#define DN 128
#define DR 64
#define DV 128
#define QL 1536
#define KVL 512
#define DQ 192           // DN + DR
#define CKVS 640         // ckv row stride (576 padded to 640)
#define KVD 256          // DN + DV
#define NCAT 2176        // QL + CKVS (fused first GEMM)
#define NCATP 2304       // NCAT padded to 9*256 for the 256-wide GEMM tile
#define EPSF 1e-6f

typedef short bfrag __attribute__((ext_vector_type(8)));   // 8 bf16 (4 VGPRs)
typedef float facc  __attribute__((ext_vector_type(4)));   // 4 fp32 acc

// ---------------- helpers ----------------
__device__ __forceinline__ ushort f2bf(float f) {
    union { float f; unsigned u; } v; v.f = f;
    unsigned r = v.u + 0x7fffu + ((v.u >> 16) & 1u);  // RNE
    return (ushort)(r >> 16);
}
__device__ __forceinline__ float bf2f(ushort u) {
    union { unsigned u; float f; } v; v.u = ((unsigned)u) << 16;
    return v.f;
}
__device__ __forceinline__ float fexp2(float x) {   // raw v_exp_f32 (2^x)
    float r; asm("v_exp_f32 %0, %1" : "=v"(r) : "v"(x)); return r;
}
__device__ __forceinline__ float wave_red_sum(float v) {
    #pragma unroll
    for (int o = 32; o > 0; o >>= 1) v += __shfl_down(v, o);
    return v;
}
__device__ __forceinline__ void gl2lds16(const ushort* g, ushort* l) {
    __builtin_amdgcn_global_load_lds(
        (const __attribute__((address_space(1))) void*)g,
        (__attribute__((address_space(3))) void*)l, 16, 0, 0);
}
__device__ __forceinline__ void storeC(float* c, float v)  { *c = v; }
__device__ __forceinline__ void storeC(ushort* c, float v) { *c = f2bf(v); }

// ---------------- fp32 -> bf16 cast (vectorized) ----------------
__global__ __launch_bounds__(256) void castf2bf(const float* __restrict__ x,
                                                ushort* __restrict__ y) {
    const int i = blockIdx.x * 256 + threadIdx.x;
    const float4 v = ((const float4*)x)[i];
    ushort4 o;
    o.x = f2bf(v.x); o.y = f2bf(v.y); o.z = f2bf(v.z); o.w = f2bf(v.w);
    ((ushort4*)y)[i] = o;
}

// ------- batched weight cast+transpose: 5 segments in one launch ----------
struct WtBatch {
    const float* src[5];
    ushort* dst[5];
    int K[5];
    int N[5];
    int nx[5];
    int base[6];
};
__global__ __launch_bounds__(256) void wtrans_b(WtBatch d) {
    __shared__ float tile[32][33];
    int bid = blockIdx.x;
    int seg = 0;
    while (bid >= d.base[seg + 1]) ++seg;
    const int l = bid - d.base[seg];
    const int nx = d.nx[seg];
    const int bx = l % nx, by = l / nx;
    const float* W = d.src[seg];
    ushort* Wt = d.dst[seg];
    const int K = d.K[seg], N = d.N[seg];
    const int k0 = by * 32, n0 = bx * 32;
    const int t = threadIdx.x;
    const int tx = t & 31, ty = t >> 5;
    #pragma unroll
    for (int r = 0; r < 4; ++r) {
        const int n = n0 + tx;
        tile[ty + r * 8][tx] =
            (n < N) ? W[(size_t)(k0 + ty + r * 8) * N + n] : 0.f;
    }
    __syncthreads();
    #pragma unroll
    for (int r = 0; r < 4; ++r) {
        const int n = n0 + ty + r * 8;
        Wt[(size_t)n * K + k0 + tx] = f2bf(tile[tx][ty + r * 8]);
    }
}

// ================== 256x256 8-phase MFMA GEMM (m201 template) ==============
// 512 threads = 8 waves (2M x 4N), per-wave C = 128x64, BK=64, dbuf LDS 128KB
// (static __shared__).  See round-1 notes; schedule verified on HW (r2/r3).

__device__ __forceinline__ void stage_half(const ushort* __restrict__ G,
                                           int ldg, int grow0, int kcol0,
                                           ushort* Lr, int wave, int lane) {
    const int r0   = lane >> 3;
    const int slot = (lane & 7) ^ r0;          // inverse-swizzled global slot
    const ushort* s0 = G + (size_t)(grow0 + wave * 16 + r0) * ldg + kcol0 + slot * 8;
    gl2lds16(s0,                    Lr + wave * 1024);        // rows w*16..+8
    gl2lds16(s0 + (size_t)8 * ldg,  Lr + wave * 1024 + 512);  // rows +8..+16
}

#define PH_PRE  do { __builtin_amdgcn_sched_barrier(0);                      \
                     __builtin_amdgcn_s_barrier();                           \
                     asm volatile("s_waitcnt lgkmcnt(0)" ::: "memory");      \
                     __builtin_amdgcn_sched_barrier(0);                      \
                     __builtin_amdgcn_s_setprio(1); } while (0)
#define PH_POST do { __builtin_amdgcn_s_setprio(0);                          \
                     __builtin_amdgcn_sched_barrier(0);                      \
                     __builtin_amdgcn_s_barrier(); } while (0)

#define MFMA16(RB)                                                           \
    _Pragma("unroll")                                                        \
    for (int i = 0; i < 4; ++i)                                              \
        _Pragma("unroll")                                                    \
        for (int j = 0; j < 4; ++j)                                          \
            acc[(RB) + i][j] = __builtin_amdgcn_mfma_f32_16x16x32_bf16(      \
                a[i], b[j], acc[(RB) + i][j], 0, 0, 0);

#define GEMM256_CORE(A_, Bt_, K_, NBX_)                                       \
    __shared__ ushort L[65536]; /* 128 KiB static */                          \
    const int t    = threadIdx.x;                                             \
    const int lane = t & 63;                                                  \
    const int wave = t >> 6;                                                  \
    const int wm   = wave >> 2;                                               \
    const int wn   = wave & 3;                                                \
    const int quad = lane >> 4;                                               \
    const int lrow = lane & 15;                                               \
    int wg = (int)blockIdx.x;                                                 \
    { const int cpx = (int)gridDim.x >> 3; wg = (wg & 7) * cpx + (wg >> 3); } \
    const int bx = wg % (NBX_), by = wg / (NBX_);                             \
    const int m0 = by * 256, n0 = bx * 256;                                   \
    const int s0x8  = (quad ^ (lrow & 7)) * 8;   /* swizzled slot, kh=0 */    \
    const int s1x8  = s0x8 ^ 32;                 /* kh=1: slot^4          */  \
    const int abase = lrow * 64;                                              \
    const int bbase = (wn & 1) * 4096 + lrow * 64;                            \
    facc acc[8][4];                                                           \
    _Pragma("unroll")                                                         \
    for (int i = 0; i < 8; ++i)                                               \
        _Pragma("unroll")                                                     \
        for (int j = 0; j < 4; ++j) acc[i][j] = (facc)(0.f);                  \
    const int nk = (K_) >> 6;                                                 \
    /* prologue: K0 all 4 halves -> buf0; K1 B halves -> buf1 */              \
    stage_half((A_),  (K_), m0,        0, L,         wave, lane);             \
    stage_half((A_),  (K_), m0 + 128,  0, L + 8192,  wave, lane);             \
    stage_half((Bt_), (K_), n0,        0, L + 16384, wave, lane);             \
    stage_half((Bt_), (K_), n0 + 128,  0, L + 24576, wave, lane);             \
    stage_half((Bt_), (K_), n0,       64, L + 49152, wave, lane);             \
    stage_half((Bt_), (K_), n0 + 128, 64, L + 57344, wave, lane);             \
    asm volatile("s_waitcnt vmcnt(4)" ::: "memory");                          \
    __builtin_amdgcn_s_barrier();                                             \
    for (int kt = 0; kt < nk; ++kt) {                                         \
        const int p = kt & 1;                                                 \
        ushort* LA = L + p * 32768 + wm * 8192;                               \
        ushort* LB = L + p * 32768 + 16384 + (wn >> 1) * 8192;                \
        ushort* Lq = L + (p ^ 1) * 32768;                                     \
        const int kn = (kt + 1) * 64;                                         \
        bfrag a[4], b[4];                                                     \
        /* ---- q1: frags m0-3, kh0 ---- */                                   \
        _Pragma("unroll")                                                     \
        for (int i = 0; i < 4; ++i)                                           \
            a[i] = *(const bfrag*)(LA + i * 1024 + abase + s0x8);             \
        _Pragma("unroll")                                                     \
        for (int j = 0; j < 4; ++j)                                           \
            b[j] = *(const bfrag*)(LB + bbase + j * 1024 + s0x8);             \
        if (kt + 1 < nk) stage_half((A_), (K_), m0, kn, Lq, wave, lane);      \
        PH_PRE;                                                               \
        MFMA16(0)                                                             \
        PH_POST;                                                              \
        /* ---- q2: frags m4-7, kh0 (b reused) ---- */                        \
        _Pragma("unroll")                                                     \
        for (int i = 0; i < 4; ++i)                                           \
            a[i] = *(const bfrag*)(LA + (4 + i) * 1024 + abase + s0x8);       \
        if (kt + 1 < nk)                                                      \
            stage_half((A_), (K_), m0 + 128, kn, Lq + 8192, wave, lane);      \
        PH_PRE;                                                               \
        MFMA16(4)                                                             \
        PH_POST;                                                              \
        /* ---- q3: frags m0-3, kh1 ---- */                                   \
        _Pragma("unroll")                                                     \
        for (int i = 0; i < 4; ++i)                                           \
            a[i] = *(const bfrag*)(LA + i * 1024 + abase + s1x8);             \
        _Pragma("unroll")                                                     \
        for (int j = 0; j < 4; ++j)                                           \
            b[j] = *(const bfrag*)(LB + bbase + j * 1024 + s1x8);             \
        PH_PRE;                                                               \
        MFMA16(0)                                                             \
        PH_POST;                                                              \
        /* ---- q4: frags m4-7, kh1; stage B(kt+2); counted vmcnt ---- */     \
        _Pragma("unroll")                                                     \
        for (int i = 0; i < 4; ++i)                                           \
            a[i] = *(const bfrag*)(LA + (4 + i) * 1024 + abase + s1x8);       \
        if (kt + 2 < nk) {                                                    \
            stage_half((Bt_), (K_), n0,       kn + 64,                        \
                       L + p * 32768 + 16384, wave, lane);                    \
            stage_half((Bt_), (K_), n0 + 128, kn + 64,                        \
                       L + p * 32768 + 24576, wave, lane);                    \
            asm volatile("s_waitcnt vmcnt(4)" ::: "memory");                  \
        } else {                                                              \
            asm volatile("s_waitcnt vmcnt(0)" ::: "memory");                  \
        }                                                                     \
        PH_PRE;                                                               \
        MFMA16(4)                                                             \
        PH_POST;                                                              \
    }

// ---------------- generic 256-tile GEMM, row-major C ----------------
template <typename OUT, int K, int NBX, int NOUT>
__global__ __launch_bounds__(512, 2) void gemm256(const ushort* __restrict__ A,
                                                  const ushort* __restrict__ Bt,
                                                  OUT* __restrict__ C) {
    GEMM256_CORE(A, Bt, K, NBX)
    #pragma unroll
    for (int m = 0; m < 8; ++m) {
        const int row = m0 + wm * 128 + m * 16 + quad * 4;
        #pragma unroll
        for (int nf = 0; nf < 4; ++nf) {
            const int col = n0 + wn * 64 + nf * 16 + lrow;
            #pragma unroll
            for (int r = 0; r < 4; ++r)
                storeC(&C[(size_t)(row + r) * NOUT + col], acc[m][nf][r]);
        }
    }
}

// ====== 256x128-tile 2-phase variant (full-grid fill for M4096xN2048) ======
// 8 waves as 4M x 2N, per-wave C = 64x64, acc[4][4], BK=64.
// LDS 112KB: A dbuf 2x16KB-pairs (2 halves each) + B TRIPLE buffer 3x16KB.
// B 3-buf keeps every stage barrier-separated from the last read of its
// region (same hazard class as the verified 256^2 schedule).  Waits:
// ph2(kt): vmcnt(2) retires A(kt+1)x4 (issued ph1(kt)) keeping B(kt+2)x2 in
// flight; B(kt+2) is retired by ph2(kt+1)'s vmcnt(2) before its ph1(kt+2)
// read.  Tail: vmcnt(0).
template <int K, int NBX, int NOUT>
__global__ __launch_bounds__(512, 2) void gemmW(const ushort* __restrict__ A,
                                                const ushort* __restrict__ Bt,
                                                float* __restrict__ C) {
    __shared__ ushort L[57344];   // 112 KiB
    const int t    = threadIdx.x;
    const int lane = t & 63;
    const int wave = t >> 6;
    const int wm   = wave >> 1;          // 0..3
    const int wn   = wave & 1;           // 0..1
    const int quad = lane >> 4;
    const int lrow = lane & 15;
    int wg = (int)blockIdx.x;
    { const int cpx = (int)gridDim.x >> 3; wg = (wg & 7) * cpx + (wg >> 3); }
    const int bx = wg % NBX, by = wg / NBX;
    const int m0 = by * 256, n0 = bx * 128;
    const int s0x8 = (quad ^ (lrow & 7)) * 8;
    const int s1x8 = s0x8 ^ 32;
    facc acc[4][4];
    #pragma unroll
    for (int i = 0; i < 4; ++i)
        #pragma unroll
        for (int j = 0; j < 4; ++j) acc[i][j] = (facc)(0.f);
    const int nk = K >> 6;
    // prologue: A(0) both halves -> buf0; B(0) -> bbuf0; B(1) -> bbuf1
    stage_half(A,  K, m0,        0, L,          wave, lane);
    stage_half(A,  K, m0 + 128,  0, L + 8192,   wave, lane);
    stage_half(Bt, K, n0,        0, L + 32768,  wave, lane);
    stage_half(Bt, K, n0,       64, L + 40960,  wave, lane);
    asm volatile("s_waitcnt vmcnt(0)" ::: "memory");
    __builtin_amdgcn_s_barrier();
    int bp = 0, bp2 = 2;   // kt%3 and (kt+2)%3
    for (int kt = 0; kt < nk; ++kt) {
        const int p = kt & 1;
        ushort* LA = L + p * 16384 + (wm >> 1) * 8192
                       + ((wm & 1) * 64 + lrow) * 64;
        ushort* LB = L + 32768 + bp * 8192 + (wn * 64 + lrow) * 64;
        const int kn = (kt + 1) * 64;
        bfrag a[4], b[4];
        // ---- ph1: kh0 ----
        #pragma unroll
        for (int i = 0; i < 4; ++i) a[i] = *(const bfrag*)(LA + i * 1024 + s0x8);
        #pragma unroll
        for (int j = 0; j < 4; ++j) b[j] = *(const bfrag*)(LB + j * 1024 + s0x8);
        if (kt + 1 < nk) {
            stage_half(A, K, m0,       kn, L + (p ^ 1) * 16384,        wave, lane);
            stage_half(A, K, m0 + 128, kn, L + (p ^ 1) * 16384 + 8192, wave, lane);
        }
        if (kt + 2 < nk)
            stage_half(Bt, K, n0, kn + 64, L + 32768 + bp2 * 8192, wave, lane);
        PH_PRE;
        MFMA16(0)
        PH_POST;
        // ---- ph2: kh1 ----
        #pragma unroll
        for (int i = 0; i < 4; ++i) a[i] = *(const bfrag*)(LA + i * 1024 + s1x8);
        #pragma unroll
        for (int j = 0; j < 4; ++j) b[j] = *(const bfrag*)(LB + j * 1024 + s1x8);
        if (kt + 2 < nk) { asm volatile("s_waitcnt vmcnt(2)" ::: "memory"); }
        else             { asm volatile("s_waitcnt vmcnt(0)" ::: "memory"); }
        PH_PRE;
        MFMA16(0)
        PH_POST;
        bp  = (bp  == 2) ? 0 : bp  + 1;
        bp2 = (bp2 == 2) ? 0 : bp2 + 1;
    }
    #pragma unroll
    for (int m = 0; m < 4; ++m) {
        const int row = m0 + wm * 64 + m * 16 + quad * 4;
        #pragma unroll
        for (int nf = 0; nf < 4; ++nf) {
            const int col = n0 + wn * 64 + nf * 16 + lrow;
            #pragma unroll
            for (int r = 0; r < 4; ++r)
                C[(size_t)(row + r) * NOUT + col] = acc[m][nf][r];
        }
    }
}

// -------- fused GEMM A: hs @ [Wqa | Wkva] -> qa_bf, ckv_bf (N pad 2304) -----
__global__ __launch_bounds__(512, 2) void gemmA256(const ushort* __restrict__ A,
                                                   const ushort* __restrict__ Bt,
                                                   ushort* __restrict__ qa,
                                                   ushort* __restrict__ ckv) {
    GEMM256_CORE(A, Bt, DD, 9)
    #pragma unroll
    for (int m = 0; m < 8; ++m) {
        const int row = m0 + wm * 128 + m * 16 + quad * 4;
        #pragma unroll
        for (int nf = 0; nf < 4; ++nf) {
            const int col = n0 + wn * 64 + nf * 16 + lrow;
            #pragma unroll
            for (int r = 0; r < 4; ++r) {
                if (col < QL)
                    qa[(size_t)(row + r) * QL + col] = f2bf(acc[m][nf][r]);
                else if (col < NCAT)
                    ckv[(size_t)(row + r) * CKVS + col - QL] = f2bf(acc[m][nf][r]);
            }
        }
    }
}

// -------- GEMM Q: qa @ Wqb -> Qbuf[(b*HH+h)*SS+s][192] -------
// scale = 192^-0.5 * log2(e) folded in: fattn uses exp2 (v_exp_f32) directly.
__global__ __launch_bounds__(512, 2) void gemmQ256(const ushort* __restrict__ A,
                                                   const ushort* __restrict__ Bt,
                                                   ushort* __restrict__ Qbuf) {
    GEMM256_CORE(A, Bt, QL, 12)
    const float scaling = 0.10411754831f; // 192^-0.5 * log2(e)
    #pragma unroll
    for (int m = 0; m < 8; ++m) {
        const int row = m0 + wm * 128 + m * 16 + quad * 4;
        #pragma unroll
        for (int nf = 0; nf < 4; ++nf) {
            const int col = n0 + wn * 64 + nf * 16 + lrow;
            const int h = col / DQ, d = col - h * DQ;
            #pragma unroll
            for (int r = 0; r < 4; ++r) {
                const int tok = row + r;
                const int b = tok >> 11, s = tok & (SS - 1);
                Qbuf[((size_t)(b * HH + h) * SS + s) * DQ + d] =
                    f2bf(acc[m][nf][r] * scaling);
            }
        }
    }
}

// ---------------- RMSNorm bf16 in-place ----------------
__global__ __launch_bounds__(256) void rmsnorm_bf_ip(ushort* __restrict__ x,
                                                     const float* __restrict__ w,
                                                     int n) {
    ushort* xr = x + (size_t)blockIdx.x * n;
    const int t = threadIdx.x;
    float ss = 0.f;
    for (int i = t; i < n; i += 256) { float v = bf2f(xr[i]); ss += v * v; }
    ss = wave_red_sum(ss);
    __shared__ float red[4];
    const int lane = t & 63, wid = t >> 6;
    if (lane == 0) red[wid] = ss;
    __syncthreads();
    const float tot = red[0] + red[1] + red[2] + red[3];
    const float scale = rsqrtf(tot / (float)n + EPSF);
    for (int i = t; i < n; i += 256) xr[i] = f2bf(w[i] * bf2f(xr[i]) * scale);
}

// ------- kv RMSNorm (ckv[:, :512] -> kvn) fused with roped k_rot -> krb -----
__global__ __launch_bounds__(256) void rmsnorm_kv(const ushort* __restrict__ x,
                                                  const float* __restrict__ w,
                                                  ushort* __restrict__ y,
                                                  ushort* __restrict__ krb,
                                                  const float* __restrict__ cosb,
                                                  const float* __restrict__ sinb) {
    const int row = blockIdx.x;
    const ushort* xr = x + (size_t)row * CKVS;
    ushort* yr = y + (size_t)row * KVL;
    const int t = threadIdx.x;
    if (t < 64) {   // k_rot rope (independent of the norm)
        const int p = t;
        const ushort* kin = xr + KVL;
        const float c  = cosb[(size_t)row * DR + p];
        const float sn = sinb[(size_t)row * DR + p];
        const float self = bf2f(kin[p]);
        const float partner = bf2f(kin[p < 32 ? p + 32 : p - 32]);
        const float v = (p < 32) ? (self * c - partner * sn)
                                 : (self * c + partner * sn);
        krb[(size_t)row * DR + p] = f2bf(v);
    }
    float ss = 0.f;
    for (int i = t; i < KVL; i += 256) { float v = bf2f(xr[i]); ss += v * v; }
    ss = wave_red_sum(ss);
    __shared__ float red[4];
    const int lane = t & 63, wid = t >> 6;
    if (lane == 0) red[wid] = ss;
    __syncthreads();
    const float tot = red[0] + red[1] + red[2] + red[3];
    const float scale = rsqrtf(tot / (float)KVL + EPSF);
    for (int i = t; i < KVL; i += 256) yr[i] = f2bf(w[i] * bf2f(xr[i]) * scale);
}

// ---------------- qrope: in-place rope on Qbuf rope lanes ----------------
__global__ __launch_bounds__(256) void qrope(ushort* __restrict__ Qbuf,
                                             const float* __restrict__ cosb,
                                             const float* __restrict__ sinb) {
    const int tok = blockIdx.x;
    const int b = tok >> 11, s = tok & (SS - 1);
    const int t = threadIdx.x;
    const int p = t & 31, hh = t >> 5;
    const float c0 = cosb[(size_t)tok * DR + p];
    const float s0 = sinb[(size_t)tok * DR + p];
    const float c1 = cosb[(size_t)tok * DR + p + 32];
    const float s1 = sinb[(size_t)tok * DR + p + 32];
    #pragma unroll
    for (int it = 0; it < 2; ++it) {
        const int h = hh + it * 8;
        ushort* base = Qbuf + ((size_t)(b * HH + h) * SS + s) * DQ + DN;
        const float x0 = bf2f(base[p]), x1 = bf2f(base[p + 32]);
        base[p]      = f2bf(x0 * c0 - x1 * s0);
        base[p + 32] = f2bf(x1 * c1 + x0 * s1);
    }
}

// ---------------- vprep: transpose V -> Vt[bh][dv][SS] bf16 ----------------
__global__ __launch_bounds__(256) void vprep(const ushort* __restrict__ kv_bf,
                                             ushort* __restrict__ Vtb) {
    __shared__ ushort tile[32][33];
    const int kp0 = blockIdx.x * 32, dv0 = blockIdx.y * 32, bh = blockIdx.z;
    const int b = bh / HH, h = bh - b * HH;
    const int t = threadIdx.x, tx = t & 31, ty = t >> 5;
    #pragma unroll
    for (int r = 0; r < 4; ++r)
        tile[ty + r * 8][tx] =
            kv_bf[(size_t)(b * SS + kp0 + ty + r * 8) * (HH * KVD) + h * KVD + DN + dv0 + tx];
    __syncthreads();
    #pragma unroll
    for (int r = 0; r < 4; ++r)
        Vtb[((size_t)bh * DV + dv0 + ty + r * 8) * SS + kp0 + tx] = tile[tx][ty + r * 8];
}

// ---------------- MFMA flash attention, q-tile 128, uniform pairing -------
// v3: prefetch loads PINNED with sched_barrier(0) (r3 showed the compiler
// sank them: VGPR 124->128 only).  exp2 path (log2e folded into Q scaling).
__global__ __launch_bounds__(256, 2) void fattn_mfma(
    const ushort* __restrict__ Qb,   // [(b*HH+h)*SS+s][192] pre-scaled+roped
    const ushort* __restrict__ kvb,  // [tok][HH*KVD]
    const ushort* __restrict__ krb,  // [tok][64]
    const ushort* __restrict__ Vt,   // [(b*HH+h)*DV+dv][SS]
    ushort* __restrict__ o)          // [tok][HH*DV]
{
    const int h  = blockIdx.y;
    const int b  = blockIdx.z;
    const int qt = b ? (15 - (int)blockIdx.x) : (int)blockIdx.x;
    const int bh = b * HH + h;
    const int q0 = qt * 128;
    const int t    = threadIdx.x;
    const int lane = t & 63;
    const int wave = t >> 6;
    const int quad = lane >> 4;
    const int n    = lane & 15;
    const int wstrip = wave * 16;

    __shared__ ushort Ksu[6 * 64 * 32];   // 24 KB
    __shared__ ushort Vtu[2 * 128 * 32];  // 16 KB
    __shared__ ushort Psu[2 * 128 * 40];  // 20 KB (padded rows)

    const ushort* vbase = Vt + (size_t)bh * DV * SS;

    // preload Q A-frags for both strips
    bfrag aQ[2][6];
    #pragma unroll
    for (int sp = 0; sp < 2; ++sp) {
        const ushort* qrow = Qb + ((size_t)bh * SS + q0 + sp * 64 + wstrip + n) * DQ;
        #pragma unroll
        for (int kb = 0; kb < 6; ++kb)
            aQ[sp][kb] = *(const bfrag*)(qrow + kb * 32 + quad * 8);
    }

    facc oacc[2][8];
    float lp[2][4];
    #pragma unroll
    for (int sp = 0; sp < 2; ++sp) {
        #pragma unroll
        for (int jd = 0; jd < 8; ++jd) oacc[sp][jd] = (facc)(0.f);
        #pragma unroll
        for (int r = 0; r < 4; ++r) lp[sp][r] = 0.f;
    }

    // prologue: stage tile kt=0 via global_load_lds (full drain is fine once)
    #pragma unroll
    for (int i = 0; i < 6; ++i) {
        const int g = wave + 4 * i;
        const int kb = g >> 2;                    // wave-uniform
        const int rem = (g & 3) * 64 + lane;
        const int row = rem >> 2, sub = rem & 3;
        const int tok = b * SS + row;
        const ushort* src = (kb < 4)
            ? kvb + (size_t)tok * (HH * KVD) + h * KVD + kb * 32 + sub * 8
            : krb + (size_t)tok * DR + (kb - 4) * 32 + sub * 8;
        gl2lds16(src, Ksu + g * 512);
    }
    #pragma unroll
    for (int i = 0; i < 4; ++i) {
        const int g = wave + 4 * i;
        const int kb2 = g >> 3;                   // wave-uniform
        const int rem = (g & 7) * 64 + lane;
        const int dv = rem >> 2, sub = rem & 3;
        gl2lds16(vbase + (size_t)dv * SS + kb2 * 32 + sub * 8, Vtu + g * 512);
    }
    __syncthreads();

    const int nkt = 2 * qt + 2;
    for (int kt = 0; kt < nkt; ++kt) {
        const int k0 = kt * 64;
        const int k1 = k0 + 64;
        const bool more = (kt + 1 < nkt);

        // ---- issue next-tile global loads into registers (no wait) ----
        bfrag kreg[6], vreg[4];
        if (more) {
            #pragma unroll
            for (int i = 0; i < 6; ++i) {
                const int g = wave + 4 * i;
                const int kb = g >> 2;
                const int rem = (g & 3) * 64 + lane;
                const int row = rem >> 2, sub = rem & 3;
                const int tok = b * SS + k1 + row;
                const ushort* src = (kb < 4)
                    ? kvb + (size_t)tok * (HH * KVD) + h * KVD + kb * 32 + sub * 8
                    : krb + (size_t)tok * DR + (kb - 4) * 32 + sub * 8;
                kreg[i] = *(const bfrag*)src;
            }
            #pragma unroll
            for (int i = 0; i < 4; ++i) {
                const int g = wave + 4 * i;
                const int kb2 = g >> 3;
                const int rem = (g & 7) * 64 + lane;
                const int dv = rem >> 2, sub = rem & 3;
                vreg[i] = *(const bfrag*)(vbase + (size_t)dv * SS + k1 + kb2 * 32 + sub * 8);
            }
        }
        __builtin_amdgcn_sched_barrier(0);   // pin load issue BEFORE compute

        // ---- S = Q K^T, both strips share each K frag ----
        facc s[2][4];
        #pragma unroll
        for (int sp = 0; sp < 2; ++sp)
            #pragma unroll
            for (int j = 0; j < 4; ++j) s[sp][j] = (facc)(0.f);
        #pragma unroll
        for (int kb = 0; kb < 6; ++kb) {
            #pragma unroll
            for (int j = 0; j < 4; ++j) {
                const bfrag bk =
                    *(const bfrag*)&Ksu[kb * 2048 + (j * 16 + n) * 32 + quad * 8];
                s[0][j] = __builtin_amdgcn_mfma_f32_16x16x32_bf16(aQ[0][kb], bk, s[0][j], 0, 0, 0);
                s[1][j] = __builtin_amdgcn_mfma_f32_16x16x32_bf16(aQ[1][kb], bk, s[1][j], 0, 0, 0);
            }
        }

        // ---- exp2 (m=0) + causal select; P -> LDS (wave-private rows) ----
        const bool fullt = (k1 <= q0);   // tile entirely below the diagonal
        if (fullt) {
            #pragma unroll
            for (int sp = 0; sp < 2; ++sp) {
                #pragma unroll
                for (int j = 0; j < 4; ++j) {
                    #pragma unroll
                    for (int r = 0; r < 4; ++r) {
                        const float p = fexp2(s[sp][j][r]);
                        lp[sp][r] += p;
                        Psu[(j >> 1) * 5120 + (sp * 64 + wstrip + quad * 4 + r) * 40
                            + (j & 1) * 16 + n] = f2bf(p);
                    }
                }
            }
        } else {
            #pragma unroll
            for (int sp = 0; sp < 2; ++sp) {
                const int rowg0 = q0 + sp * 64 + wstrip + quad * 4;
                #pragma unroll
                for (int j = 0; j < 4; ++j) {
                    const int kpos = k0 + j * 16 + n;
                    #pragma unroll
                    for (int r = 0; r < 4; ++r) {
                        const float p = (kpos <= rowg0 + r) ? fexp2(s[sp][j][r]) : 0.f;
                        lp[sp][r] += p;
                        Psu[(j >> 1) * 5120 + (sp * 64 + wstrip + quad * 4 + r) * 40
                            + (j & 1) * 16 + n] = f2bf(p);
                    }
                }
            }
        }

        // ---- O += P @ V; V frags shared across strips ----
        #pragma unroll
        for (int kb2 = 0; kb2 < 2; ++kb2) {
            const bfrag aP0 = *(const bfrag*)&Psu[kb2 * 5120 + (wstrip + n) * 40 + quad * 8];
            const bfrag aP1 = *(const bfrag*)&Psu[kb2 * 5120 + (64 + wstrip + n) * 40 + quad * 8];
            #pragma unroll
            for (int jd = 0; jd < 8; ++jd) {
                const bfrag bV = *(const bfrag*)&Vtu[kb2 * 4096 + (jd * 16 + n) * 32 + quad * 8];
                oacc[0][jd] = __builtin_amdgcn_mfma_f32_16x16x32_bf16(aP0, bV, oacc[0][jd], 0, 0, 0);
                oacc[1][jd] = __builtin_amdgcn_mfma_f32_16x16x32_bf16(aP1, bV, oacc[1][jd], 0, 0, 0);
            }
        }

        __syncthreads();   // all LDS readers drained (also drains vmcnt -> regs valid)
        if (more) {
            // refill Ksu/Vtu from registers (wave-linear b128, conflict-free)
            #pragma unroll
            for (int i = 0; i < 6; ++i)
                *(bfrag*)(Ksu + (wave + 4 * i) * 512 + lane * 8) = kreg[i];
            #pragma unroll
            for (int i = 0; i < 4; ++i)
                *(bfrag*)(Vtu + (wave + 4 * i) * 512 + lane * 8) = vreg[i];
        }
        __syncthreads();   // new tile visible before next QK^T
    }

    // reduce l partials, epilogue
    #pragma unroll
    for (int sp = 0; sp < 2; ++sp) {
        #pragma unroll
        for (int r = 0; r < 4; ++r) {
            float v = lp[sp][r];
            #pragma unroll
            for (int msk = 1; msk < 16; msk <<= 1) v += __shfl_xor(v, msk);
            const float inv = 1.f / v;
            ushort* op = o + (size_t)(b * SS + q0 + sp * 64 + wstrip + quad * 4 + r)
                             * (HH * DV) + h * DV;
            #pragma unroll
            for (int jd = 0; jd < 8; ++jd)
                op[jd * 16 + n] = f2bf(oacc[sp][jd][r] * inv);
        }
    }
}

// ---------------- launch ----------------
extern "C" void kernel_launch(void* const* d_in, const int* in_sizes, int n_in,
                              void* d_out, int out_size, void* d_ws, size_t ws_size,
                              hipStream_t stream) {
    const float* hs    = (const float*)d_in[0];
    const float* cosb  = (const float*)d_in[1];
    const float* sinb  = (const float*)d_in[2];
    const float* Wqa   = (const float*)d_in[3];
    const float* qa_w  = (const float*)d_in[4];
    const float* Wqb   = (const float*)d_in[5];
    const float* Wkva  = (const float*)d_in[6];
    const float* kva_w = (const float*)d_in[7];
    const float* Wkvb  = (const float*)d_in[8];
    const float* Wo    = (const float*)d_in[9];
    float* out = (float*)d_out;

    const int T = BB * SS; // 4096 tokens

    char* w = (char*)d_ws;
    auto alloc = [&](size_t bytes) {
        void* r = (void*)w;
        w += (bytes + 255) & ~(size_t)255;
        return r;
    };
    ushort* hs_bf  = (ushort*)alloc((size_t)T * DD * 2);            // 16.8 MB
    ushort* Wcat   = (ushort*)alloc((size_t)NCATP * DD * 2);        //  9.4 (pad rows 2176..2303 read-but-discarded)
    ushort* Wqbt   = (ushort*)alloc((size_t)(HH * DQ) * QL * 2);    //  9.4
    ushort* Wkvbt  = (ushort*)alloc((size_t)(HH * KVD) * KVL * 2);  //  4.2
    ushort* Wot    = (ushort*)alloc((size_t)DD * DD * 2);           //  8.4
    ushort* qa_bf  = (ushort*)alloc((size_t)T * QL * 2);            // 12.6
    ushort* Qbuf   = (ushort*)alloc((size_t)T * HH * DQ * 2);       // 25.2
    ushort* ckv_bf = (ushort*)alloc((size_t)T * CKVS * 2);          //  5.2
    ushort* kvn_bf = (ushort*)alloc((size_t)T * KVL * 2);           //  4.2
    ushort* kv_bf  = (ushort*)alloc((size_t)T * HH * KVD * 2);      // 33.6
    ushort* krb    = (ushort*)alloc((size_t)T * DR * 2);            //  0.5
    // aliases (lifetimes verified):
    ushort* Vtb    = Wcat;   // 16.8 MB over Wcat+Wqbt (dead after gemmA/gemmQ)
    ushort* ao_bf  = hs_bf;  // hs_bf dead after gemmA

    // 0. cast hs; all 5 weight transposes in ONE batched launch
    castf2bf<<<(T * DD / 4) / 256, 256, 0, stream>>>(hs, hs_bf);
    WtBatch wb;
    wb.src[0] = Wqa;  wb.dst[0] = Wcat;                      wb.K[0] = DD;  wb.N[0] = QL;       wb.nx[0] = 48;
    wb.src[1] = Wkva; wb.dst[1] = Wcat + (size_t)QL * DD;    wb.K[1] = DD;  wb.N[1] = KVL + DR; wb.nx[1] = 20;
    wb.src[2] = Wqb;  wb.dst[2] = Wqbt;                      wb.K[2] = QL;  wb.N[2] = HH * DQ;  wb.nx[2] = 96;
    wb.src[3] = Wkvb; wb.dst[3] = Wkvbt;                     wb.K[3] = KVL; wb.N[3] = HH * KVD; wb.nx[3] = 128;
    wb.src[4] = Wo;   wb.dst[4] = Wot;                       wb.K[4] = DD;  wb.N[4] = DD;       wb.nx[4] = 64;
    wb.base[0] = 0;
    wb.base[1] = wb.base[0] + wb.nx[0] * (DD / 32);   // 3072
    wb.base[2] = wb.base[1] + wb.nx[1] * (DD / 32);   // 4352
    wb.base[3] = wb.base[2] + wb.nx[2] * (QL / 32);   // 8960
    wb.base[4] = wb.base[3] + wb.nx[3] * (KVL / 32);  // 11008
    wb.base[5] = wb.base[4] + wb.nx[4] * (DD / 32);   // 15104
    wtrans_b<<<wb.base[5], 256, 0, stream>>>(wb);

    // 1. fused: qa | ckv = hs @ [Wqa | Wkva]  (256-tile, N padded to 2304)
    gemmA256<<<dim3(9 * 16), 512, 0, stream>>>(hs_bf, Wcat, qa_bf, ckv_bf);
    // 2. rmsnorm qa in place
    rmsnorm_bf_ip<<<T, 256, 0, stream>>>(qa_bf, qa_w, QL);
    // 3. Q = qa @ Wqb -> Qbuf layout, scale (incl. log2e) folded
    gemmQ256<<<dim3(12 * 16), 512, 0, stream>>>(qa_bf, Wqbt, Qbuf);
    // 4. rope Q in place (rope lanes only)
    qrope<<<T, 256, 0, stream>>>(Qbuf, cosb, sinb);
    // 5. kvn = rmsnorm(ckv[:, :512]) + roped k_rot -> krb (fused)
    rmsnorm_kv<<<T, 256, 0, stream>>>(ckv_bf, kva_w, kvn_bf, krb, cosb, sinb);
    // 6. kv = kvn @ Wkvb (bf16)
    gemm256<ushort, KVL, 16, HH * KVD><<<dim3(16 * 16), 512, 0, stream>>>(kvn_bf, Wkvbt, kv_bf);
    // 7. V transpose -> Vt
    vprep<<<dim3(SS / 32, DV / 32, BB * HH), 256, 0, stream>>>(kv_bf, Vtb);
    // 8. MFMA flash attention (q-tile 128, uniform pairing) -> ao (bf16)
    fattn_mfma<<<dim3(16, HH, BB), 256, 0, stream>>>(Qbuf, kv_bf, krb, Vtb, ao_bf);
    // 9. out = ao @ Wo (fp32), 256x128 tile -> 256 blocks (full fill)
    gemmW<DD, 16, DD><<<dim3(256), 512, 0, stream>>>(ao_bf, Wot, out);
}

// Round 5
// 423.251 us; speedup vs baseline: 1.1437x; 1.0162x over previous
//
#include <hip/hip_runtime.h>
#include <math.h>

#define BB 2
#define SS 2048
#define DD 2048
#define HH 16
#define DN 128
#define DR 64
#define DV 128
#define QL 1536
#define KVL 512
#define DQ 192           // DN + DR
#define CKVS 640         // ckv row stride (576 padded to 640)
#define KVD 256          // DN + DV
#define NCAT 2176        // QL + CKVS (fused first GEMM)
#define NCATP 2304       // NCAT padded to 9*256 for the 256-wide GEMM tile
#define EPSF 1e-6f

typedef short bfrag __attribute__((ext_vector_type(8)));   // 8 bf16 (4 VGPRs)
typedef float facc  __attribute__((ext_vector_type(4)));   // 4 fp32 acc

// ---------------- helpers ----------------
__device__ __forceinline__ ushort f2bf(float f) {
    union { float f; unsigned u; } v; v.f = f;
    unsigned r = v.u + 0x7fffu + ((v.u >> 16) & 1u);  // RNE
    return (ushort)(r >> 16);
}
__device__ __forceinline__ float bf2f(ushort u) {
    union { unsigned u; float f; } v; v.u = ((unsigned)u) << 16;
    return v.f;
}
__device__ __forceinline__ float fexp2(float x) {   // raw v_exp_f32 (2^x)
    float r; asm("v_exp_f32 %0, %1" : "=v"(r) : "v"(x)); return r;
}
__device__ __forceinline__ float wave_red_sum(float v) {
    #pragma unroll
    for (int o = 32; o > 0; o >>= 1) v += __shfl_down(v, o);
    return v;
}
__device__ __forceinline__ void gl2lds16(const ushort* g, ushort* l) {
    __builtin_amdgcn_global_load_lds(
        (const __attribute__((address_space(1))) void*)g,
        (__attribute__((address_space(3))) void*)l, 16, 0, 0);
}

// ---------------- fp32 -> bf16 cast (vectorized) ----------------
__global__ __launch_bounds__(256) void castf2bf(const float* __restrict__ x,
                                                ushort* __restrict__ y) {
    const int i = blockIdx.x * 256 + threadIdx.x;
    const float4 v = ((const float4*)x)[i];
    ushort4 o;
    o.x = f2bf(v.x); o.y = f2bf(v.y); o.z = f2bf(v.z); o.w = f2bf(v.w);
    ((ushort4*)y)[i] = o;
}

// ------- batched weight cast+transpose: 5 segments in one launch ----------
struct WtBatch {
    const float* src[5];
    ushort* dst[5];
    int K[5];
    int N[5];
    int nx[5];
    int base[6];
};
__global__ __launch_bounds__(256) void wtrans_b(WtBatch d) {
    __shared__ float tile[32][33];
    int bid = blockIdx.x;
    int seg = 0;
    while (bid >= d.base[seg + 1]) ++seg;
    const int l = bid - d.base[seg];
    const int nx = d.nx[seg];
    const int bx = l % nx, by = l / nx;
    const float* W = d.src[seg];
    ushort* Wt = d.dst[seg];
    const int K = d.K[seg], N = d.N[seg];
    const int k0 = by * 32, n0 = bx * 32;
    const int t = threadIdx.x;
    const int tx = t & 31, ty = t >> 5;
    #pragma unroll
    for (int r = 0; r < 4; ++r) {
        const int n = n0 + tx;
        tile[ty + r * 8][tx] =
            (n < N) ? W[(size_t)(k0 + ty + r * 8) * N + n] : 0.f;
    }
    __syncthreads();
    #pragma unroll
    for (int r = 0; r < 4; ++r) {
        const int n = n0 + ty + r * 8;
        Wt[(size_t)n * K + k0 + tx] = f2bf(tile[tx][ty + r * 8]);
    }
}

// ================== 256x256 8-phase MFMA GEMM (m201 template) ==============
// Caller declares __shared__ ushort L[65536] and passes a (pre-XCD-swizzled)
// linear block id LID_.  Schedule as verified r2-r4 on HW.

__device__ __forceinline__ void stage_half(const ushort* __restrict__ G,
                                           int ldg, int grow0, int kcol0,
                                           ushort* Lr, int wave, int lane) {
    const int r0   = lane >> 3;
    const int slot = (lane & 7) ^ r0;          // inverse-swizzled global slot
    const ushort* s0 = G + (size_t)(grow0 + wave * 16 + r0) * ldg + kcol0 + slot * 8;
    gl2lds16(s0,                    Lr + wave * 1024);        // rows w*16..+8
    gl2lds16(s0 + (size_t)8 * ldg,  Lr + wave * 1024 + 512);  // rows +8..+16
}

#define PH_PRE  do { __builtin_amdgcn_sched_barrier(0);                      \
                     __builtin_amdgcn_s_barrier();                           \
                     asm volatile("s_waitcnt lgkmcnt(0)" ::: "memory");      \
                     __builtin_amdgcn_sched_barrier(0);                      \
                     __builtin_amdgcn_s_setprio(1); } while (0)
#define PH_POST do { __builtin_amdgcn_s_setprio(0);                          \
                     __builtin_amdgcn_sched_barrier(0);                      \
                     __builtin_amdgcn_s_barrier(); } while (0)

#define MFMA16(RB)                                                           \
    _Pragma("unroll")                                                        \
    for (int i = 0; i < 4; ++i)                                              \
        _Pragma("unroll")                                                    \
        for (int j = 0; j < 4; ++j)                                          \
            acc[(RB) + i][j] = __builtin_amdgcn_mfma_f32_16x16x32_bf16(      \
                a[i], b[j], acc[(RB) + i][j], 0, 0, 0);

#define GEMM256_CORE(A_, Bt_, K_, NBX_, LID_)                                 \
    const int t    = threadIdx.x;                                             \
    const int lane = t & 63;                                                  \
    const int wave = t >> 6;                                                  \
    const int wm   = wave >> 2;                                               \
    const int wn   = wave & 3;                                                \
    const int quad = lane >> 4;                                               \
    const int lrow = lane & 15;                                               \
    const int bx = (LID_) % (NBX_), by = (LID_) / (NBX_);                     \
    const int m0 = by * 256, n0 = bx * 256;                                   \
    const int s0x8  = (quad ^ (lrow & 7)) * 8;   /* swizzled slot, kh=0 */    \
    const int s1x8  = s0x8 ^ 32;                 /* kh=1: slot^4          */  \
    const int abase = lrow * 64;                                              \
    const int bbase = (wn & 1) * 4096 + lrow * 64;                            \
    facc acc[8][4];                                                           \
    _Pragma("unroll")                                                         \
    for (int i = 0; i < 8; ++i)                                               \
        _Pragma("unroll")                                                     \
        for (int j = 0; j < 4; ++j) acc[i][j] = (facc)(0.f);                  \
    const int nk = (K_) >> 6;                                                 \
    /* prologue: K0 all 4 halves -> buf0; K1 B halves -> buf1 */              \
    stage_half((A_),  (K_), m0,        0, L,         wave, lane);             \
    stage_half((A_),  (K_), m0 + 128,  0, L + 8192,  wave, lane);             \
    stage_half((Bt_), (K_), n0,        0, L + 16384, wave, lane);             \
    stage_half((Bt_), (K_), n0 + 128,  0, L + 24576, wave, lane);             \
    stage_half((Bt_), (K_), n0,       64, L + 49152, wave, lane);             \
    stage_half((Bt_), (K_), n0 + 128, 64, L + 57344, wave, lane);             \
    asm volatile("s_waitcnt vmcnt(4)" ::: "memory");                          \
    __builtin_amdgcn_s_barrier();                                             \
    for (int kt = 0; kt < nk; ++kt) {                                         \
        const int p = kt & 1;                                                 \
        ushort* LA = L + p * 32768 + wm * 8192;                               \
        ushort* LB = L + p * 32768 + 16384 + (wn >> 1) * 8192;                \
        ushort* Lq = L + (p ^ 1) * 32768;                                     \
        const int kn = (kt + 1) * 64;                                         \
        bfrag a[4], b[4];                                                     \
        /* ---- q1: frags m0-3, kh0 ---- */                                   \
        _Pragma("unroll")                                                     \
        for (int i = 0; i < 4; ++i)                                           \
            a[i] = *(const bfrag*)(LA + i * 1024 + abase + s0x8);             \
        _Pragma("unroll")                                                     \
        for (int j = 0; j < 4; ++j)                                           \
            b[j] = *(const bfrag*)(LB + bbase + j * 1024 + s0x8);             \
        if (kt + 1 < nk) stage_half((A_), (K_), m0, kn, Lq, wave, lane);      \
        PH_PRE;                                                               \
        MFMA16(0)                                                             \
        PH_POST;                                                              \
        /* ---- q2: frags m4-7, kh0 (b reused) ---- */                        \
        _Pragma("unroll")                                                     \
        for (int i = 0; i < 4; ++i)                                           \
            a[i] = *(const bfrag*)(LA + (4 + i) * 1024 + abase + s0x8);       \
        if (kt + 1 < nk)                                                      \
            stage_half((A_), (K_), m0 + 128, kn, Lq + 8192, wave, lane);      \
        PH_PRE;                                                               \
        MFMA16(4)                                                             \
        PH_POST;                                                              \
        /* ---- q3: frags m0-3, kh1 ---- */                                   \
        _Pragma("unroll")                                                     \
        for (int i = 0; i < 4; ++i)                                           \
            a[i] = *(const bfrag*)(LA + i * 1024 + abase + s1x8);             \
        _Pragma("unroll")                                                     \
        for (int j = 0; j < 4; ++j)                                           \
            b[j] = *(const bfrag*)(LB + bbase + j * 1024 + s1x8);             \
        PH_PRE;                                                               \
        MFMA16(0)                                                             \
        PH_POST;                                                              \
        /* ---- q4: frags m4-7, kh1; stage B(kt+2); counted vmcnt ---- */     \
        _Pragma("unroll")                                                     \
        for (int i = 0; i < 4; ++i)                                           \
            a[i] = *(const bfrag*)(LA + (4 + i) * 1024 + abase + s1x8);       \
        if (kt + 2 < nk) {                                                    \
            stage_half((Bt_), (K_), n0,       kn + 64,                        \
                       L + p * 32768 + 16384, wave, lane);                    \
            stage_half((Bt_), (K_), n0 + 128, kn + 64,                        \
                       L + p * 32768 + 24576, wave, lane);                    \
            asm volatile("s_waitcnt vmcnt(4)" ::: "memory");                  \
        } else {                                                              \
            asm volatile("s_waitcnt vmcnt(0)" ::: "memory");                  \
        }                                                                     \
        PH_PRE;                                                               \
        MFMA16(4)                                                             \
        PH_POST;                                                              \
    }

// ====== 256x128-tile 2-phase variant (full-grid fill for M4096xN2048) ======
template <int K, int NBX, int NOUT>
__global__ __launch_bounds__(512, 2) void gemmW(const ushort* __restrict__ A,
                                                const ushort* __restrict__ Bt,
                                                float* __restrict__ C) {
    __shared__ ushort L[57344];   // 112 KiB
    const int t    = threadIdx.x;
    const int lane = t & 63;
    const int wave = t >> 6;
    const int wm   = wave >> 1;          // 0..3
    const int wn   = wave & 1;           // 0..1
    const int quad = lane >> 4;
    const int lrow = lane & 15;
    int wg = (int)blockIdx.x;
    { const int cpx = (int)gridDim.x >> 3; wg = (wg & 7) * cpx + (wg >> 3); }
    const int bx = wg % NBX, by = wg / NBX;
    const int m0 = by * 256, n0 = bx * 128;
    const int s0x8 = (quad ^ (lrow & 7)) * 8;
    const int s1x8 = s0x8 ^ 32;
    facc acc[4][4];
    #pragma unroll
    for (int i = 0; i < 4; ++i)
        #pragma unroll
        for (int j = 0; j < 4; ++j) acc[i][j] = (facc)(0.f);
    const int nk = K >> 6;
    stage_half(A,  K, m0,        0, L,          wave, lane);
    stage_half(A,  K, m0 + 128,  0, L + 8192,   wave, lane);
    stage_half(Bt, K, n0,        0, L + 32768,  wave, lane);
    stage_half(Bt, K, n0,       64, L + 40960,  wave, lane);
    asm volatile("s_waitcnt vmcnt(0)" ::: "memory");
    __builtin_amdgcn_s_barrier();
    int bp = 0, bp2 = 2;   // kt%3 and (kt+2)%3
    for (int kt = 0; kt < nk; ++kt) {
        const int p = kt & 1;
        ushort* LA = L + p * 16384 + (wm >> 1) * 8192
                       + ((wm & 1) * 64 + lrow) * 64;
        ushort* LB = L + 32768 + bp * 8192 + (wn * 64 + lrow) * 64;
        const int kn = (kt + 1) * 64;
        bfrag a[4], b[4];
        // ---- ph1: kh0 ----
        #pragma unroll
        for (int i = 0; i < 4; ++i) a[i] = *(const bfrag*)(LA + i * 1024 + s0x8);
        #pragma unroll
        for (int j = 0; j < 4; ++j) b[j] = *(const bfrag*)(LB + j * 1024 + s0x8);
        if (kt + 1 < nk) {
            stage_half(A, K, m0,       kn, L + (p ^ 1) * 16384,        wave, lane);
            stage_half(A, K, m0 + 128, kn, L + (p ^ 1) * 16384 + 8192, wave, lane);
        }
        if (kt + 2 < nk)
            stage_half(Bt, K, n0, kn + 64, L + 32768 + bp2 * 8192, wave, lane);
        PH_PRE;
        MFMA16(0)
        PH_POST;
        // ---- ph2: kh1 ----
        #pragma unroll
        for (int i = 0; i < 4; ++i) a[i] = *(const bfrag*)(LA + i * 1024 + s1x8);
        #pragma unroll
        for (int j = 0; j < 4; ++j) b[j] = *(const bfrag*)(LB + j * 1024 + s1x8);
        if (kt + 2 < nk) { asm volatile("s_waitcnt vmcnt(2)" ::: "memory"); }
        else             { asm volatile("s_waitcnt vmcnt(0)" ::: "memory"); }
        PH_PRE;
        MFMA16(0)
        PH_POST;
        bp  = (bp  == 2) ? 0 : bp  + 1;
        bp2 = (bp2 == 2) ? 0 : bp2 + 1;
    }
    #pragma unroll
    for (int m = 0; m < 4; ++m) {
        const int row = m0 + wm * 64 + m * 16 + quad * 4;
        #pragma unroll
        for (int nf = 0; nf < 4; ++nf) {
            const int col = n0 + wn * 64 + nf * 16 + lrow;
            #pragma unroll
            for (int r = 0; r < 4; ++r)
                C[(size_t)(row + r) * NOUT + col] = acc[m][nf][r];
        }
    }
}

// -------- fused GEMM A: hs @ [Wqa | Wkva] -> qa_bf, ckv_bf (N pad 2304) -----
__global__ __launch_bounds__(512, 2) void gemmA256(const ushort* __restrict__ A,
                                                   const ushort* __restrict__ Bt,
                                                   ushort* __restrict__ qa,
                                                   ushort* __restrict__ ckv) {
    __shared__ ushort L[65536];
    const int lid = ((int)blockIdx.x & 7) * 18 + ((int)blockIdx.x >> 3); // 144=18*8
    GEMM256_CORE(A, Bt, DD, 9, lid)
    #pragma unroll
    for (int m = 0; m < 8; ++m) {
        const int row = m0 + wm * 128 + m * 16 + quad * 4;
        #pragma unroll
        for (int nf = 0; nf < 4; ++nf) {
            const int col = n0 + wn * 64 + nf * 16 + lrow;
            #pragma unroll
            for (int r = 0; r < 4; ++r) {
                if (col < QL)
                    qa[(size_t)(row + r) * QL + col] = f2bf(acc[m][nf][r]);
                else if (col < NCAT)
                    ckv[(size_t)(row + r) * CKVS + col - QL] = f2bf(acc[m][nf][r]);
            }
        }
    }
}

// ------ grouped GEMM: blocks 0..191 = Q (qa@Wqb), 192..447 = kv (kvn@Wkvb) --
// Both segments run concurrently -> one balanced fill instead of two
// sequential underfilled dispatches.  Per-segment bijective XCD swizzle.
__global__ __launch_bounds__(512, 2) void gemmQKV(
    const ushort* __restrict__ qa,  const ushort* __restrict__ Wqbt,
    ushort* __restrict__ Qbuf,
    const ushort* __restrict__ kvn, const ushort* __restrict__ Wkvbt,
    ushort* __restrict__ kvb) {
    __shared__ ushort L[65536];
    const int bid = (int)blockIdx.x;
    if (bid < 192) {
        const int lid = (bid & 7) * 24 + (bid >> 3);       // 192 = 24*8
        GEMM256_CORE(qa, Wqbt, QL, 12, lid)
        const float scaling = 0.10411754831f; // 192^-0.5 * log2(e)
        #pragma unroll
        for (int m = 0; m < 8; ++m) {
            const int row = m0 + wm * 128 + m * 16 + quad * 4;
            #pragma unroll
            for (int nf = 0; nf < 4; ++nf) {
                const int col = n0 + wn * 64 + nf * 16 + lrow;
                const int h = col / DQ, d = col - h * DQ;
                #pragma unroll
                for (int r = 0; r < 4; ++r) {
                    const int tok = row + r;
                    const int b = tok >> 11, s = tok & (SS - 1);
                    Qbuf[((size_t)(b * HH + h) * SS + s) * DQ + d] =
                        f2bf(acc[m][nf][r] * scaling);
                }
            }
        }
    } else {
        const int b2 = bid - 192;
        const int lid = (b2 & 7) * 32 + (b2 >> 3);         // 256 = 32*8
        GEMM256_CORE(kvn, Wkvbt, KVL, 16, lid)
        #pragma unroll
        for (int m = 0; m < 8; ++m) {
            const int row = m0 + wm * 128 + m * 16 + quad * 4;
            #pragma unroll
            for (int nf = 0; nf < 4; ++nf) {
                const int col = n0 + wn * 64 + nf * 16 + lrow;
                #pragma unroll
                for (int r = 0; r < 4; ++r)
                    kvb[(size_t)(row + r) * (HH * KVD) + col] = f2bf(acc[m][nf][r]);
            }
        }
    }
}

// ------- merged RMSNorms: bid<T -> qa in-place; else kv norm + k_rot rope ---
__global__ __launch_bounds__(256) void rmsnorm2(ushort* __restrict__ qa,
                                                const float* __restrict__ qaw,
                                                const ushort* __restrict__ ckv,
                                                const float* __restrict__ kvw,
                                                ushort* __restrict__ kvn,
                                                ushort* __restrict__ krb,
                                                const float* __restrict__ cosb,
                                                const float* __restrict__ sinb) {
    __shared__ float red[4];
    const int t = threadIdx.x;
    const int lane = t & 63, wid = t >> 6;
    const int bid = (int)blockIdx.x;
    if (bid < BB * SS) {
        ushort* xr = qa + (size_t)bid * QL;
        float ss = 0.f;
        for (int i = t; i < QL; i += 256) { float v = bf2f(xr[i]); ss += v * v; }
        ss = wave_red_sum(ss);
        if (lane == 0) red[wid] = ss;
        __syncthreads();
        const float tot = red[0] + red[1] + red[2] + red[3];
        const float sc = rsqrtf(tot / (float)QL + EPSF);
        for (int i = t; i < QL; i += 256) xr[i] = f2bf(qaw[i] * bf2f(xr[i]) * sc);
    } else {
        const int row = bid - BB * SS;
        const ushort* xr = ckv + (size_t)row * CKVS;
        ushort* yr = kvn + (size_t)row * KVL;
        if (t < 64) {   // k_rot rope (independent of the norm)
            const int p = t;
            const ushort* kin = xr + KVL;
            const float c  = cosb[(size_t)row * DR + p];
            const float sn = sinb[(size_t)row * DR + p];
            const float self = bf2f(kin[p]);
            const float partner = bf2f(kin[p < 32 ? p + 32 : p - 32]);
            const float v = (p < 32) ? (self * c - partner * sn)
                                     : (self * c + partner * sn);
            krb[(size_t)row * DR + p] = f2bf(v);
        }
        float ss = 0.f;
        for (int i = t; i < KVL; i += 256) { float v = bf2f(xr[i]); ss += v * v; }
        ss = wave_red_sum(ss);
        if (lane == 0) red[wid] = ss;
        __syncthreads();
        const float tot = red[0] + red[1] + red[2] + red[3];
        const float sc = rsqrtf(tot / (float)KVL + EPSF);
        for (int i = t; i < KVL; i += 256) yr[i] = f2bf(kvw[i] * bf2f(xr[i]) * sc);
    }
}

// ------- merged qrope + vprep: bid<T -> rope Qbuf; else V-transpose --------
__global__ __launch_bounds__(256) void ropevprep(ushort* __restrict__ Qbuf,
                                                 const float* __restrict__ cosb,
                                                 const float* __restrict__ sinb,
                                                 const ushort* __restrict__ kvb,
                                                 ushort* __restrict__ Vtb) {
    __shared__ ushort tile[32][33];
    const int bid = (int)blockIdx.x;
    const int t = threadIdx.x;
    if (bid < BB * SS) {
        const int tok = bid;
        const int b = tok >> 11, s = tok & (SS - 1);
        const int p = t & 31, hh = t >> 5;
        const float c0 = cosb[(size_t)tok * DR + p];
        const float s0 = sinb[(size_t)tok * DR + p];
        const float c1 = cosb[(size_t)tok * DR + p + 32];
        const float s1 = sinb[(size_t)tok * DR + p + 32];
        #pragma unroll
        for (int it = 0; it < 2; ++it) {
            const int h = hh + it * 8;
            ushort* base = Qbuf + ((size_t)(b * HH + h) * SS + s) * DQ + DN;
            const float x0 = bf2f(base[p]), x1 = bf2f(base[p + 32]);
            base[p]      = f2bf(x0 * c0 - x1 * s0);
            base[p + 32] = f2bf(x1 * c1 + x0 * s1);
        }
    } else {
        const int v = bid - BB * SS;             // 0..8191
        const int kp0 = (v & 63) * 32;
        const int dv0 = ((v >> 6) & 3) * 32;
        const int bh  = v >> 8;
        const int b = bh / HH, h = bh - b * HH;
        const int tx = t & 31, ty = t >> 5;
        #pragma unroll
        for (int r = 0; r < 4; ++r)
            tile[ty + r * 8][tx] =
                kvb[(size_t)(b * SS + kp0 + ty + r * 8) * (HH * KVD) + h * KVD + DN + dv0 + tx];
        __syncthreads();
        #pragma unroll
        for (int r = 0; r < 4; ++r)
            Vtb[((size_t)bh * DV + dv0 + ty + r * 8) * SS + kp0 + tx] = tile[tx][ty + r * 8];
    }
}

// ---------------- MFMA flash attention, q-tile 128, uniform pairing -------
// v4: prefetch + LDS refill both UNCONDITIONAL (last-iter loads clamped
// in-range, last-iter refill writes dead tiles) -> the load issues live in
// the same scheduling region as the sched_barrier and cannot be sunk.
// (r3/r4 showed if(more)-guarded loads were sunk by cross-block passes:
// VGPR stayed 128.)
__global__ __launch_bounds__(256, 2) void fattn_mfma(
    const ushort* __restrict__ Qb,   // [(b*HH+h)*SS+s][192] pre-scaled+roped
    const ushort* __restrict__ kvb,  // [tok][HH*KVD]
    const ushort* __restrict__ krb,  // [tok][64]
    const ushort* __restrict__ Vt,   // [(b*HH+h)*DV+dv][SS]
    ushort* __restrict__ o)          // [tok][HH*DV]
{
    const int h  = blockIdx.y;
    const int b  = blockIdx.z;
    const int qt = b ? (15 - (int)blockIdx.x) : (int)blockIdx.x;
    const int bh = b * HH + h;
    const int q0 = qt * 128;
    const int t    = threadIdx.x;
    const int lane = t & 63;
    const int wave = t >> 6;
    const int quad = lane >> 4;
    const int n    = lane & 15;
    const int wstrip = wave * 16;

    __shared__ ushort Ksu[6 * 64 * 32];   // 24 KB
    __shared__ ushort Vtu[2 * 128 * 32];  // 16 KB
    __shared__ ushort Psu[2 * 128 * 40];  // 20 KB (padded rows)

    const ushort* vbase = Vt + (size_t)bh * DV * SS;

    // preload Q A-frags for both strips
    bfrag aQ[2][6];
    #pragma unroll
    for (int sp = 0; sp < 2; ++sp) {
        const ushort* qrow = Qb + ((size_t)bh * SS + q0 + sp * 64 + wstrip + n) * DQ;
        #pragma unroll
        for (int kb = 0; kb < 6; ++kb)
            aQ[sp][kb] = *(const bfrag*)(qrow + kb * 32 + quad * 8);
    }

    facc oacc[2][8];
    float lp[2][4];
    #pragma unroll
    for (int sp = 0; sp < 2; ++sp) {
        #pragma unroll
        for (int jd = 0; jd < 8; ++jd) oacc[sp][jd] = (facc)(0.f);
        #pragma unroll
        for (int r = 0; r < 4; ++r) lp[sp][r] = 0.f;
    }

    // prologue: stage tile kt=0 via global_load_lds
    #pragma unroll
    for (int i = 0; i < 6; ++i) {
        const int g = wave + 4 * i;
        const int kb = g >> 2;                    // wave-uniform
        const int rem = (g & 3) * 64 + lane;
        const int row = rem >> 2, sub = rem & 3;
        const int tok = b * SS + row;
        const ushort* src = (kb < 4)
            ? kvb + (size_t)tok * (HH * KVD) + h * KVD + kb * 32 + sub * 8
            : krb + (size_t)tok * DR + (kb - 4) * 32 + sub * 8;
        gl2lds16(src, Ksu + g * 512);
    }
    #pragma unroll
    for (int i = 0; i < 4; ++i) {
        const int g = wave + 4 * i;
        const int kb2 = g >> 3;                   // wave-uniform
        const int rem = (g & 7) * 64 + lane;
        const int dv = rem >> 2, sub = rem & 3;
        gl2lds16(vbase + (size_t)dv * SS + kb2 * 32 + sub * 8, Vtu + g * 512);
    }
    __syncthreads();

    const int nkt = 2 * qt + 2;
    for (int kt = 0; kt < nkt; ++kt) {
        const int k0 = kt * 64;
        const bool more = (kt + 1 < nkt);
        const int kk = more ? (k0 + 64) : (SS - 64);   // clamped prefetch base

        // ---- issue next-tile global loads into registers (UNCONDITIONAL) ---
        bfrag kreg[6], vreg[4];
        #pragma unroll
        for (int i = 0; i < 6; ++i) {
            const int g = wave + 4 * i;
            const int kb = g >> 2;
            const int rem = (g & 3) * 64 + lane;
            const int row = rem >> 2, sub = rem & 3;
            const int tok = b * SS + kk + row;
            const ushort* src = (kb < 4)
                ? kvb + (size_t)tok * (HH * KVD) + h * KVD + kb * 32 + sub * 8
                : krb + (size_t)tok * DR + (kb - 4) * 32 + sub * 8;
            kreg[i] = *(const bfrag*)src;
        }
        #pragma unroll
        for (int i = 0; i < 4; ++i) {
            const int g = wave + 4 * i;
            const int kb2 = g >> 3;
            const int rem = (g & 7) * 64 + lane;
            const int dv = rem >> 2, sub = rem & 3;
            vreg[i] = *(const bfrag*)(vbase + (size_t)dv * SS + kk + kb2 * 32 + sub * 8);
        }
        __builtin_amdgcn_sched_barrier(0);   // pin load issue BEFORE compute

        // ---- S = Q K^T, both strips share each K frag ----
        facc s[2][4];
        #pragma unroll
        for (int sp = 0; sp < 2; ++sp)
            #pragma unroll
            for (int j = 0; j < 4; ++j) s[sp][j] = (facc)(0.f);
        #pragma unroll
        for (int kb = 0; kb < 6; ++kb) {
            #pragma unroll
            for (int j = 0; j < 4; ++j) {
                const bfrag bk =
                    *(const bfrag*)&Ksu[kb * 2048 + (j * 16 + n) * 32 + quad * 8];
                s[0][j] = __builtin_amdgcn_mfma_f32_16x16x32_bf16(aQ[0][kb], bk, s[0][j], 0, 0, 0);
                s[1][j] = __builtin_amdgcn_mfma_f32_16x16x32_bf16(aQ[1][kb], bk, s[1][j], 0, 0, 0);
            }
        }

        // ---- exp2 (m=0) + causal select; P -> LDS (wave-private rows) ----
        const bool fullt = (k0 + 64 <= q0);   // tile entirely below diagonal
        if (fullt) {
            #pragma unroll
            for (int sp = 0; sp < 2; ++sp) {
                #pragma unroll
                for (int j = 0; j < 4; ++j) {
                    #pragma unroll
                    for (int r = 0; r < 4; ++r) {
                        const float p = fexp2(s[sp][j][r]);
                        lp[sp][r] += p;
                        Psu[(j >> 1) * 5120 + (sp * 64 + wstrip + quad * 4 + r) * 40
                            + (j & 1) * 16 + n] = f2bf(p);
                    }
                }
            }
        } else {
            #pragma unroll
            for (int sp = 0; sp < 2; ++sp) {
                const int rowg0 = q0 + sp * 64 + wstrip + quad * 4;
                #pragma unroll
                for (int j = 0; j < 4; ++j) {
                    const int kpos = k0 + j * 16 + n;
                    #pragma unroll
                    for (int r = 0; r < 4; ++r) {
                        const float p = (kpos <= rowg0 + r) ? fexp2(s[sp][j][r]) : 0.f;
                        lp[sp][r] += p;
                        Psu[(j >> 1) * 5120 + (sp * 64 + wstrip + quad * 4 + r) * 40
                            + (j & 1) * 16 + n] = f2bf(p);
                    }
                }
            }
        }

        // ---- O += P @ V; V frags shared across strips ----
        #pragma unroll
        for (int kb2 = 0; kb2 < 2; ++kb2) {
            const bfrag aP0 = *(const bfrag*)&Psu[kb2 * 5120 + (wstrip + n) * 40 + quad * 8];
            const bfrag aP1 = *(const bfrag*)&Psu[kb2 * 5120 + (64 + wstrip + n) * 40 + quad * 8];
            #pragma unroll
            for (int jd = 0; jd < 8; ++jd) {
                const bfrag bV = *(const bfrag*)&Vtu[kb2 * 4096 + (jd * 16 + n) * 32 + quad * 8];
                oacc[0][jd] = __builtin_amdgcn_mfma_f32_16x16x32_bf16(aP0, bV, oacc[0][jd], 0, 0, 0);
                oacc[1][jd] = __builtin_amdgcn_mfma_f32_16x16x32_bf16(aP1, bV, oacc[1][jd], 0, 0, 0);
            }
        }

        __syncthreads();   // LDS readers drained (+ drains vmcnt -> regs valid)
        // refill Ksu/Vtu from registers (UNCONDITIONAL; dead on last iter)
        #pragma unroll
        for (int i = 0; i < 6; ++i)
            *(bfrag*)(Ksu + (wave + 4 * i) * 512 + lane * 8) = kreg[i];
        #pragma unroll
        for (int i = 0; i < 4; ++i)
            *(bfrag*)(Vtu + (wave + 4 * i) * 512 + lane * 8) = vreg[i];
        __syncthreads();   // new tile visible before next QK^T
    }

    // reduce l partials, epilogue
    #pragma unroll
    for (int sp = 0; sp < 2; ++sp) {
        #pragma unroll
        for (int r = 0; r < 4; ++r) {
            float v = lp[sp][r];
            #pragma unroll
            for (int msk = 1; msk < 16; msk <<= 1) v += __shfl_xor(v, msk);
            const float inv = 1.f / v;
            ushort* op = o + (size_t)(b * SS + q0 + sp * 64 + wstrip + quad * 4 + r)
                             * (HH * DV) + h * DV;
            #pragma unroll
            for (int jd = 0; jd < 8; ++jd)
                op[jd * 16 + n] = f2bf(oacc[sp][jd][r] * inv);
        }
    }
}

// ---------------- launch ----------------
extern "C" void kernel_launch(void* const* d_in, const int* in_sizes, int n_in,
                              void* d_out, int out_size, void* d_ws, size_t ws_size,
                              hipStream_t stream) {
    const float* hs    = (const float*)d_in[0];
    const float* cosb  = (const float*)d_in[1];
    const float* sinb  = (const float*)d_in[2];
    const float* Wqa   = (const float*)d_in[3];
    const float* qa_w  = (const float*)d_in[4];
    const float* Wqb   = (const float*)d_in[5];
    const float* Wkva  = (const float*)d_in[6];
    const float* kva_w = (const float*)d_in[7];
    const float* Wkvb  = (const float*)d_in[8];
    const float* Wo    = (const float*)d_in[9];
    float* out = (float*)d_out;

    const int T = BB * SS; // 4096 tokens

    char* w = (char*)d_ws;
    auto alloc = [&](size_t bytes) {
        void* r = (void*)w;
        w += (bytes + 255) & ~(size_t)255;
        return r;
    };
    ushort* hs_bf  = (ushort*)alloc((size_t)T * DD * 2);            // 16.8 MB
    ushort* Wcat   = (ushort*)alloc((size_t)NCATP * DD * 2);        //  9.4
    ushort* Wqbt   = (ushort*)alloc((size_t)(HH * DQ) * QL * 2);    //  9.4
    ushort* Wkvbt  = (ushort*)alloc((size_t)(HH * KVD) * KVL * 2);  //  4.2
    ushort* Wot    = (ushort*)alloc((size_t)DD * DD * 2);           //  8.4
    ushort* qa_bf  = (ushort*)alloc((size_t)T * QL * 2);            // 12.6
    ushort* Qbuf   = (ushort*)alloc((size_t)T * HH * DQ * 2);       // 25.2
    ushort* ckv_bf = (ushort*)alloc((size_t)T * CKVS * 2);          //  5.2
    ushort* kvn_bf = (ushort*)alloc((size_t)T * KVL * 2);           //  4.2
    ushort* kv_bf  = (ushort*)alloc((size_t)T * HH * KVD * 2);      // 33.6
    ushort* krb    = (ushort*)alloc((size_t)T * DR * 2);            //  0.5
    // aliases (lifetimes verified):
    ushort* Vtb    = Wcat;   // over Wcat+Wqbt (dead after gemmA/gemmQKV)
    ushort* ao_bf  = hs_bf;  // hs_bf dead after gemmA

    // 0. cast hs; all 5 weight transposes in ONE batched launch
    castf2bf<<<(T * DD / 4) / 256, 256, 0, stream>>>(hs, hs_bf);
    WtBatch wb;
    wb.src[0] = Wqa;  wb.dst[0] = Wcat;                      wb.K[0] = DD;  wb.N[0] = QL;       wb.nx[0] = 48;
    wb.src[1] = Wkva; wb.dst[1] = Wcat + (size_t)QL * DD;    wb.K[1] = DD;  wb.N[1] = KVL + DR; wb.nx[1] = 20;
    wb.src[2] = Wqb;  wb.dst[2] = Wqbt;                      wb.K[2] = QL;  wb.N[2] = HH * DQ;  wb.nx[2] = 96;
    wb.src[3] = Wkvb; wb.dst[3] = Wkvbt;                     wb.K[3] = KVL; wb.N[3] = HH * KVD; wb.nx[3] = 128;
    wb.src[4] = Wo;   wb.dst[4] = Wot;                       wb.K[4] = DD;  wb.N[4] = DD;       wb.nx[4] = 64;
    wb.base[0] = 0;
    wb.base[1] = wb.base[0] + wb.nx[0] * (DD / 32);   // 3072
    wb.base[2] = wb.base[1] + wb.nx[1] * (DD / 32);   // 4352
    wb.base[3] = wb.base[2] + wb.nx[2] * (QL / 32);   // 8960
    wb.base[4] = wb.base[3] + wb.nx[3] * (KVL / 32);  // 11008
    wb.base[5] = wb.base[4] + wb.nx[4] * (DD / 32);   // 15104
    wtrans_b<<<wb.base[5], 256, 0, stream>>>(wb);

    // 1. fused: qa | ckv = hs @ [Wqa | Wkva]
    gemmA256<<<dim3(144), 512, 0, stream>>>(hs_bf, Wcat, qa_bf, ckv_bf);
    // 2. both RMSNorms (qa in-place; ckv->kvn + k_rot rope) in ONE launch
    rmsnorm2<<<2 * T, 256, 0, stream>>>(qa_bf, qa_w, ckv_bf, kva_w, kvn_bf,
                                        krb, cosb, sinb);
    // 3. grouped GEMM: Q (qa@Wqb -> Qbuf, scale folded) + kv (kvn@Wkvb)
    gemmQKV<<<dim3(448), 512, 0, stream>>>(qa_bf, Wqbt, Qbuf,
                                           kvn_bf, Wkvbt, kv_bf);
    // 4. rope Q + V transpose in ONE launch
    ropevprep<<<T + 8192, 256, 0, stream>>>(Qbuf, cosb, sinb, kv_bf, Vtb);
    // 5. MFMA flash attention -> ao (bf16)
    fattn_mfma<<<dim3(16, HH, BB), 256, 0, stream>>>(Qbuf, kv_bf, krb, Vtb, ao_bf);
    // 6. out = ao @ Wo (fp32), 256x128 tile -> 256 blocks (full fill)
    gemmW<DD, 16, DD><<<dim3(256), 512, 0, stream>>>(ao_bf, Wot, out);
}

// Round 6
// 414.268 us; speedup vs baseline: 1.1685x; 1.0217x over previous
//
#include <hip/hip_runtime.h>
#include <math.h>

#define BB 2
#define SS 2048
#define DD 2048
#define HH 16
#define DN 128
#define DR 64
#define DV 128
#define QL 1536
#define KVL 512
#define DQ 192           // DN + DR
#define CKVS 640         // ckv row stride (576 padded to 640)
#define KVD 256          // DN + DV
#define NCAT 2176        // QL + CKVS (fused first GEMM)
#define NCATP 2304       // NCAT padded to 9*256 for the 256-wide GEMM tile
#define EPSF 1e-6f

typedef short bfrag __attribute__((ext_vector_type(8)));   // 8 bf16 (4 VGPRs)
typedef float facc  __attribute__((ext_vector_type(4)));   // 4 fp32 acc

// ---------------- helpers ----------------
__device__ __forceinline__ ushort f2bf(float f) {
    union { float f; unsigned u; } v; v.f = f;
    unsigned r = v.u + 0x7fffu + ((v.u >> 16) & 1u);  // RNE
    return (ushort)(r >> 16);
}
__device__ __forceinline__ float bf2f(ushort u) {
    union { unsigned u; float f; } v; v.u = ((unsigned)u) << 16;
    return v.f;
}
__device__ __forceinline__ float fexp2(float x) {   // raw v_exp_f32 (2^x)
    float r; asm("v_exp_f32 %0, %1" : "=v"(r) : "v"(x)); return r;
}
__device__ __forceinline__ float wave_red_sum(float v) {
    #pragma unroll
    for (int o = 32; o > 0; o >>= 1) v += __shfl_down(v, o);
    return v;
}
__device__ __forceinline__ void gl2lds16(const ushort* g, ushort* l) {
    __builtin_amdgcn_global_load_lds(
        (const __attribute__((address_space(1))) void*)g,
        (__attribute__((address_space(3))) void*)l, 16, 0, 0);
}

// ---------------- fp32 -> bf16 cast (vectorized) ----------------
__global__ __launch_bounds__(256) void castf2bf(const float* __restrict__ x,
                                                ushort* __restrict__ y) {
    const int i = blockIdx.x * 256 + threadIdx.x;
    const float4 v = ((const float4*)x)[i];
    ushort4 o;
    o.x = f2bf(v.x); o.y = f2bf(v.y); o.z = f2bf(v.z); o.w = f2bf(v.w);
    ((ushort4*)y)[i] = o;
}

// ------- batched weight cast+transpose (now only Wqa, Wkva) ----------
struct WtBatch {
    const float* src[2];
    ushort* dst[2];
    int K[2];
    int N[2];
    int nx[2];
    int base[3];
};
__global__ __launch_bounds__(256) void wtrans_b(WtBatch d) {
    __shared__ float tile[32][33];
    int bid = blockIdx.x;
    int seg = (bid >= d.base[1]) ? 1 : 0;
    const int l = bid - d.base[seg];
    const int nx = d.nx[seg];
    const int bx = l % nx, by = l / nx;
    const float* W = d.src[seg];
    ushort* Wt = d.dst[seg];
    const int K = d.K[seg], N = d.N[seg];
    const int k0 = by * 32, n0 = bx * 32;
    const int t = threadIdx.x;
    const int tx = t & 31, ty = t >> 5;
    #pragma unroll
    for (int r = 0; r < 4; ++r) {
        const int n = n0 + tx;
        tile[ty + r * 8][tx] =
            (n < N) ? W[(size_t)(k0 + ty + r * 8) * N + n] : 0.f;
    }
    __syncthreads();
    #pragma unroll
    for (int r = 0; r < 4; ++r) {
        const int n = n0 + ty + r * 8;
        Wt[(size_t)n * K + k0 + tx] = f2bf(tile[tx][ty + r * 8]);
    }
}

// ================== 256x256 8-phase MFMA GEMM core (m201 template) =========
// Caller declares __shared__ ushort L[65536] and passes pre-swizzled LID_.

__device__ __forceinline__ void stage_half(const ushort* __restrict__ G,
                                           int ldg, int grow0, int kcol0,
                                           ushort* Lr, int wave, int lane) {
    const int r0   = lane >> 3;
    const int slot = (lane & 7) ^ r0;          // inverse-swizzled global slot
    const ushort* s0 = G + (size_t)(grow0 + wave * 16 + r0) * ldg + kcol0 + slot * 8;
    gl2lds16(s0,                    Lr + wave * 1024);        // rows w*16..+8
    gl2lds16(s0 + (size_t)8 * ldg,  Lr + wave * 1024 + 512);  // rows +8..+16
}

#define PH_PRE  do { __builtin_amdgcn_sched_barrier(0);                      \
                     __builtin_amdgcn_s_barrier();                           \
                     asm volatile("s_waitcnt lgkmcnt(0)" ::: "memory");      \
                     __builtin_amdgcn_sched_barrier(0);                      \
                     __builtin_amdgcn_s_setprio(1); } while (0)
#define PH_POST do { __builtin_amdgcn_s_setprio(0);                          \
                     __builtin_amdgcn_sched_barrier(0);                      \
                     __builtin_amdgcn_s_barrier(); } while (0)

#define MFMA16(RB)                                                           \
    _Pragma("unroll")                                                        \
    for (int i = 0; i < 4; ++i)                                              \
        _Pragma("unroll")                                                    \
        for (int j = 0; j < 4; ++j)                                          \
            acc[(RB) + i][j] = __builtin_amdgcn_mfma_f32_16x16x32_bf16(      \
                a[i], b[j], acc[(RB) + i][j], 0, 0, 0);

#define GEMM256_CORE(A_, Bt_, K_, NBX_, LID_)                                 \
    const int t    = threadIdx.x;                                             \
    const int lane = t & 63;                                                  \
    const int wave = t >> 6;                                                  \
    const int wm   = wave >> 2;                                               \
    const int wn   = wave & 3;                                                \
    const int quad = lane >> 4;                                               \
    const int lrow = lane & 15;                                               \
    const int bx = (LID_) % (NBX_), by = (LID_) / (NBX_);                     \
    const int m0 = by * 256, n0 = bx * 256;                                   \
    const int s0x8  = (quad ^ (lrow & 7)) * 8;   /* swizzled slot, kh=0 */    \
    const int s1x8  = s0x8 ^ 32;                 /* kh=1: slot^4          */  \
    const int abase = lrow * 64;                                              \
    const int bbase = (wn & 1) * 4096 + lrow * 64;                            \
    facc acc[8][4];                                                           \
    _Pragma("unroll")                                                         \
    for (int i = 0; i < 8; ++i)                                               \
        _Pragma("unroll")                                                     \
        for (int j = 0; j < 4; ++j) acc[i][j] = (facc)(0.f);                  \
    const int nk = (K_) >> 6;                                                 \
    stage_half((A_),  (K_), m0,        0, L,         wave, lane);             \
    stage_half((A_),  (K_), m0 + 128,  0, L + 8192,  wave, lane);             \
    stage_half((Bt_), (K_), n0,        0, L + 16384, wave, lane);             \
    stage_half((Bt_), (K_), n0 + 128,  0, L + 24576, wave, lane);             \
    stage_half((Bt_), (K_), n0,       64, L + 49152, wave, lane);             \
    stage_half((Bt_), (K_), n0 + 128, 64, L + 57344, wave, lane);             \
    asm volatile("s_waitcnt vmcnt(4)" ::: "memory");                          \
    __builtin_amdgcn_s_barrier();                                             \
    for (int kt = 0; kt < nk; ++kt) {                                         \
        const int p = kt & 1;                                                 \
        ushort* LA = L + p * 32768 + wm * 8192;                               \
        ushort* LB = L + p * 32768 + 16384 + (wn >> 1) * 8192;                \
        ushort* Lq = L + (p ^ 1) * 32768;                                     \
        const int kn = (kt + 1) * 64;                                         \
        bfrag a[4], b[4];                                                     \
        _Pragma("unroll")                                                     \
        for (int i = 0; i < 4; ++i)                                           \
            a[i] = *(const bfrag*)(LA + i * 1024 + abase + s0x8);             \
        _Pragma("unroll")                                                     \
        for (int j = 0; j < 4; ++j)                                           \
            b[j] = *(const bfrag*)(LB + bbase + j * 1024 + s0x8);             \
        if (kt + 1 < nk) stage_half((A_), (K_), m0, kn, Lq, wave, lane);      \
        PH_PRE;                                                               \
        MFMA16(0)                                                             \
        PH_POST;                                                              \
        _Pragma("unroll")                                                     \
        for (int i = 0; i < 4; ++i)                                           \
            a[i] = *(const bfrag*)(LA + (4 + i) * 1024 + abase + s0x8);       \
        if (kt + 1 < nk)                                                      \
            stage_half((A_), (K_), m0 + 128, kn, Lq + 8192, wave, lane);      \
        PH_PRE;                                                               \
        MFMA16(4)                                                             \
        PH_POST;                                                              \
        _Pragma("unroll")                                                     \
        for (int i = 0; i < 4; ++i)                                           \
            a[i] = *(const bfrag*)(LA + i * 1024 + abase + s1x8);             \
        _Pragma("unroll")                                                     \
        for (int j = 0; j < 4; ++j)                                           \
            b[j] = *(const bfrag*)(LB + bbase + j * 1024 + s1x8);             \
        PH_PRE;                                                               \
        MFMA16(0)                                                             \
        PH_POST;                                                              \
        _Pragma("unroll")                                                     \
        for (int i = 0; i < 4; ++i)                                           \
            a[i] = *(const bfrag*)(LA + (4 + i) * 1024 + abase + s1x8);       \
        if (kt + 2 < nk) {                                                    \
            stage_half((Bt_), (K_), n0,       kn + 64,                        \
                       L + p * 32768 + 16384, wave, lane);                    \
            stage_half((Bt_), (K_), n0 + 128, kn + 64,                        \
                       L + p * 32768 + 24576, wave, lane);                    \
            asm volatile("s_waitcnt vmcnt(4)" ::: "memory");                  \
        } else {                                                              \
            asm volatile("s_waitcnt vmcnt(0)" ::: "memory");                  \
        }                                                                     \
        PH_PRE;                                                               \
        MFMA16(4)                                                             \
        PH_POST;                                                              \
    }

// ====== 256x128-tile 2-phase core (full-fill variant; schedule per r4/r5) ===
#define GEMMW_CORE(A_, Bt_, K_, NBX_, LID_)                                   \
    const int t    = threadIdx.x;                                             \
    const int lane = t & 63;                                                  \
    const int wave = t >> 6;                                                  \
    const int wm   = wave >> 1;          /* 0..3 */                           \
    const int wn   = wave & 1;           /* 0..1 */                           \
    const int quad = lane >> 4;                                               \
    const int lrow = lane & 15;                                               \
    const int bx = (LID_) % (NBX_), by = (LID_) / (NBX_);                     \
    const int m0 = by * 256, n0 = bx * 128;                                   \
    const int s0x8 = (quad ^ (lrow & 7)) * 8;                                 \
    const int s1x8 = s0x8 ^ 32;                                               \
    facc acc[4][4];                                                           \
    _Pragma("unroll")                                                         \
    for (int i = 0; i < 4; ++i)                                               \
        _Pragma("unroll")                                                     \
        for (int j = 0; j < 4; ++j) acc[i][j] = (facc)(0.f);                  \
    const int nk = (K_) >> 6;                                                 \
    stage_half((A_),  (K_), m0,        0, L,          wave, lane);            \
    stage_half((A_),  (K_), m0 + 128,  0, L + 8192,   wave, lane);            \
    stage_half((Bt_), (K_), n0,        0, L + 32768,  wave, lane);            \
    stage_half((Bt_), (K_), n0,       64, L + 40960,  wave, lane);            \
    asm volatile("s_waitcnt vmcnt(0)" ::: "memory");                          \
    __builtin_amdgcn_s_barrier();                                             \
    int bp = 0, bp2 = 2;   /* kt%3 and (kt+2)%3 */                            \
    for (int kt = 0; kt < nk; ++kt) {                                         \
        const int p = kt & 1;                                                 \
        ushort* LA = L + p * 16384 + (wm >> 1) * 8192                         \
                       + ((wm & 1) * 64 + lrow) * 64;                         \
        ushort* LB = L + 32768 + bp * 8192 + (wn * 64 + lrow) * 64;           \
        const int kn = (kt + 1) * 64;                                         \
        bfrag a[4], b[4];                                                     \
        _Pragma("unroll")                                                     \
        for (int i = 0; i < 4; ++i) a[i] = *(const bfrag*)(LA + i * 1024 + s0x8); \
        _Pragma("unroll")                                                     \
        for (int j = 0; j < 4; ++j) b[j] = *(const bfrag*)(LB + j * 1024 + s0x8); \
        if (kt + 1 < nk) {                                                    \
            stage_half((A_), (K_), m0,       kn, L + (p ^ 1) * 16384,        wave, lane); \
            stage_half((A_), (K_), m0 + 128, kn, L + (p ^ 1) * 16384 + 8192, wave, lane); \
        }                                                                     \
        if (kt + 2 < nk)                                                      \
            stage_half((Bt_), (K_), n0, kn + 64, L + 32768 + bp2 * 8192, wave, lane); \
        PH_PRE;                                                               \
        MFMA16(0)                                                             \
        PH_POST;                                                              \
        _Pragma("unroll")                                                     \
        for (int i = 0; i < 4; ++i) a[i] = *(const bfrag*)(LA + i * 1024 + s1x8); \
        _Pragma("unroll")                                                     \
        for (int j = 0; j < 4; ++j) b[j] = *(const bfrag*)(LB + j * 1024 + s1x8); \
        if (kt + 2 < nk) { asm volatile("s_waitcnt vmcnt(2)" ::: "memory"); } \
        else             { asm volatile("s_waitcnt vmcnt(0)" ::: "memory"); } \
        PH_PRE;                                                               \
        MFMA16(0)                                                             \
        PH_POST;                                                              \
        bp  = (bp  == 2) ? 0 : bp  + 1;                                       \
        bp2 = (bp2 == 2) ? 0 : bp2 + 1;                                       \
    }

// ------- gemmW: out = ao @ Wo (fp32), 256x128 tiles, full 256-block fill ----
template <int K, int NBX, int NOUT>
__global__ __launch_bounds__(512, 2) void gemmW(const ushort* __restrict__ A,
                                                const ushort* __restrict__ Bt,
                                                float* __restrict__ C) {
    __shared__ ushort L[57344];   // 112 KiB
    int wg = (int)blockIdx.x;
    { const int cpx = (int)gridDim.x >> 3; wg = (wg & 7) * cpx + (wg >> 3); }
    GEMMW_CORE(A, Bt, K, NBX, wg)
    #pragma unroll
    for (int m = 0; m < 4; ++m) {
        const int row = m0 + wm * 64 + m * 16 + quad * 4;
        #pragma unroll
        for (int nf = 0; nf < 4; ++nf) {
            const int col = n0 + wn * 64 + nf * 16 + lrow;
            #pragma unroll
            for (int r = 0; r < 4; ++r)
                C[(size_t)(row + r) * NOUT + col] = acc[m][nf][r];
        }
    }
}

// ====== gemmAW: gemmA (144 x 256^2 blocks) + 112 transpose-walker blocks ====
// gemmA fills only 144/256 CUs; the 112 walkers cast+transpose Wqb/Wkvb/Wo
// (10752 32x32 tiles = 5376 pairs = 112 x 48) on the otherwise-idle CUs.
// Grid = 256 = exactly 1 block/CU (LDS 128KB/block).
__global__ __launch_bounds__(512, 2) void gemmAW(
    const ushort* __restrict__ A,   const ushort* __restrict__ Bt,
    ushort* __restrict__ qa,        ushort* __restrict__ ckv,
    const float* __restrict__ Wqb,  ushort* __restrict__ Wqbt,
    const float* __restrict__ Wkvb, ushort* __restrict__ Wkvbt,
    const float* __restrict__ Wo,   ushort* __restrict__ Wot) {
    __shared__ ushort L[65536];
    const int bid = (int)blockIdx.x;
    if (bid < 144) {
        const int lid = (bid & 7) * 18 + (bid >> 3);   // 144 = 18*8 bijective
        GEMM256_CORE(A, Bt, DD, 9, lid)
        #pragma unroll
        for (int m = 0; m < 8; ++m) {
            const int row = m0 + wm * 128 + m * 16 + quad * 4;
            #pragma unroll
            for (int nf = 0; nf < 4; ++nf) {
                const int col = n0 + wn * 64 + nf * 16 + lrow;
                #pragma unroll
                for (int r = 0; r < 4; ++r) {
                    if (col < QL)
                        qa[(size_t)(row + r) * QL + col] = f2bf(acc[m][nf][r]);
                    else if (col < NCAT)
                        ckv[(size_t)(row + r) * CKVS + col - QL] = f2bf(acc[m][nf][r]);
                }
            }
        }
    } else {
        const int wid = bid - 144;            // 0..111
        const int t   = threadIdx.x;
        const int half = t >> 8;              // two 256-thread halves
        const int tl = t & 255;
        const int tx = tl & 31, ty = tl >> 5;
        float (*tile)[33] = (float(*)[33])((float*)L + half * 32 * 33);
        for (int it = 0; it < 48; ++it) {
            const int idx = (it * 112 + wid) * 2 + half;   // 0..10751
            const float* W; ushort* Wt; int K, N, nx, l;
            if (idx < 4608)      { l = idx;        W = Wqb;  Wt = Wqbt;  K = QL;  N = HH * DQ;  nx = 96; }
            else if (idx < 6656) { l = idx - 4608; W = Wkvb; Wt = Wkvbt; K = KVL; N = HH * KVD; nx = 128; }
            else                 { l = idx - 6656; W = Wo;   Wt = Wot;   K = DD;  N = DD;       nx = 64; }
            const int bx2 = l % nx, by2 = l / nx;
            const int k0 = by2 * 32, n0w = bx2 * 32;
            #pragma unroll
            for (int r = 0; r < 4; ++r)
                tile[ty + r * 8][tx] = W[(size_t)(k0 + ty + r * 8) * N + n0w + tx];
            __syncthreads();
            #pragma unroll
            for (int r = 0; r < 4; ++r)
                Wt[(size_t)(n0w + ty + r * 8) * K + k0 + tx] = f2bf(tile[tx][ty + r * 8]);
            __syncthreads();
        }
    }
}

// ------ grouped GEMM on 256x128 tiles: blocks 0..383 = Q, 384..895 = kv -----
// Fine granularity balances the long-Q/short-kv mix across all 256 CUs
// (the old 256^2 split left 192 Q-CUs idle while 64 CUs ran 4 kv rounds).
__global__ __launch_bounds__(512, 2) void gemmQKV(
    const ushort* __restrict__ qa,  const ushort* __restrict__ Wqbt,
    ushort* __restrict__ Qbuf,
    const ushort* __restrict__ kvn, const ushort* __restrict__ Wkvbt,
    ushort* __restrict__ kvb) {
    __shared__ ushort L[57344];
    const int bid = (int)blockIdx.x;
    if (bid < 384) {
        const int lid = (bid & 7) * 48 + (bid >> 3);   // 384 = 48*8
        GEMMW_CORE(qa, Wqbt, QL, 24, lid)              // N=3072 -> 24 cols
        const float scaling = 0.10411754831f; // 192^-0.5 * log2(e)
        #pragma unroll
        for (int m = 0; m < 4; ++m) {
            const int row = m0 + wm * 64 + m * 16 + quad * 4;
            #pragma unroll
            for (int nf = 0; nf < 4; ++nf) {
                const int col = n0 + wn * 64 + nf * 16 + lrow;
                const int h = col / DQ, d = col - h * DQ;
                #pragma unroll
                for (int r = 0; r < 4; ++r) {
                    const int tok = row + r;
                    const int b = tok >> 11, s2 = tok & (SS - 1);
                    Qbuf[((size_t)(b * HH + h) * SS + s2) * DQ + d] =
                        f2bf(acc[m][nf][r] * scaling);
                }
            }
        }
    } else {
        const int b2 = bid - 384;
        const int lid = (b2 & 7) * 64 + (b2 >> 3);     // 512 = 64*8
        GEMMW_CORE(kvn, Wkvbt, KVL, 32, lid)           // N=4096 -> 32 cols
        #pragma unroll
        for (int m = 0; m < 4; ++m) {
            const int row = m0 + wm * 64 + m * 16 + quad * 4;
            #pragma unroll
            for (int nf = 0; nf < 4; ++nf) {
                const int col = n0 + wn * 64 + nf * 16 + lrow;
                #pragma unroll
                for (int r = 0; r < 4; ++r)
                    kvb[(size_t)(row + r) * (HH * KVD) + col] = f2bf(acc[m][nf][r]);
            }
        }
    }
}

// ------- merged RMSNorms: bid<T -> qa in-place; else kv norm + k_rot rope ---
__global__ __launch_bounds__(256) void rmsnorm2(ushort* __restrict__ qa,
                                                const float* __restrict__ qaw,
                                                const ushort* __restrict__ ckv,
                                                const float* __restrict__ kvw,
                                                ushort* __restrict__ kvn,
                                                ushort* __restrict__ krb,
                                                const float* __restrict__ cosb,
                                                const float* __restrict__ sinb) {
    __shared__ float red[4];
    const int t = threadIdx.x;
    const int lane = t & 63, wid = t >> 6;
    const int bid = (int)blockIdx.x;
    if (bid < BB * SS) {
        ushort* xr = qa + (size_t)bid * QL;
        float ss = 0.f;
        for (int i = t; i < QL; i += 256) { float v = bf2f(xr[i]); ss += v * v; }
        ss = wave_red_sum(ss);
        if (lane == 0) red[wid] = ss;
        __syncthreads();
        const float tot = red[0] + red[1] + red[2] + red[3];
        const float sc = rsqrtf(tot / (float)QL + EPSF);
        for (int i = t; i < QL; i += 256) xr[i] = f2bf(qaw[i] * bf2f(xr[i]) * sc);
    } else {
        const int row = bid - BB * SS;
        const ushort* xr = ckv + (size_t)row * CKVS;
        ushort* yr = kvn + (size_t)row * KVL;
        if (t < 64) {   // k_rot rope (independent of the norm)
            const int p = t;
            const ushort* kin = xr + KVL;
            const float c  = cosb[(size_t)row * DR + p];
            const float sn = sinb[(size_t)row * DR + p];
            const float self = bf2f(kin[p]);
            const float partner = bf2f(kin[p < 32 ? p + 32 : p - 32]);
            const float v = (p < 32) ? (self * c - partner * sn)
                                     : (self * c + partner * sn);
            krb[(size_t)row * DR + p] = f2bf(v);
        }
        float ss = 0.f;
        for (int i = t; i < KVL; i += 256) { float v = bf2f(xr[i]); ss += v * v; }
        ss = wave_red_sum(ss);
        if (lane == 0) red[wid] = ss;
        __syncthreads();
        const float tot = red[0] + red[1] + red[2] + red[3];
        const float sc = rsqrtf(tot / (float)KVL + EPSF);
        for (int i = t; i < KVL; i += 256) yr[i] = f2bf(kvw[i] * bf2f(xr[i]) * sc);
    }
}

// ------- merged qrope + vprep: bid<T -> rope Qbuf; else V-transpose --------
__global__ __launch_bounds__(256) void ropevprep(ushort* __restrict__ Qbuf,
                                                 const float* __restrict__ cosb,
                                                 const float* __restrict__ sinb,
                                                 const ushort* __restrict__ kvb,
                                                 ushort* __restrict__ Vtb) {
    __shared__ ushort tile[32][33];
    const int bid = (int)blockIdx.x;
    const int t = threadIdx.x;
    if (bid < BB * SS) {
        const int tok = bid;
        const int b = tok >> 11, s = tok & (SS - 1);
        const int p = t & 31, hh = t >> 5;
        const float c0 = cosb[(size_t)tok * DR + p];
        const float s0 = sinb[(size_t)tok * DR + p];
        const float c1 = cosb[(size_t)tok * DR + p + 32];
        const float s1 = sinb[(size_t)tok * DR + p + 32];
        #pragma unroll
        for (int it = 0; it < 2; ++it) {
            const int h = hh + it * 8;
            ushort* base = Qbuf + ((size_t)(b * HH + h) * SS + s) * DQ + DN;
            const float x0 = bf2f(base[p]), x1 = bf2f(base[p + 32]);
            base[p]      = f2bf(x0 * c0 - x1 * s0);
            base[p + 32] = f2bf(x1 * c1 + x0 * s1);
        }
    } else {
        const int v = bid - BB * SS;             // 0..8191
        const int kp0 = (v & 63) * 32;
        const int dv0 = ((v >> 6) & 3) * 32;
        const int bh  = v >> 8;
        const int b = bh / HH, h = bh - b * HH;
        const int tx = t & 31, ty = t >> 5;
        #pragma unroll
        for (int r = 0; r < 4; ++r)
            tile[ty + r * 8][tx] =
                kvb[(size_t)(b * SS + kp0 + ty + r * 8) * (HH * KVD) + h * KVD + DN + dv0 + tx];
        __syncthreads();
        #pragma unroll
        for (int r = 0; r < 4; ++r)
            Vtb[((size_t)bh * DV + dv0 + ty + r * 8) * SS + kp0 + tx] = tile[tx][ty + r * 8];
    }
}

// ---------------- MFMA flash attention (v4 structure, unchanged) ----------
__global__ __launch_bounds__(256, 2) void fattn_mfma(
    const ushort* __restrict__ Qb,   // [(b*HH+h)*SS+s][192] pre-scaled+roped
    const ushort* __restrict__ kvb,  // [tok][HH*KVD]
    const ushort* __restrict__ krb,  // [tok][64]
    const ushort* __restrict__ Vt,   // [(b*HH+h)*DV+dv][SS]
    ushort* __restrict__ o)          // [tok][HH*DV]
{
    const int h  = blockIdx.y;
    const int b  = blockIdx.z;
    const int qt = b ? (15 - (int)blockIdx.x) : (int)blockIdx.x;
    const int bh = b * HH + h;
    const int q0 = qt * 128;
    const int t    = threadIdx.x;
    const int lane = t & 63;
    const int wave = t >> 6;
    const int quad = lane >> 4;
    const int n    = lane & 15;
    const int wstrip = wave * 16;

    __shared__ ushort Ksu[6 * 64 * 32];   // 24 KB
    __shared__ ushort Vtu[2 * 128 * 32];  // 16 KB
    __shared__ ushort Psu[2 * 128 * 40];  // 20 KB (padded rows)

    const ushort* vbase = Vt + (size_t)bh * DV * SS;

    // preload Q A-frags for both strips
    bfrag aQ[2][6];
    #pragma unroll
    for (int sp = 0; sp < 2; ++sp) {
        const ushort* qrow = Qb + ((size_t)bh * SS + q0 + sp * 64 + wstrip + n) * DQ;
        #pragma unroll
        for (int kb = 0; kb < 6; ++kb)
            aQ[sp][kb] = *(const bfrag*)(qrow + kb * 32 + quad * 8);
    }

    facc oacc[2][8];
    float lp[2][4];
    #pragma unroll
    for (int sp = 0; sp < 2; ++sp) {
        #pragma unroll
        for (int jd = 0; jd < 8; ++jd) oacc[sp][jd] = (facc)(0.f);
        #pragma unroll
        for (int r = 0; r < 4; ++r) lp[sp][r] = 0.f;
    }

    // prologue: stage tile kt=0 via global_load_lds
    #pragma unroll
    for (int i = 0; i < 6; ++i) {
        const int g = wave + 4 * i;
        const int kb = g >> 2;                    // wave-uniform
        const int rem = (g & 3) * 64 + lane;
        const int row = rem >> 2, sub = rem & 3;
        const int tok = b * SS + row;
        const ushort* src = (kb < 4)
            ? kvb + (size_t)tok * (HH * KVD) + h * KVD + kb * 32 + sub * 8
            : krb + (size_t)tok * DR + (kb - 4) * 32 + sub * 8;
        gl2lds16(src, Ksu + g * 512);
    }
    #pragma unroll
    for (int i = 0; i < 4; ++i) {
        const int g = wave + 4 * i;
        const int kb2 = g >> 3;                   // wave-uniform
        const int rem = (g & 7) * 64 + lane;
        const int dv = rem >> 2, sub = rem & 3;
        gl2lds16(vbase + (size_t)dv * SS + kb2 * 32 + sub * 8, Vtu + g * 512);
    }
    __syncthreads();

    const int nkt = 2 * qt + 2;
    for (int kt = 0; kt < nkt; ++kt) {
        const int k0 = kt * 64;
        const int kk = (kt + 1 < nkt) ? (k0 + 64) : (SS - 64);  // clamped

        // ---- issue next-tile global loads into registers (UNCONDITIONAL) ---
        bfrag kreg[6], vreg[4];
        #pragma unroll
        for (int i = 0; i < 6; ++i) {
            const int g = wave + 4 * i;
            const int kb = g >> 2;
            const int rem = (g & 3) * 64 + lane;
            const int row = rem >> 2, sub = rem & 3;
            const int tok = b * SS + kk + row;
            const ushort* src = (kb < 4)
                ? kvb + (size_t)tok * (HH * KVD) + h * KVD + kb * 32 + sub * 8
                : krb + (size_t)tok * DR + (kb - 4) * 32 + sub * 8;
            kreg[i] = *(const bfrag*)src;
        }
        #pragma unroll
        for (int i = 0; i < 4; ++i) {
            const int g = wave + 4 * i;
            const int kb2 = g >> 3;
            const int rem = (g & 7) * 64 + lane;
            const int dv = rem >> 2, sub = rem & 3;
            vreg[i] = *(const bfrag*)(vbase + (size_t)dv * SS + kk + kb2 * 32 + sub * 8);
        }
        __builtin_amdgcn_sched_barrier(0);   // pin load issue BEFORE compute

        // ---- S = Q K^T, both strips share each K frag ----
        facc s[2][4];
        #pragma unroll
        for (int sp = 0; sp < 2; ++sp)
            #pragma unroll
            for (int j = 0; j < 4; ++j) s[sp][j] = (facc)(0.f);
        #pragma unroll
        for (int kb = 0; kb < 6; ++kb) {
            #pragma unroll
            for (int j = 0; j < 4; ++j) {
                const bfrag bk =
                    *(const bfrag*)&Ksu[kb * 2048 + (j * 16 + n) * 32 + quad * 8];
                s[0][j] = __builtin_amdgcn_mfma_f32_16x16x32_bf16(aQ[0][kb], bk, s[0][j], 0, 0, 0);
                s[1][j] = __builtin_amdgcn_mfma_f32_16x16x32_bf16(aQ[1][kb], bk, s[1][j], 0, 0, 0);
            }
        }

        // ---- exp2 (m=0) + causal select; P -> LDS (wave-private rows) ----
        const bool fullt = (k0 + 64 <= q0);   // tile entirely below diagonal
        if (fullt) {
            #pragma unroll
            for (int sp = 0; sp < 2; ++sp) {
                #pragma unroll
                for (int j = 0; j < 4; ++j) {
                    #pragma unroll
                    for (int r = 0; r < 4; ++r) {
                        const float p = fexp2(s[sp][j][r]);
                        lp[sp][r] += p;
                        Psu[(j >> 1) * 5120 + (sp * 64 + wstrip + quad * 4 + r) * 40
                            + (j & 1) * 16 + n] = f2bf(p);
                    }
                }
            }
        } else {
            #pragma unroll
            for (int sp = 0; sp < 2; ++sp) {
                const int rowg0 = q0 + sp * 64 + wstrip + quad * 4;
                #pragma unroll
                for (int j = 0; j < 4; ++j) {
                    const int kpos = k0 + j * 16 + n;
                    #pragma unroll
                    for (int r = 0; r < 4; ++r) {
                        const float p = (kpos <= rowg0 + r) ? fexp2(s[sp][j][r]) : 0.f;
                        lp[sp][r] += p;
                        Psu[(j >> 1) * 5120 + (sp * 64 + wstrip + quad * 4 + r) * 40
                            + (j & 1) * 16 + n] = f2bf(p);
                    }
                }
            }
        }

        // ---- O += P @ V; V frags shared across strips ----
        #pragma unroll
        for (int kb2 = 0; kb2 < 2; ++kb2) {
            const bfrag aP0 = *(const bfrag*)&Psu[kb2 * 5120 + (wstrip + n) * 40 + quad * 8];
            const bfrag aP1 = *(const bfrag*)&Psu[kb2 * 5120 + (64 + wstrip + n) * 40 + quad * 8];
            #pragma unroll
            for (int jd = 0; jd < 8; ++jd) {
                const bfrag bV = *(const bfrag*)&Vtu[kb2 * 4096 + (jd * 16 + n) * 32 + quad * 8];
                oacc[0][jd] = __builtin_amdgcn_mfma_f32_16x16x32_bf16(aP0, bV, oacc[0][jd], 0, 0, 0);
                oacc[1][jd] = __builtin_amdgcn_mfma_f32_16x16x32_bf16(aP1, bV, oacc[1][jd], 0, 0, 0);
            }
        }

        __syncthreads();   // LDS readers drained (+ drains vmcnt -> regs valid)
        // refill Ksu/Vtu from registers (UNCONDITIONAL; dead on last iter)
        #pragma unroll
        for (int i = 0; i < 6; ++i)
            *(bfrag*)(Ksu + (wave + 4 * i) * 512 + lane * 8) = kreg[i];
        #pragma unroll
        for (int i = 0; i < 4; ++i)
            *(bfrag*)(Vtu + (wave + 4 * i) * 512 + lane * 8) = vreg[i];
        __syncthreads();   // new tile visible before next QK^T
    }

    // reduce l partials, epilogue
    #pragma unroll
    for (int sp = 0; sp < 2; ++sp) {
        #pragma unroll
        for (int r = 0; r < 4; ++r) {
            float v = lp[sp][r];
            #pragma unroll
            for (int msk = 1; msk < 16; msk <<= 1) v += __shfl_xor(v, msk);
            const float inv = 1.f / v;
            ushort* op = o + (size_t)(b * SS + q0 + sp * 64 + wstrip + quad * 4 + r)
                             * (HH * DV) + h * DV;
            #pragma unroll
            for (int jd = 0; jd < 8; ++jd)
                op[jd * 16 + n] = f2bf(oacc[sp][jd][r] * inv);
        }
    }
}

// ---------------- launch ----------------
extern "C" void kernel_launch(void* const* d_in, const int* in_sizes, int n_in,
                              void* d_out, int out_size, void* d_ws, size_t ws_size,
                              hipStream_t stream) {
    const float* hs    = (const float*)d_in[0];
    const float* cosb  = (const float*)d_in[1];
    const float* sinb  = (const float*)d_in[2];
    const float* Wqa   = (const float*)d_in[3];
    const float* qa_w  = (const float*)d_in[4];
    const float* Wqb   = (const float*)d_in[5];
    const float* Wkva  = (const float*)d_in[6];
    const float* kva_w = (const float*)d_in[7];
    const float* Wkvb  = (const float*)d_in[8];
    const float* Wo    = (const float*)d_in[9];
    float* out = (float*)d_out;

    const int T = BB * SS; // 4096 tokens

    char* w = (char*)d_ws;
    auto alloc = [&](size_t bytes) {
        void* r = (void*)w;
        w += (bytes + 255) & ~(size_t)255;
        return r;
    };
    ushort* hs_bf  = (ushort*)alloc((size_t)T * DD * 2);            // 16.8 MB
    ushort* Wcat   = (ushort*)alloc((size_t)NCATP * DD * 2);        //  9.4
    ushort* Wqbt   = (ushort*)alloc((size_t)(HH * DQ) * QL * 2);    //  9.4
    ushort* Wkvbt  = (ushort*)alloc((size_t)(HH * KVD) * KVL * 2);  //  4.2
    ushort* Wot    = (ushort*)alloc((size_t)DD * DD * 2);           //  8.4
    ushort* qa_bf  = (ushort*)alloc((size_t)T * QL * 2);            // 12.6
    ushort* Qbuf   = (ushort*)alloc((size_t)T * HH * DQ * 2);       // 25.2
    ushort* ckv_bf = (ushort*)alloc((size_t)T * CKVS * 2);          //  5.2
    ushort* kvn_bf = (ushort*)alloc((size_t)T * KVL * 2);           //  4.2
    ushort* kv_bf  = (ushort*)alloc((size_t)T * HH * KVD * 2);      // 33.6
    ushort* krb    = (ushort*)alloc((size_t)T * DR * 2);            //  0.5
    // aliases (lifetimes verified):
    ushort* Vtb    = Wcat;   // over Wcat+Wqbt (dead after gemmAW/gemmQKV)
    ushort* ao_bf  = hs_bf;  // hs_bf dead after gemmAW

    // 0. cast hs; transpose Wqa/Wkva only (the rest backfills gemmAW)
    castf2bf<<<(T * DD / 4) / 256, 256, 0, stream>>>(hs, hs_bf);
    WtBatch wb;
    wb.src[0] = Wqa;  wb.dst[0] = Wcat;                   wb.K[0] = DD; wb.N[0] = QL;       wb.nx[0] = 48;
    wb.src[1] = Wkva; wb.dst[1] = Wcat + (size_t)QL * DD; wb.K[1] = DD; wb.N[1] = KVL + DR; wb.nx[1] = 20;
    wb.base[0] = 0;
    wb.base[1] = wb.nx[0] * (DD / 32);                // 3072
    wb.base[2] = wb.base[1] + wb.nx[1] * (DD / 32);   // 4352
    wtrans_b<<<wb.base[2], 256, 0, stream>>>(wb);

    // 1. gemmA (144 blocks) + Wqb/Wkvb/Wo transpose walkers (112 blocks)
    gemmAW<<<dim3(256), 512, 0, stream>>>(hs_bf, Wcat, qa_bf, ckv_bf,
                                          Wqb, Wqbt, Wkvb, Wkvbt, Wo, Wot);
    // 2. both RMSNorms (qa in-place; ckv->kvn + k_rot rope) in ONE launch
    rmsnorm2<<<2 * T, 256, 0, stream>>>(qa_bf, qa_w, ckv_bf, kva_w, kvn_bf,
                                        krb, cosb, sinb);
    // 3. grouped GEMM on 256x128 tiles: Q (384 blocks) + kv (512 blocks)
    gemmQKV<<<dim3(896), 512, 0, stream>>>(qa_bf, Wqbt, Qbuf,
                                           kvn_bf, Wkvbt, kv_bf);
    // 4. rope Q + V transpose in ONE launch
    ropevprep<<<T + 8192, 256, 0, stream>>>(Qbuf, cosb, sinb, kv_bf, Vtb);
    // 5. MFMA flash attention -> ao (bf16)
    fattn_mfma<<<dim3(16, HH, BB), 256, 0, stream>>>(Qbuf, kv_bf, krb, Vtb, ao_bf);
    // 6. out = ao @ Wo (fp32), 256x128 tile -> 256 blocks (full fill)
    gemmW<DD, 16, DD><<<dim3(256), 512, 0, stream>>>(ao_bf, Wot, out);
}

// Round 7
// 402.970 us; speedup vs baseline: 1.2013x; 1.0280x over previous
//
#include <hip/hip_runtime.h>
#include <math.h>

#define BB 2
#define SS 2048
#define DD 2048
#define HH 16
#define DN 128
#define DR 64
#define DV 128
#define QL 1536
#define KVL 512
#define DQ 192           // DN + DR
#define CKVS 640         // ckv row stride (576 padded to 640)
#define KVD 256          // DN + DV
#define NCAT 2176        // QL + CKVS (fused first GEMM)
#define NCATP 2304       // NCAT padded to 9*256 for the 256-wide GEMM tile
#define EPSF 1e-6f

typedef short bfrag __attribute__((ext_vector_type(8)));   // 8 bf16 (4 VGPRs)
typedef float facc  __attribute__((ext_vector_type(4)));   // 4 fp32 acc

// ---------------- helpers ----------------
__device__ __forceinline__ ushort f2bf(float f) {
    union { float f; unsigned u; } v; v.f = f;
    unsigned r = v.u + 0x7fffu + ((v.u >> 16) & 1u);  // RNE
    return (ushort)(r >> 16);
}
__device__ __forceinline__ float bf2f(ushort u) {
    union { unsigned u; float f; } v; v.u = ((unsigned)u) << 16;
    return v.f;
}
__device__ __forceinline__ float fexp2(float x) {   // raw v_exp_f32 (2^x)
    float r; asm("v_exp_f32 %0, %1" : "=v"(r) : "v"(x)); return r;
}
__device__ __forceinline__ float wave_red_sum(float v) {
    #pragma unroll
    for (int o = 32; o > 0; o >>= 1) v += __shfl_down(v, o);
    return v;
}
__device__ __forceinline__ void gl2lds16(const ushort* g, ushort* l) {
    __builtin_amdgcn_global_load_lds(
        (const __attribute__((address_space(1))) void*)g,
        (__attribute__((address_space(3))) void*)l, 16, 0, 0);
}

// ---------------- fp32 -> bf16 cast (vectorized) ----------------
__global__ __launch_bounds__(256) void castf2bf(const float* __restrict__ x,
                                                ushort* __restrict__ y) {
    const int i = blockIdx.x * 256 + threadIdx.x;
    const float4 v = ((const float4*)x)[i];
    ushort4 o;
    o.x = f2bf(v.x); o.y = f2bf(v.y); o.z = f2bf(v.z); o.w = f2bf(v.w);
    ((ushort4*)y)[i] = o;
}

// ------- batched weight cast+transpose (now only Wqa, Wkva) ----------
struct WtBatch {
    const float* src[2];
    ushort* dst[2];
    int K[2];
    int N[2];
    int nx[2];
    int base[3];
};
__global__ __launch_bounds__(256) void wtrans_b(WtBatch d) {
    __shared__ float tile[32][33];
    int bid = blockIdx.x;
    int seg = (bid >= d.base[1]) ? 1 : 0;
    const int l = bid - d.base[seg];
    const int nx = d.nx[seg];
    const int bx = l % nx, by = l / nx;
    const float* W = d.src[seg];
    ushort* Wt = d.dst[seg];
    const int K = d.K[seg], N = d.N[seg];
    const int k0 = by * 32, n0 = bx * 32;
    const int t = threadIdx.x;
    const int tx = t & 31, ty = t >> 5;
    #pragma unroll
    for (int r = 0; r < 4; ++r) {
        const int n = n0 + tx;
        tile[ty + r * 8][tx] =
            (n < N) ? W[(size_t)(k0 + ty + r * 8) * N + n] : 0.f;
    }
    __syncthreads();
    #pragma unroll
    for (int r = 0; r < 4; ++r) {
        const int n = n0 + ty + r * 8;
        Wt[(size_t)n * K + k0 + tx] = f2bf(tile[tx][ty + r * 8]);
    }
}

// ================== 256x256 8-phase MFMA GEMM core (m201 template) =========
// Caller declares __shared__ ushort L[65536] and passes pre-swizzled LID_.

__device__ __forceinline__ void stage_half(const ushort* __restrict__ G,
                                           int ldg, int grow0, int kcol0,
                                           ushort* Lr, int wave, int lane) {
    const int r0   = lane >> 3;
    const int slot = (lane & 7) ^ r0;          // inverse-swizzled global slot
    const ushort* s0 = G + (size_t)(grow0 + wave * 16 + r0) * ldg + kcol0 + slot * 8;
    gl2lds16(s0,                    Lr + wave * 1024);        // rows w*16..+8
    gl2lds16(s0 + (size_t)8 * ldg,  Lr + wave * 1024 + 512);  // rows +8..+16
}

#define PH_PRE  do { __builtin_amdgcn_sched_barrier(0);                      \
                     __builtin_amdgcn_s_barrier();                           \
                     asm volatile("s_waitcnt lgkmcnt(0)" ::: "memory");      \
                     __builtin_amdgcn_sched_barrier(0);                      \
                     __builtin_amdgcn_s_setprio(1); } while (0)
#define PH_POST do { __builtin_amdgcn_s_setprio(0);                          \
                     __builtin_amdgcn_sched_barrier(0);                      \
                     __builtin_amdgcn_s_barrier(); } while (0)

#define MFMA16(RB)                                                           \
    _Pragma("unroll")                                                        \
    for (int i = 0; i < 4; ++i)                                              \
        _Pragma("unroll")                                                    \
        for (int j = 0; j < 4; ++j)                                          \
            acc[(RB) + i][j] = __builtin_amdgcn_mfma_f32_16x16x32_bf16(      \
                a[i], b[j], acc[(RB) + i][j], 0, 0, 0);

#define GEMM256_CORE(A_, Bt_, K_, NBX_, LID_)                                 \
    const int t    = threadIdx.x;                                             \
    const int lane = t & 63;                                                  \
    const int wave = t >> 6;                                                  \
    const int wm   = wave >> 2;                                               \
    const int wn   = wave & 3;                                                \
    const int quad = lane >> 4;                                               \
    const int lrow = lane & 15;                                               \
    const int bx = (LID_) % (NBX_), by = (LID_) / (NBX_);                     \
    const int m0 = by * 256, n0 = bx * 256;                                   \
    const int s0x8  = (quad ^ (lrow & 7)) * 8;   /* swizzled slot, kh=0 */    \
    const int s1x8  = s0x8 ^ 32;                 /* kh=1: slot^4          */  \
    const int abase = lrow * 64;                                              \
    const int bbase = (wn & 1) * 4096 + lrow * 64;                            \
    facc acc[8][4];                                                           \
    _Pragma("unroll")                                                         \
    for (int i = 0; i < 8; ++i)                                               \
        _Pragma("unroll")                                                     \
        for (int j = 0; j < 4; ++j) acc[i][j] = (facc)(0.f);                  \
    const int nk = (K_) >> 6;                                                 \
    stage_half((A_),  (K_), m0,        0, L,         wave, lane);             \
    stage_half((A_),  (K_), m0 + 128,  0, L + 8192,  wave, lane);             \
    stage_half((Bt_), (K_), n0,        0, L + 16384, wave, lane);             \
    stage_half((Bt_), (K_), n0 + 128,  0, L + 24576, wave, lane);             \
    stage_half((Bt_), (K_), n0,       64, L + 49152, wave, lane);             \
    stage_half((Bt_), (K_), n0 + 128, 64, L + 57344, wave, lane);             \
    asm volatile("s_waitcnt vmcnt(4)" ::: "memory");                          \
    __builtin_amdgcn_s_barrier();                                             \
    for (int kt = 0; kt < nk; ++kt) {                                         \
        const int p = kt & 1;                                                 \
        ushort* LA = L + p * 32768 + wm * 8192;                               \
        ushort* LB = L + p * 32768 + 16384 + (wn >> 1) * 8192;                \
        ushort* Lq = L + (p ^ 1) * 32768;                                     \
        const int kn = (kt + 1) * 64;                                         \
        bfrag a[4], b[4];                                                     \
        _Pragma("unroll")                                                     \
        for (int i = 0; i < 4; ++i)                                           \
            a[i] = *(const bfrag*)(LA + i * 1024 + abase + s0x8);             \
        _Pragma("unroll")                                                     \
        for (int j = 0; j < 4; ++j)                                           \
            b[j] = *(const bfrag*)(LB + bbase + j * 1024 + s0x8);             \
        if (kt + 1 < nk) stage_half((A_), (K_), m0, kn, Lq, wave, lane);      \
        PH_PRE;                                                               \
        MFMA16(0)                                                             \
        PH_POST;                                                              \
        _Pragma("unroll")                                                     \
        for (int i = 0; i < 4; ++i)                                           \
            a[i] = *(const bfrag*)(LA + (4 + i) * 1024 + abase + s0x8);       \
        if (kt + 1 < nk)                                                      \
            stage_half((A_), (K_), m0 + 128, kn, Lq + 8192, wave, lane);      \
        PH_PRE;                                                               \
        MFMA16(4)                                                             \
        PH_POST;                                                              \
        _Pragma("unroll")                                                     \
        for (int i = 0; i < 4; ++i)                                           \
            a[i] = *(const bfrag*)(LA + i * 1024 + abase + s1x8);             \
        _Pragma("unroll")                                                     \
        for (int j = 0; j < 4; ++j)                                           \
            b[j] = *(const bfrag*)(LB + bbase + j * 1024 + s1x8);             \
        PH_PRE;                                                               \
        MFMA16(0)                                                             \
        PH_POST;                                                              \
        _Pragma("unroll")                                                     \
        for (int i = 0; i < 4; ++i)                                           \
            a[i] = *(const bfrag*)(LA + (4 + i) * 1024 + abase + s1x8);       \
        if (kt + 2 < nk) {                                                    \
            stage_half((Bt_), (K_), n0,       kn + 64,                        \
                       L + p * 32768 + 16384, wave, lane);                    \
            stage_half((Bt_), (K_), n0 + 128, kn + 64,                        \
                       L + p * 32768 + 24576, wave, lane);                    \
            asm volatile("s_waitcnt vmcnt(4)" ::: "memory");                  \
        } else {                                                              \
            asm volatile("s_waitcnt vmcnt(0)" ::: "memory");                  \
        }                                                                     \
        PH_PRE;                                                               \
        MFMA16(4)                                                             \
        PH_POST;                                                              \
    }

// ====== 256x128-tile 2-phase core (full-fill variant; schedule per r4/r5) ===
#define GEMMW_CORE(A_, Bt_, K_, NBX_, LID_)                                   \
    const int t    = threadIdx.x;                                             \
    const int lane = t & 63;                                                  \
    const int wave = t >> 6;                                                  \
    const int wm   = wave >> 1;          /* 0..3 */                           \
    const int wn   = wave & 1;           /* 0..1 */                           \
    const int quad = lane >> 4;                                               \
    const int lrow = lane & 15;                                               \
    const int bx = (LID_) % (NBX_), by = (LID_) / (NBX_);                     \
    const int m0 = by * 256, n0 = bx * 128;                                   \
    const int s0x8 = (quad ^ (lrow & 7)) * 8;                                 \
    const int s1x8 = s0x8 ^ 32;                                               \
    facc acc[4][4];                                                           \
    _Pragma("unroll")                                                         \
    for (int i = 0; i < 4; ++i)                                               \
        _Pragma("unroll")                                                     \
        for (int j = 0; j < 4; ++j) acc[i][j] = (facc)(0.f);                  \
    const int nk = (K_) >> 6;                                                 \
    stage_half((A_),  (K_), m0,        0, L,          wave, lane);            \
    stage_half((A_),  (K_), m0 + 128,  0, L + 8192,   wave, lane);            \
    stage_half((Bt_), (K_), n0,        0, L + 32768,  wave, lane);            \
    stage_half((Bt_), (K_), n0,       64, L + 40960,  wave, lane);            \
    asm volatile("s_waitcnt vmcnt(0)" ::: "memory");                          \
    __builtin_amdgcn_s_barrier();                                             \
    int bp = 0, bp2 = 2;   /* kt%3 and (kt+2)%3 */                            \
    for (int kt = 0; kt < nk; ++kt) {                                         \
        const int p = kt & 1;                                                 \
        ushort* LA = L + p * 16384 + (wm >> 1) * 8192                         \
                       + ((wm & 1) * 64 + lrow) * 64;                         \
        ushort* LB = L + 32768 + bp * 8192 + (wn * 64 + lrow) * 64;           \
        const int kn = (kt + 1) * 64;                                         \
        bfrag a[4], b[4];                                                     \
        _Pragma("unroll")                                                     \
        for (int i = 0; i < 4; ++i) a[i] = *(const bfrag*)(LA + i * 1024 + s0x8); \
        _Pragma("unroll")                                                     \
        for (int j = 0; j < 4; ++j) b[j] = *(const bfrag*)(LB + j * 1024 + s0x8); \
        if (kt + 1 < nk) {                                                    \
            stage_half((A_), (K_), m0,       kn, L + (p ^ 1) * 16384,        wave, lane); \
            stage_half((A_), (K_), m0 + 128, kn, L + (p ^ 1) * 16384 + 8192, wave, lane); \
        }                                                                     \
        if (kt + 2 < nk)                                                      \
            stage_half((Bt_), (K_), n0, kn + 64, L + 32768 + bp2 * 8192, wave, lane); \
        PH_PRE;                                                               \
        MFMA16(0)                                                             \
        PH_POST;                                                              \
        _Pragma("unroll")                                                     \
        for (int i = 0; i < 4; ++i) a[i] = *(const bfrag*)(LA + i * 1024 + s1x8); \
        _Pragma("unroll")                                                     \
        for (int j = 0; j < 4; ++j) b[j] = *(const bfrag*)(LB + j * 1024 + s1x8); \
        if (kt + 2 < nk) { asm volatile("s_waitcnt vmcnt(2)" ::: "memory"); } \
        else             { asm volatile("s_waitcnt vmcnt(0)" ::: "memory"); } \
        PH_PRE;                                                               \
        MFMA16(0)                                                             \
        PH_POST;                                                              \
        bp  = (bp  == 2) ? 0 : bp  + 1;                                       \
        bp2 = (bp2 == 2) ? 0 : bp2 + 1;                                       \
    }

// ------- gemmW: out = ao @ Wo (fp32), 256x128 tiles, full 256-block fill ----
template <int K, int NBX, int NOUT>
__global__ __launch_bounds__(512, 2) void gemmW(const ushort* __restrict__ A,
                                                const ushort* __restrict__ Bt,
                                                float* __restrict__ C) {
    __shared__ ushort L[57344];   // 112 KiB
    int wg = (int)blockIdx.x;
    { const int cpx = (int)gridDim.x >> 3; wg = (wg & 7) * cpx + (wg >> 3); }
    GEMMW_CORE(A, Bt, K, NBX, wg)
    #pragma unroll
    for (int m = 0; m < 4; ++m) {
        const int row = m0 + wm * 64 + m * 16 + quad * 4;
        #pragma unroll
        for (int nf = 0; nf < 4; ++nf) {
            const int col = n0 + wn * 64 + nf * 16 + lrow;
            #pragma unroll
            for (int r = 0; r < 4; ++r)
                C[(size_t)(row + r) * NOUT + col] = acc[m][nf][r];
        }
    }
}

// ====== gemmAW: gemmA (144 x 256^2 blocks) + 112 transpose-walker blocks ====
__global__ __launch_bounds__(512, 2) void gemmAW(
    const ushort* __restrict__ A,   const ushort* __restrict__ Bt,
    ushort* __restrict__ qa,        ushort* __restrict__ ckv,
    const float* __restrict__ Wqb,  ushort* __restrict__ Wqbt,
    const float* __restrict__ Wkvb, ushort* __restrict__ Wkvbt,
    const float* __restrict__ Wo,   ushort* __restrict__ Wot) {
    __shared__ ushort L[65536];
    const int bid = (int)blockIdx.x;
    if (bid < 144) {
        const int lid = (bid & 7) * 18 + (bid >> 3);   // 144 = 18*8 bijective
        GEMM256_CORE(A, Bt, DD, 9, lid)
        #pragma unroll
        for (int m = 0; m < 8; ++m) {
            const int row = m0 + wm * 128 + m * 16 + quad * 4;
            #pragma unroll
            for (int nf = 0; nf < 4; ++nf) {
                const int col = n0 + wn * 64 + nf * 16 + lrow;
                #pragma unroll
                for (int r = 0; r < 4; ++r) {
                    if (col < QL)
                        qa[(size_t)(row + r) * QL + col] = f2bf(acc[m][nf][r]);
                    else if (col < NCAT)
                        ckv[(size_t)(row + r) * CKVS + col - QL] = f2bf(acc[m][nf][r]);
                }
            }
        }
    } else {
        const int wid = bid - 144;            // 0..111
        const int t   = threadIdx.x;
        const int half = t >> 8;              // two 256-thread halves
        const int tl = t & 255;
        const int tx = tl & 31, ty = tl >> 5;
        float (*tile)[33] = (float(*)[33])((float*)L + half * 32 * 33);
        for (int it = 0; it < 48; ++it) {
            const int idx = (it * 112 + wid) * 2 + half;   // 0..10751
            const float* W; ushort* Wt; int K, N, nx, l;
            if (idx < 4608)      { l = idx;        W = Wqb;  Wt = Wqbt;  K = QL;  N = HH * DQ;  nx = 96; }
            else if (idx < 6656) { l = idx - 4608; W = Wkvb; Wt = Wkvbt; K = KVL; N = HH * KVD; nx = 128; }
            else                 { l = idx - 6656; W = Wo;   Wt = Wot;   K = DD;  N = DD;       nx = 64; }
            const int bx2 = l % nx, by2 = l / nx;
            const int k0 = by2 * 32, n0w = bx2 * 32;
            #pragma unroll
            for (int r = 0; r < 4; ++r)
                tile[ty + r * 8][tx] = W[(size_t)(k0 + ty + r * 8) * N + n0w + tx];
            __syncthreads();
            #pragma unroll
            for (int r = 0; r < 4; ++r)
                Wt[(size_t)(n0w + ty + r * 8) * K + k0 + tx] = f2bf(tile[tx][ty + r * 8]);
            __syncthreads();
        }
    }
}

// ------ grouped GEMM (8-phase 256^2): blocks 0..191 = Q, 192..447 = kv ------
// Back on the 8-phase core (r5-build verified): per-block efficiency ~2x the
// 2-phase core; dynamic backfill handles the long-Q/short-kv mix (LPT: Q
// first).  Per-segment bijective XCD swizzle.
__global__ __launch_bounds__(512, 2) void gemmQKV(
    const ushort* __restrict__ qa,  const ushort* __restrict__ Wqbt,
    ushort* __restrict__ Qbuf,
    const ushort* __restrict__ kvn, const ushort* __restrict__ Wkvbt,
    ushort* __restrict__ kvb) {
    __shared__ ushort L[65536];
    const int bid = (int)blockIdx.x;
    if (bid < 192) {
        const int lid = (bid & 7) * 24 + (bid >> 3);       // 192 = 24*8
        GEMM256_CORE(qa, Wqbt, QL, 12, lid)
        const float scaling = 0.10411754831f; // 192^-0.5 * log2(e)
        #pragma unroll
        for (int m = 0; m < 8; ++m) {
            const int row = m0 + wm * 128 + m * 16 + quad * 4;
            #pragma unroll
            for (int nf = 0; nf < 4; ++nf) {
                const int col = n0 + wn * 64 + nf * 16 + lrow;
                const int h = col / DQ, d = col - h * DQ;
                #pragma unroll
                for (int r = 0; r < 4; ++r) {
                    const int tok = row + r;
                    const int b = tok >> 11, s2 = tok & (SS - 1);
                    Qbuf[((size_t)(b * HH + h) * SS + s2) * DQ + d] =
                        f2bf(acc[m][nf][r] * scaling);
                }
            }
        }
    } else {
        const int b2 = bid - 192;
        const int lid = (b2 & 7) * 32 + (b2 >> 3);         // 256 = 32*8
        GEMM256_CORE(kvn, Wkvbt, KVL, 16, lid)
        #pragma unroll
        for (int m = 0; m < 8; ++m) {
            const int row = m0 + wm * 128 + m * 16 + quad * 4;
            #pragma unroll
            for (int nf = 0; nf < 4; ++nf) {
                const int col = n0 + wn * 64 + nf * 16 + lrow;
                #pragma unroll
                for (int r = 0; r < 4; ++r)
                    kvb[(size_t)(row + r) * (HH * KVD) + col] = f2bf(acc[m][nf][r]);
            }
        }
    }
}

// ------- merged RMSNorms: bid<T -> qa in-place; else kv norm + k_rot rope ---
__global__ __launch_bounds__(256) void rmsnorm2(ushort* __restrict__ qa,
                                                const float* __restrict__ qaw,
                                                const ushort* __restrict__ ckv,
                                                const float* __restrict__ kvw,
                                                ushort* __restrict__ kvn,
                                                ushort* __restrict__ krb,
                                                const float* __restrict__ cosb,
                                                const float* __restrict__ sinb) {
    __shared__ float red[4];
    const int t = threadIdx.x;
    const int lane = t & 63, wid = t >> 6;
    const int bid = (int)blockIdx.x;
    if (bid < BB * SS) {
        ushort* xr = qa + (size_t)bid * QL;
        float ss = 0.f;
        for (int i = t; i < QL; i += 256) { float v = bf2f(xr[i]); ss += v * v; }
        ss = wave_red_sum(ss);
        if (lane == 0) red[wid] = ss;
        __syncthreads();
        const float tot = red[0] + red[1] + red[2] + red[3];
        const float sc = rsqrtf(tot / (float)QL + EPSF);
        for (int i = t; i < QL; i += 256) xr[i] = f2bf(qaw[i] * bf2f(xr[i]) * sc);
    } else {
        const int row = bid - BB * SS;
        const ushort* xr = ckv + (size_t)row * CKVS;
        ushort* yr = kvn + (size_t)row * KVL;
        if (t < 64) {   // k_rot rope (independent of the norm)
            const int p = t;
            const ushort* kin = xr + KVL;
            const float c  = cosb[(size_t)row * DR + p];
            const float sn = sinb[(size_t)row * DR + p];
            const float self = bf2f(kin[p]);
            const float partner = bf2f(kin[p < 32 ? p + 32 : p - 32]);
            const float v = (p < 32) ? (self * c - partner * sn)
                                     : (self * c + partner * sn);
            krb[(size_t)row * DR + p] = f2bf(v);
        }
        float ss = 0.f;
        for (int i = t; i < KVL; i += 256) { float v = bf2f(xr[i]); ss += v * v; }
        ss = wave_red_sum(ss);
        if (lane == 0) red[wid] = ss;
        __syncthreads();
        const float tot = red[0] + red[1] + red[2] + red[3];
        const float sc = rsqrtf(tot / (float)KVL + EPSF);
        for (int i = t; i < KVL; i += 256) yr[i] = f2bf(kvw[i] * bf2f(xr[i]) * sc);
    }
}

// ------- merged qrope + vprep: bid<T -> rope Qbuf; else V-transpose --------
__global__ __launch_bounds__(256) void ropevprep(ushort* __restrict__ Qbuf,
                                                 const float* __restrict__ cosb,
                                                 const float* __restrict__ sinb,
                                                 const ushort* __restrict__ kvb,
                                                 ushort* __restrict__ Vtb) {
    __shared__ ushort tile[32][33];
    const int bid = (int)blockIdx.x;
    const int t = threadIdx.x;
    if (bid < BB * SS) {
        const int tok = bid;
        const int b = tok >> 11, s = tok & (SS - 1);
        const int p = t & 31, hh = t >> 5;
        const float c0 = cosb[(size_t)tok * DR + p];
        const float s0 = sinb[(size_t)tok * DR + p];
        const float c1 = cosb[(size_t)tok * DR + p + 32];
        const float s1 = sinb[(size_t)tok * DR + p + 32];
        #pragma unroll
        for (int it = 0; it < 2; ++it) {
            const int h = hh + it * 8;
            ushort* base = Qbuf + ((size_t)(b * HH + h) * SS + s) * DQ + DN;
            const float x0 = bf2f(base[p]), x1 = bf2f(base[p + 32]);
            base[p]      = f2bf(x0 * c0 - x1 * s0);
            base[p + 32] = f2bf(x1 * c1 + x0 * s1);
        }
    } else {
        const int v = bid - BB * SS;             // 0..8191
        const int kp0 = (v & 63) * 32;
        const int dv0 = ((v >> 6) & 3) * 32;
        const int bh  = v >> 8;
        const int b = bh / HH, h = bh - b * HH;
        const int tx = t & 31, ty = t >> 5;
        #pragma unroll
        for (int r = 0; r < 4; ++r)
            tile[ty + r * 8][tx] =
                kvb[(size_t)(b * SS + kp0 + ty + r * 8) * (HH * KVD) + h * KVD + DN + dv0 + tx];
        __syncthreads();
        #pragma unroll
        for (int r = 0; r < 4; ++r)
            Vtb[((size_t)bh * DV + dv0 + ty + r * 8) * SS + kp0 + tx] = tile[tx][ty + r * 8];
    }
}

// ---------------- MFMA flash attention (v4 structure, unchanged) ----------
__global__ __launch_bounds__(256, 2) void fattn_mfma(
    const ushort* __restrict__ Qb,   // [(b*HH+h)*SS+s][192] pre-scaled+roped
    const ushort* __restrict__ kvb,  // [tok][HH*KVD]
    const ushort* __restrict__ krb,  // [tok][64]
    const ushort* __restrict__ Vt,   // [(b*HH+h)*DV+dv][SS]
    ushort* __restrict__ o)          // [tok][HH*DV]
{
    const int h  = blockIdx.y;
    const int b  = blockIdx.z;
    const int qt = b ? (15 - (int)blockIdx.x) : (int)blockIdx.x;
    const int bh = b * HH + h;
    const int q0 = qt * 128;
    const int t    = threadIdx.x;
    const int lane = t & 63;
    const int wave = t >> 6;
    const int quad = lane >> 4;
    const int n    = lane & 15;
    const int wstrip = wave * 16;

    __shared__ ushort Ksu[6 * 64 * 32];   // 24 KB
    __shared__ ushort Vtu[2 * 128 * 32];  // 16 KB
    __shared__ ushort Psu[2 * 128 * 40];  // 20 KB (padded rows)

    const ushort* vbase = Vt + (size_t)bh * DV * SS;

    // preload Q A-frags for both strips
    bfrag aQ[2][6];
    #pragma unroll
    for (int sp = 0; sp < 2; ++sp) {
        const ushort* qrow = Qb + ((size_t)bh * SS + q0 + sp * 64 + wstrip + n) * DQ;
        #pragma unroll
        for (int kb = 0; kb < 6; ++kb)
            aQ[sp][kb] = *(const bfrag*)(qrow + kb * 32 + quad * 8);
    }

    facc oacc[2][8];
    float lp[2][4];
    #pragma unroll
    for (int sp = 0; sp < 2; ++sp) {
        #pragma unroll
        for (int jd = 0; jd < 8; ++jd) oacc[sp][jd] = (facc)(0.f);
        #pragma unroll
        for (int r = 0; r < 4; ++r) lp[sp][r] = 0.f;
    }

    // prologue: stage tile kt=0 via global_load_lds
    #pragma unroll
    for (int i = 0; i < 6; ++i) {
        const int g = wave + 4 * i;
        const int kb = g >> 2;                    // wave-uniform
        const int rem = (g & 3) * 64 + lane;
        const int row = rem >> 2, sub = rem & 3;
        const int tok = b * SS + row;
        const ushort* src = (kb < 4)
            ? kvb + (size_t)tok * (HH * KVD) + h * KVD + kb * 32 + sub * 8
            : krb + (size_t)tok * DR + (kb - 4) * 32 + sub * 8;
        gl2lds16(src, Ksu + g * 512);
    }
    #pragma unroll
    for (int i = 0; i < 4; ++i) {
        const int g = wave + 4 * i;
        const int kb2 = g >> 3;                   // wave-uniform
        const int rem = (g & 7) * 64 + lane;
        const int dv = rem >> 2, sub = rem & 3;
        gl2lds16(vbase + (size_t)dv * SS + kb2 * 32 + sub * 8, Vtu + g * 512);
    }
    __syncthreads();

    const int nkt = 2 * qt + 2;
    for (int kt = 0; kt < nkt; ++kt) {
        const int k0 = kt * 64;
        const int kk = (kt + 1 < nkt) ? (k0 + 64) : (SS - 64);  // clamped

        // ---- issue next-tile global loads into registers (UNCONDITIONAL) ---
        bfrag kreg[6], vreg[4];
        #pragma unroll
        for (int i = 0; i < 6; ++i) {
            const int g = wave + 4 * i;
            const int kb = g >> 2;
            const int rem = (g & 3) * 64 + lane;
            const int row = rem >> 2, sub = rem & 3;
            const int tok = b * SS + kk + row;
            const ushort* src = (kb < 4)
                ? kvb + (size_t)tok * (HH * KVD) + h * KVD + kb * 32 + sub * 8
                : krb + (size_t)tok * DR + (kb - 4) * 32 + sub * 8;
            kreg[i] = *(const bfrag*)src;
        }
        #pragma unroll
        for (int i = 0; i < 4; ++i) {
            const int g = wave + 4 * i;
            const int kb2 = g >> 3;
            const int rem = (g & 7) * 64 + lane;
            const int dv = rem >> 2, sub = rem & 3;
            vreg[i] = *(const bfrag*)(vbase + (size_t)dv * SS + kk + kb2 * 32 + sub * 8);
        }
        __builtin_amdgcn_sched_barrier(0);   // pin load issue BEFORE compute

        // ---- S = Q K^T, both strips share each K frag ----
        facc s[2][4];
        #pragma unroll
        for (int sp = 0; sp < 2; ++sp)
            #pragma unroll
            for (int j = 0; j < 4; ++j) s[sp][j] = (facc)(0.f);
        #pragma unroll
        for (int kb = 0; kb < 6; ++kb) {
            #pragma unroll
            for (int j = 0; j < 4; ++j) {
                const bfrag bk =
                    *(const bfrag*)&Ksu[kb * 2048 + (j * 16 + n) * 32 + quad * 8];
                s[0][j] = __builtin_amdgcn_mfma_f32_16x16x32_bf16(aQ[0][kb], bk, s[0][j], 0, 0, 0);
                s[1][j] = __builtin_amdgcn_mfma_f32_16x16x32_bf16(aQ[1][kb], bk, s[1][j], 0, 0, 0);
            }
        }

        // ---- exp2 (m=0) + causal select; P -> LDS (wave-private rows) ----
        const bool fullt = (k0 + 64 <= q0);   // tile entirely below diagonal
        if (fullt) {
            #pragma unroll
            for (int sp = 0; sp < 2; ++sp) {
                #pragma unroll
                for (int j = 0; j < 4; ++j) {
                    #pragma unroll
                    for (int r = 0; r < 4; ++r) {
                        const float p = fexp2(s[sp][j][r]);
                        lp[sp][r] += p;
                        Psu[(j >> 1) * 5120 + (sp * 64 + wstrip + quad * 4 + r) * 40
                            + (j & 1) * 16 + n] = f2bf(p);
                    }
                }
            }
        } else {
            #pragma unroll
            for (int sp = 0; sp < 2; ++sp) {
                const int rowg0 = q0 + sp * 64 + wstrip + quad * 4;
                #pragma unroll
                for (int j = 0; j < 4; ++j) {
                    const int kpos = k0 + j * 16 + n;
                    #pragma unroll
                    for (int r = 0; r < 4; ++r) {
                        const float p = (kpos <= rowg0 + r) ? fexp2(s[sp][j][r]) : 0.f;
                        lp[sp][r] += p;
                        Psu[(j >> 1) * 5120 + (sp * 64 + wstrip + quad * 4 + r) * 40
                            + (j & 1) * 16 + n] = f2bf(p);
                    }
                }
            }
        }

        // ---- O += P @ V; V frags shared across strips ----
        #pragma unroll
        for (int kb2 = 0; kb2 < 2; ++kb2) {
            const bfrag aP0 = *(const bfrag*)&Psu[kb2 * 5120 + (wstrip + n) * 40 + quad * 8];
            const bfrag aP1 = *(const bfrag*)&Psu[kb2 * 5120 + (64 + wstrip + n) * 40 + quad * 8];
            #pragma unroll
            for (int jd = 0; jd < 8; ++jd) {
                const bfrag bV = *(const bfrag*)&Vtu[kb2 * 4096 + (jd * 16 + n) * 32 + quad * 8];
                oacc[0][jd] = __builtin_amdgcn_mfma_f32_16x16x32_bf16(aP0, bV, oacc[0][jd], 0, 0, 0);
                oacc[1][jd] = __builtin_amdgcn_mfma_f32_16x16x32_bf16(aP1, bV, oacc[1][jd], 0, 0, 0);
            }
        }

        __syncthreads();   // LDS readers drained (+ drains vmcnt -> regs valid)
        // refill Ksu/Vtu from registers (UNCONDITIONAL; dead on last iter)
        #pragma unroll
        for (int i = 0; i < 6; ++i)
            *(bfrag*)(Ksu + (wave + 4 * i) * 512 + lane * 8) = kreg[i];
        #pragma unroll
        for (int i = 0; i < 4; ++i)
            *(bfrag*)(Vtu + (wave + 4 * i) * 512 + lane * 8) = vreg[i];
        __syncthreads();   // new tile visible before next QK^T
    }

    // reduce l partials, epilogue
    #pragma unroll
    for (int sp = 0; sp < 2; ++sp) {
        #pragma unroll
        for (int r = 0; r < 4; ++r) {
            float v = lp[sp][r];
            #pragma unroll
            for (int msk = 1; msk < 16; msk <<= 1) v += __shfl_xor(v, msk);
            const float inv = 1.f / v;
            ushort* op = o + (size_t)(b * SS + q0 + sp * 64 + wstrip + quad * 4 + r)
                             * (HH * DV) + h * DV;
            #pragma unroll
            for (int jd = 0; jd < 8; ++jd)
                op[jd * 16 + n] = f2bf(oacc[sp][jd][r] * inv);
        }
    }
}

// ---------------- launch ----------------
extern "C" void kernel_launch(void* const* d_in, const int* in_sizes, int n_in,
                              void* d_out, int out_size, void* d_ws, size_t ws_size,
                              hipStream_t stream) {
    const float* hs    = (const float*)d_in[0];
    const float* cosb  = (const float*)d_in[1];
    const float* sinb  = (const float*)d_in[2];
    const float* Wqa   = (const float*)d_in[3];
    const float* qa_w  = (const float*)d_in[4];
    const float* Wqb   = (const float*)d_in[5];
    const float* Wkva  = (const float*)d_in[6];
    const float* kva_w = (const float*)d_in[7];
    const float* Wkvb  = (const float*)d_in[8];
    const float* Wo    = (const float*)d_in[9];
    float* out = (float*)d_out;

    const int T = BB * SS; // 4096 tokens

    char* w = (char*)d_ws;
    auto alloc = [&](size_t bytes) {
        void* r = (void*)w;
        w += (bytes + 255) & ~(size_t)255;
        return r;
    };
    ushort* hs_bf  = (ushort*)alloc((size_t)T * DD * 2);            // 16.8 MB
    ushort* Wcat   = (ushort*)alloc((size_t)NCATP * DD * 2);        //  9.4
    ushort* Wqbt   = (ushort*)alloc((size_t)(HH * DQ) * QL * 2);    //  9.4
    ushort* Wkvbt  = (ushort*)alloc((size_t)(HH * KVD) * KVL * 2);  //  4.2
    ushort* Wot    = (ushort*)alloc((size_t)DD * DD * 2);           //  8.4
    ushort* qa_bf  = (ushort*)alloc((size_t)T * QL * 2);            // 12.6
    ushort* Qbuf   = (ushort*)alloc((size_t)T * HH * DQ * 2);       // 25.2
    ushort* ckv_bf = (ushort*)alloc((size_t)T * CKVS * 2);          //  5.2
    ushort* kvn_bf = (ushort*)alloc((size_t)T * KVL * 2);           //  4.2
    ushort* kv_bf  = (ushort*)alloc((size_t)T * HH * KVD * 2);      // 33.6
    ushort* krb    = (ushort*)alloc((size_t)T * DR * 2);            //  0.5
    // aliases (lifetimes verified):
    ushort* Vtb    = Wcat;   // over Wcat+Wqbt (dead after gemmAW/gemmQKV)
    ushort* ao_bf  = hs_bf;  // hs_bf dead after gemmAW

    // 0. cast hs; transpose Wqa/Wkva only (the rest backfills gemmAW)
    castf2bf<<<(T * DD / 4) / 256, 256, 0, stream>>>(hs, hs_bf);
    WtBatch wb;
    wb.src[0] = Wqa;  wb.dst[0] = Wcat;                   wb.K[0] = DD; wb.N[0] = QL;       wb.nx[0] = 48;
    wb.src[1] = Wkva; wb.dst[1] = Wcat + (size_t)QL * DD; wb.K[1] = DD; wb.N[1] = KVL + DR; wb.nx[1] = 20;
    wb.base[0] = 0;
    wb.base[1] = wb.nx[0] * (DD / 32);                // 3072
    wb.base[2] = wb.base[1] + wb.nx[1] * (DD / 32);   // 4352
    wtrans_b<<<wb.base[2], 256, 0, stream>>>(wb);

    // 1. gemmA (144 blocks) + Wqb/Wkvb/Wo transpose walkers (112 blocks)
    gemmAW<<<dim3(256), 512, 0, stream>>>(hs_bf, Wcat, qa_bf, ckv_bf,
                                          Wqb, Wqbt, Wkvb, Wkvbt, Wo, Wot);
    // 2. both RMSNorms (qa in-place; ckv->kvn + k_rot rope) in ONE launch
    rmsnorm2<<<2 * T, 256, 0, stream>>>(qa_bf, qa_w, ckv_bf, kva_w, kvn_bf,
                                        krb, cosb, sinb);
    // 3. grouped GEMM (8-phase 256^2): Q (192 blocks) + kv (256 blocks)
    gemmQKV<<<dim3(448), 512, 0, stream>>>(qa_bf, Wqbt, Qbuf,
                                           kvn_bf, Wkvbt, kv_bf);
    // 4. rope Q + V transpose in ONE launch
    ropevprep<<<T + 8192, 256, 0, stream>>>(Qbuf, cosb, sinb, kv_bf, Vtb);
    // 5. MFMA flash attention -> ao (bf16)
    fattn_mfma<<<dim3(16, HH, BB), 256, 0, stream>>>(Qbuf, kv_bf, krb, Vtb, ao_bf);
    // 6. out = ao @ Wo (fp32), 256x128 tile -> 256 blocks (full fill)
    gemmW<DD, 16, DD><<<dim3(256), 512, 0, stream>>>(ao_bf, Wot, out);
}